// Round 1
// baseline (6837.091 us; speedup 1.0000x reference)
//
#include <hip/hip_runtime.h>
#include <hip/hip_bf16.h>

typedef __attribute__((ext_vector_type(8))) short bf16x8;
typedef __attribute__((ext_vector_type(4))) float f32x4;

#define Hdim 256
#define NM 32      // N2 modes
#define NB 16      // batch
#define LL 4096    // seq len
#define PCH 256    // chunk length
#define NCH 16     // chunks = LL/PCH

// workspace offsets (bytes); total 202,375,168 B
#define OFF_U    ((size_t)0)            // U fp32 (B,L,H) 67,108,864 ; reused as X2
#define OFF_Z    ((size_t)67108864)     // Z states float2 [dir][b][h][c][n] 33,554,432
#define OFF_YF   ((size_t)100663296)    // YF fp32 (B,L,H) 67,108,864 ; reused as M (bf16)
#define OFF_G    ((size_t)167772160)    // G bf16 (B,L,H) 33,554,432 ; reused as T2 (bf16)
#define OFF_WTAB ((size_t)201326592)    // w   float2 [H][N2] 65,536
#define OFF_WP   ((size_t)201392128)    // w^P float2 [H][N2] 65,536
#define OFF_CE   ((size_t)201457664)    // Ceff float2 [2][H][N2] 131,072
#define OFF_W1T  ((size_t)201588736)    // Wout^T bf16 [512][256] 262,144
#define OFF_W2T  ((size_t)201850880)    // W2^T   bf16 [512][256] 262,144
#define OFF_W3T  ((size_t)202113024)    // W3^T   bf16 [256][512] 262,144

__device__ __forceinline__ float gelu_f(float v) {
    return 0.5f * v * (1.0f + erff(v * 0.70710678118654752f));
}
__device__ __forceinline__ unsigned short f2bf(float f) {  // RNE f32->bf16
    unsigned int u = __float_as_uint(f);
    u += 0x7fffu + ((u >> 16) & 1u);
    return (unsigned short)(u >> 16);
}

// ---------------- tables: w = exp(dt*A), w^P, Ceff = 2*C*(w-1)/A ----------------
__global__ void k_tab(const float* __restrict__ logdt, const float* __restrict__ Are,
                      const float* __restrict__ Aim, const float* __restrict__ Cre,
                      const float* __restrict__ Cim, float2* __restrict__ wtab,
                      float2* __restrict__ wptab, float2* __restrict__ ceff) {
    int idx = blockIdx.x * blockDim.x + threadIdx.x;
    if (idx >= Hdim * NM) return;
    int h = idx >> 5;
    float dt = expf(logdt[h]);
    double dar = (double)dt * (double)Are[idx];
    double dai = (double)dt * (double)Aim[idx];
    double wm = exp(dar);
    double wr = wm * cos(dai), wi = wm * sin(dai);
    wtab[idx] = make_float2((float)wr, (float)wi);
    double pm = exp(dar * (double)PCH);
    double pai = dai * (double)PCH;
    wptab[idx] = make_float2((float)(pm * cos(pai)), (float)(pm * sin(pai)));
    double are = (double)Are[idx], aim = (double)Aim[idx];
    double den = are * are + aim * aim;
    double nr = wr - 1.0, ni = wi;
    double qr = (nr * are + ni * aim) / den;
    double qi = (ni * are - nr * aim) / den;
    for (int ch = 0; ch < 2; ch++) {
        double cr = (double)Cre[ch * Hdim * NM + idx];
        double ci = (double)Cim[ch * Hdim * NM + idx];
        ceff[ch * Hdim * NM + idx] = make_float2((float)(2.0 * (cr * qr - ci * qi)),
                                                 (float)(2.0 * (cr * qi + ci * qr)));
    }
}

// ---------------- weight transpose + bf16 cast ----------------
__global__ void k_wt(const float* __restrict__ W1, const float* __restrict__ W2,
                     const float* __restrict__ W3, unsigned short* __restrict__ W1T,
                     unsigned short* __restrict__ W2T, unsigned short* __restrict__ W3T) {
    int t = blockIdx.x * 256 + threadIdx.x;  // 131072 threads
    int k = t >> 9, n = t & 511;             // W1,W2: [256][512]
    W1T[n * 256 + k] = f2bf(W1[t]);
    W2T[n * 256 + k] = f2bf(W2[t]);
    int k3 = t >> 8, n3 = t & 255;           // W3: [512][256]
    W3T[n3 * 512 + k3] = f2bf(W3[t]);
}

// ---------------- layernorm (fp32 out / bf16 out) ----------------
__global__ void k_ln(const float* __restrict__ x, const float* __restrict__ g,
                     const float* __restrict__ bt, float* __restrict__ out) {
    int row = blockIdx.x * 4 + (threadIdx.x >> 6);
    int lane = threadIdx.x & 63;
    float4 v = ((const float4*)(x + (size_t)row * Hdim))[lane];
    float s = v.x + v.y + v.z + v.w;
    float ss = v.x * v.x + v.y * v.y + v.z * v.z + v.w * v.w;
#pragma unroll
    for (int o = 1; o < 64; o <<= 1) { s += __shfl_xor(s, o, 64); ss += __shfl_xor(ss, o, 64); }
    float mean = s * (1.0f / Hdim);
    float var = ss * (1.0f / Hdim) - mean * mean;
    float rstd = rsqrtf(var + 1e-5f);
    float4 gg = ((const float4*)g)[lane];
    float4 bb = ((const float4*)bt)[lane];
    float4 o;
    o.x = (v.x - mean) * rstd * gg.x + bb.x;
    o.y = (v.y - mean) * rstd * gg.y + bb.y;
    o.z = (v.z - mean) * rstd * gg.z + bb.z;
    o.w = (v.w - mean) * rstd * gg.w + bb.w;
    ((float4*)(out + (size_t)row * Hdim))[lane] = o;
}

__global__ void k_ln_bf(const float* __restrict__ x, const float* __restrict__ g,
                        const float* __restrict__ bt, unsigned short* __restrict__ out) {
    int row = blockIdx.x * 4 + (threadIdx.x >> 6);
    int lane = threadIdx.x & 63;
    float4 v = ((const float4*)(x + (size_t)row * Hdim))[lane];
    float s = v.x + v.y + v.z + v.w;
    float ss = v.x * v.x + v.y * v.y + v.z * v.z + v.w * v.w;
#pragma unroll
    for (int o = 1; o < 64; o <<= 1) { s += __shfl_xor(s, o, 64); ss += __shfl_xor(ss, o, 64); }
    float mean = s * (1.0f / Hdim);
    float var = ss * (1.0f / Hdim) - mean * mean;
    float rstd = rsqrtf(var + 1e-5f);
    float4 gg = ((const float4*)g)[lane];
    float4 bb = ((const float4*)bt)[lane];
    ushort4 o;
    o.x = f2bf((v.x - mean) * rstd * gg.x + bb.x);
    o.y = f2bf((v.y - mean) * rstd * gg.y + bb.y);
    o.z = f2bf((v.z - mean) * rstd * gg.z + bb.z);
    o.w = f2bf((v.w - mean) * rstd * gg.w + bb.w);
    ((ushort4*)(out + (size_t)row * Hdim))[lane] = o;
}

// ---------------- pass A: per-chunk local end-states z (both dirs) ----------------
// fwd (dir0): z = sum_j w^{P-1-j} u[j]   bwd (dir1): z = sum_j w^j u[j]
__global__ void k_passA(const float* __restrict__ U, const float2* __restrict__ wtab,
                        float2* __restrict__ Z) {
    int h = threadIdx.x;
    int b = blockIdx.y;
    int c = blockIdx.x >> 1, dir = blockIdx.x & 1;
    float2 w[NM], s[NM];
#pragma unroll
    for (int n = 0; n < NM; n++) { w[n] = wtab[h * NM + n]; s[n] = make_float2(0.f, 0.f); }
    const float* up = U + ((size_t)b * LL + (size_t)c * PCH) * Hdim + h;
    int off = dir ? (PCH - 1) * Hdim : 0;
    int step = dir ? -Hdim : Hdim;
    for (int j = 0; j < PCH; j++) {
        float u = up[off];
        off += step;
#pragma unroll
        for (int n = 0; n < NM; n++) {
            float sr = fmaf(w[n].x, s[n].x, fmaf(-w[n].y, s[n].y, u));
            float si = fmaf(w[n].y, s[n].x, w[n].x * s[n].y);
            s[n].x = sr; s[n].y = si;
        }
    }
    float2* zp = Z + ((size_t)((dir * NB + b) * Hdim + h) * NCH + c) * NM;
#pragma unroll
    for (int n = 0; n < NM; n++) zp[n] = s[n];
}

// ---------------- prefix over chunks (in place: Z -> incoming state per chunk) ----------------
__global__ void k_prefix(float2* __restrict__ Z, const float2* __restrict__ wptab) {
    int t = blockIdx.x * 256 + threadIdx.x;  // 262144 = 2*16*256*32
    int n = t & 31;
    int h = (t >> 5) & 255;
    int b = (t >> 13) & 15;
    int dir = (t >> 17) & 1;
    float2 wp = wptab[h * NM + n];
    float2* zp = Z + (size_t)((dir * NB + b) * Hdim + h) * (NCH * NM) + n;
    float2 st = make_float2(0.f, 0.f);
    if (dir == 0) {
        for (int c = 0; c < NCH; c++) {
            float2 z = zp[c * NM];
            zp[c * NM] = st;
            float tr = fmaf(wp.x, st.x, fmaf(-wp.y, st.y, z.x));
            float ti = fmaf(wp.y, st.x, fmaf(wp.x, st.y, z.y));
            st = make_float2(tr, ti);
        }
    } else {
        for (int c = NCH - 1; c >= 0; c--) {
            float2 z = zp[c * NM];
            zp[c * NM] = st;
            float tr = fmaf(wp.x, st.x, fmaf(-wp.y, st.y, z.x));
            float ti = fmaf(wp.y, st.x, fmaf(wp.x, st.y, z.y));
            st = make_float2(tr, ti);
        }
    }
}

// ---------------- pass B fwd: y_fwd, seeded with incoming state ----------------
__global__ void k_pbf(const float* __restrict__ U, const float2* __restrict__ wtab,
                      const float2* __restrict__ ce0, const float2* __restrict__ Z,
                      float* __restrict__ YF) {
    int h = threadIdx.x;
    int b = blockIdx.y, c = blockIdx.x;
    float2 w[NM], s[NM], ce[NM];
    const float2* zp = Z + ((size_t)(b * Hdim + h) * NCH + c) * NM;  // dir0
#pragma unroll
    for (int n = 0; n < NM; n++) { w[n] = wtab[h * NM + n]; ce[n] = ce0[h * NM + n]; s[n] = zp[n]; }
    size_t base = ((size_t)b * LL + (size_t)c * PCH) * Hdim + h;
    for (int j = 0; j < PCH; j++) {
        float u = U[base + (size_t)j * Hdim];
        float acc = 0.f;
#pragma unroll
        for (int n = 0; n < NM; n++) {
            float sr = fmaf(w[n].x, s[n].x, fmaf(-w[n].y, s[n].y, u));
            float si = fmaf(w[n].y, s[n].x, w[n].x * s[n].y);
            s[n].x = sr; s[n].y = si;
            acc = fmaf(ce[n].x, sr, acc);
            acc = fmaf(-ce[n].y, si, acc);
        }
        YF[base + (size_t)j * Hdim] = acc;
    }
}

// ---------------- pass B bwd: y = yf + y_bwd + u*D, gelu, -> bf16 ----------------
__global__ void k_pbb(const float* __restrict__ U, const float* __restrict__ YF,
                      const float2* __restrict__ wtab, const float2* __restrict__ ce1,
                      const float2* __restrict__ Z, const float* __restrict__ Dsk,
                      unsigned short* __restrict__ G) {
    int h = threadIdx.x;
    int b = blockIdx.y, c = blockIdx.x;
    float2 w[NM], s[NM], ce[NM];
    const float2* zp = Z + ((size_t)((NB + b) * Hdim + h) * NCH + c) * NM;  // dir1
#pragma unroll
    for (int n = 0; n < NM; n++) { w[n] = wtab[h * NM + n]; ce[n] = ce1[h * NM + n]; s[n] = zp[n]; }
    float dskip = Dsk[h];
    size_t base = ((size_t)b * LL + (size_t)c * PCH) * Hdim + h;
    for (int j = PCH - 1; j >= 0; j--) {
        size_t idx = base + (size_t)j * Hdim;
        float u = U[idx];
        float acc = 0.f;
#pragma unroll
        for (int n = 0; n < NM; n++) {
            acc = fmaf(ce[n].x, s[n].x, acc);
            acc = fmaf(-ce[n].y, s[n].y, acc);
        }
        float tot = YF[idx] + acc + u * dskip;
        G[idx] = f2bf(gelu_f(tot));
#pragma unroll
        for (int n = 0; n < NM; n++) {   // state update AFTER emit (anticausal)
            float sr = fmaf(w[n].x, s[n].x, fmaf(-w[n].y, s[n].y, u));
            float si = fmaf(w[n].y, s[n].x, w[n].x * s[n].y);
            s[n].x = sr; s[n].y = si;
        }
    }
}

// ---------------- GEMM1: zz = G@Wout + bout ; X2 = x + zz[:,:256]*sigmoid(zz[:,256:]) ----------------
__global__ void k_gemm1(const unsigned short* __restrict__ Gm, const unsigned short* __restrict__ W1T,
                        const float* __restrict__ bo, const float* __restrict__ xin,
                        float* __restrict__ X2) {
    int w = threadIdx.x >> 6, lane = threadIdx.x & 63;
    int wr = w & 1, wc = w >> 1;
    int m0 = blockIdx.x * 128 + wr * 64;
    int nb = blockIdx.y * 64 + wc * 32;
    int lr = lane & 15, lk = (lane >> 4) * 8;
    f32x4 acc[4][4];
#pragma unroll
    for (int i = 0; i < 4; i++)
#pragma unroll
        for (int j = 0; j < 4; j++) acc[i][j] = (f32x4){0.f, 0.f, 0.f, 0.f};
    for (int kk = 0; kk < 256; kk += 32) {
        bf16x8 a[4], bA[2], bB[2];
#pragma unroll
        for (int mi = 0; mi < 4; mi++)
            a[mi] = *(const bf16x8*)(Gm + (size_t)(m0 + mi * 16 + lr) * 256 + kk + lk);
#pragma unroll
        for (int nf = 0; nf < 2; nf++) {
            int col = nb + nf * 16 + lr;
            bA[nf] = *(const bf16x8*)(W1T + (size_t)col * 256 + kk + lk);
            bB[nf] = *(const bf16x8*)(W1T + (size_t)(col + 256) * 256 + kk + lk);
        }
#pragma unroll
        for (int mi = 0; mi < 4; mi++)
#pragma unroll
            for (int nf = 0; nf < 2; nf++) {
                acc[mi][nf] = __builtin_amdgcn_mfma_f32_16x16x32_bf16(a[mi], bA[nf], acc[mi][nf], 0, 0, 0);
                acc[mi][nf + 2] = __builtin_amdgcn_mfma_f32_16x16x32_bf16(a[mi], bB[nf], acc[mi][nf + 2], 0, 0, 0);
            }
    }
#pragma unroll
    for (int mi = 0; mi < 4; mi++)
#pragma unroll
        for (int nf = 0; nf < 2; nf++) {
            int col = nb + nf * 16 + lr;
            float biasA = bo[col], biasB = bo[col + 256];
#pragma unroll
            for (int r = 0; r < 4; r++) {
                int row = m0 + mi * 16 + (lane >> 4) * 4 + r;
                float zzA = acc[mi][nf][r] + biasA;
                float zzB = acc[mi][nf + 2][r] + biasB;
                float v = zzA / (1.0f + expf(-zzB));
                size_t idx = (size_t)row * 256 + col;
                X2[idx] = xin[idx] + v;
            }
        }
}

// ---------------- GEMM2: M = gelu(T2@W2 + b2) (bf16 out) ----------------
__global__ void k_gemm2(const unsigned short* __restrict__ T2, const unsigned short* __restrict__ W2T,
                        const float* __restrict__ b2, unsigned short* __restrict__ Mo) {
    int w = threadIdx.x >> 6, lane = threadIdx.x & 63;
    int wr = w & 1, wc = w >> 1;
    int m0 = blockIdx.x * 128 + wr * 64;
    int nb = blockIdx.y * 64 + wc * 32;
    int lr = lane & 15, lk = (lane >> 4) * 8;
    f32x4 acc[4][2];
#pragma unroll
    for (int i = 0; i < 4; i++) { acc[i][0] = (f32x4){0.f,0.f,0.f,0.f}; acc[i][1] = (f32x4){0.f,0.f,0.f,0.f}; }
    for (int kk = 0; kk < 256; kk += 32) {
        bf16x8 a[4], b[2];
#pragma unroll
        for (int mi = 0; mi < 4; mi++)
            a[mi] = *(const bf16x8*)(T2 + (size_t)(m0 + mi * 16 + lr) * 256 + kk + lk);
#pragma unroll
        for (int nf = 0; nf < 2; nf++)
            b[nf] = *(const bf16x8*)(W2T + (size_t)(nb + nf * 16 + lr) * 256 + kk + lk);
#pragma unroll
        for (int mi = 0; mi < 4; mi++)
#pragma unroll
            for (int nf = 0; nf < 2; nf++)
                acc[mi][nf] = __builtin_amdgcn_mfma_f32_16x16x32_bf16(a[mi], b[nf], acc[mi][nf], 0, 0, 0);
    }
#pragma unroll
    for (int mi = 0; mi < 4; mi++)
#pragma unroll
        for (int nf = 0; nf < 2; nf++) {
            int col = nb + nf * 16 + lr;
            float bias = b2[col];
#pragma unroll
            for (int r = 0; r < 4; r++) {
                int row = m0 + mi * 16 + (lane >> 4) * 4 + r;
                Mo[(size_t)row * 512 + col] = f2bf(gelu_f(acc[mi][nf][r] + bias));
            }
        }
}

// ---------------- GEMM3: out = X2 + M@W3 + b3 ----------------
__global__ void k_gemm3(const unsigned short* __restrict__ Mb, const unsigned short* __restrict__ W3T,
                        const float* __restrict__ b3, const float* __restrict__ X2,
                        float* __restrict__ out) {
    int w = threadIdx.x >> 6, lane = threadIdx.x & 63;
    int wr = w & 1, wc = w >> 1;
    int m0 = blockIdx.x * 128 + wr * 64;
    int nb = blockIdx.y * 64 + wc * 32;
    int lr = lane & 15, lk = (lane >> 4) * 8;
    f32x4 acc[4][2];
#pragma unroll
    for (int i = 0; i < 4; i++) { acc[i][0] = (f32x4){0.f,0.f,0.f,0.f}; acc[i][1] = (f32x4){0.f,0.f,0.f,0.f}; }
    for (int kk = 0; kk < 512; kk += 32) {
        bf16x8 a[4], b[2];
#pragma unroll
        for (int mi = 0; mi < 4; mi++)
            a[mi] = *(const bf16x8*)(Mb + (size_t)(m0 + mi * 16 + lr) * 512 + kk + lk);
#pragma unroll
        for (int nf = 0; nf < 2; nf++)
            b[nf] = *(const bf16x8*)(W3T + (size_t)(nb + nf * 16 + lr) * 512 + kk + lk);
#pragma unroll
        for (int mi = 0; mi < 4; mi++)
#pragma unroll
            for (int nf = 0; nf < 2; nf++)
                acc[mi][nf] = __builtin_amdgcn_mfma_f32_16x16x32_bf16(a[mi], b[nf], acc[mi][nf], 0, 0, 0);
    }
#pragma unroll
    for (int mi = 0; mi < 4; mi++)
#pragma unroll
        for (int nf = 0; nf < 2; nf++) {
            int col = nb + nf * 16 + lr;
            float bias = b3[col];
#pragma unroll
            for (int r = 0; r < 4; r++) {
                int row = m0 + mi * 16 + (lane >> 4) * 4 + r;
                size_t idx = (size_t)row * 256 + col;
                out[idx] = X2[idx] + acc[mi][nf][r] + bias;
            }
        }
}

extern "C" void kernel_launch(void* const* d_in, const int* in_sizes, int n_in,
                              void* d_out, int out_size, void* d_ws, size_t ws_size,
                              hipStream_t stream) {
    const float* x     = (const float*)d_in[0];
    const float* ln1g  = (const float*)d_in[1];
    const float* ln1b  = (const float*)d_in[2];
    const float* ln2g  = (const float*)d_in[3];
    const float* ln2b  = (const float*)d_in[4];
    const float* logdt = (const float*)d_in[5];
    const float* Are   = (const float*)d_in[6];
    const float* Aim   = (const float*)d_in[7];
    const float* Cre   = (const float*)d_in[8];
    const float* Cim   = (const float*)d_in[9];
    const float* Dsk   = (const float*)d_in[10];
    const float* Wout  = (const float*)d_in[11];
    const float* bo    = (const float*)d_in[12];
    const float* W2    = (const float*)d_in[13];
    const float* b2    = (const float*)d_in[14];
    const float* W3    = (const float*)d_in[15];
    const float* b3    = (const float*)d_in[16];

    char* ws = (char*)d_ws;
    float*          U    = (float*)(ws + OFF_U);      // later X2
    float2*         Z    = (float2*)(ws + OFF_Z);
    float*          YF   = (float*)(ws + OFF_YF);     // later M (bf16)
    unsigned short* G    = (unsigned short*)(ws + OFF_G);  // later T2
    float2*         WT   = (float2*)(ws + OFF_WTAB);
    float2*         WP   = (float2*)(ws + OFF_WP);
    float2*         CE   = (float2*)(ws + OFF_CE);
    unsigned short* W1T  = (unsigned short*)(ws + OFF_W1T);
    unsigned short* W2T  = (unsigned short*)(ws + OFF_W2T);
    unsigned short* W3T  = (unsigned short*)(ws + OFF_W3T);
    float*          X2   = U;
    unsigned short* T2   = G;
    unsigned short* Mb   = (unsigned short*)YF;

    k_tab<<<32, 256, 0, stream>>>(logdt, Are, Aim, Cre, Cim, WT, WP, CE);
    k_wt<<<512, 256, 0, stream>>>(Wout, W2, W3, W1T, W2T, W3T);
    k_ln<<<NB * LL / 4, 256, 0, stream>>>(x, ln1g, ln1b, U);
    k_passA<<<dim3(NCH * 2, NB), 256, 0, stream>>>(U, WT, Z);
    k_prefix<<<1024, 256, 0, stream>>>(Z, WP);
    k_pbf<<<dim3(NCH, NB), 256, 0, stream>>>(U, WT, CE, Z, YF);
    k_pbb<<<dim3(NCH, NB), 256, 0, stream>>>(U, YF, WT, CE + Hdim * NM, Z, Dsk, G);
    k_gemm1<<<dim3(512, 4), 256, 0, stream>>>(G, W1T, bo, x, X2);
    k_ln_bf<<<NB * LL / 4, 256, 0, stream>>>(X2, ln2g, ln2b, T2);
    k_gemm2<<<dim3(512, 8), 256, 0, stream>>>(T2, W2T, b2, Mb);
    k_gemm3<<<dim3(512, 4), 256, 0, stream>>>(Mb, W3T, b3, X2, (float*)d_out);
}

// Round 2
// 822.124 us; speedup vs baseline: 8.3164x; 8.3164x over previous
//
#include <hip/hip_runtime.h>
#include <hip/hip_bf16.h>

typedef __attribute__((ext_vector_type(8))) short bf16x8;
typedef __attribute__((ext_vector_type(4))) float f32x4;

#define Hdim 256
#define NM 32      // N2 modes
#define NMT 8      // modes per thread (mode-split 4)
#define NB 16      // batch
#define LL 4096    // seq len
#define PCH 256    // chunk length
#define NCH 16     // chunks = LL/PCH

// workspace offsets (bytes); total 202,375,168 B
#define OFF_U    ((size_t)0)            // U fp32 (B,L,H) 67,108,864 ; reused as X2
#define OFF_Z    ((size_t)67108864)     // Z states float2 [dir][b][h][c][n] 33,554,432
#define OFF_YF   ((size_t)100663296)    // YF fp32 (B,L,H) 67,108,864 ; reused as M (bf16)
#define OFF_G    ((size_t)167772160)    // G bf16 (B,L,H) 33,554,432 ; reused as T2 (bf16)
#define OFF_WTAB ((size_t)201326592)    // w   float2 [H][N2] 65,536
#define OFF_WP   ((size_t)201392128)    // w^P float2 [H][N2] 65,536
#define OFF_CE   ((size_t)201457664)    // Ceff float2 [2][H][N2] 131,072
#define OFF_W1T  ((size_t)201588736)    // Wout^T bf16 [512][256] 262,144
#define OFF_W2T  ((size_t)201850880)    // W2^T   bf16 [512][256] 262,144
#define OFF_W3T  ((size_t)202113024)    // W3^T   bf16 [256][512] 262,144

__device__ __forceinline__ float gelu_f(float v) {
    return 0.5f * v * (1.0f + erff(v * 0.70710678118654752f));
}
__device__ __forceinline__ unsigned short f2bf(float f) {  // RNE f32->bf16
    unsigned int u = __float_as_uint(f);
    u += 0x7fffu + ((u >> 16) & 1u);
    return (unsigned short)(u >> 16);
}

// ---------------- tables: w = exp(dt*A), w^P, Ceff = 2*C*(w-1)/A ----------------
__global__ void k_tab(const float* __restrict__ logdt, const float* __restrict__ Are,
                      const float* __restrict__ Aim, const float* __restrict__ Cre,
                      const float* __restrict__ Cim, float2* __restrict__ wtab,
                      float2* __restrict__ wptab, float2* __restrict__ ceff) {
    int idx = blockIdx.x * blockDim.x + threadIdx.x;
    if (idx >= Hdim * NM) return;
    int h = idx >> 5;
    float dt = expf(logdt[h]);
    double dar = (double)dt * (double)Are[idx];
    double dai = (double)dt * (double)Aim[idx];
    double wm = exp(dar);
    double wr = wm * cos(dai), wi = wm * sin(dai);
    wtab[idx] = make_float2((float)wr, (float)wi);
    double pm = exp(dar * (double)PCH);
    double pai = dai * (double)PCH;
    wptab[idx] = make_float2((float)(pm * cos(pai)), (float)(pm * sin(pai)));
    double are = (double)Are[idx], aim = (double)Aim[idx];
    double den = are * are + aim * aim;
    double nr = wr - 1.0, ni = wi;
    double qr = (nr * are + ni * aim) / den;
    double qi = (ni * are - nr * aim) / den;
    for (int ch = 0; ch < 2; ch++) {
        double cr = (double)Cre[ch * Hdim * NM + idx];
        double ci = (double)Cim[ch * Hdim * NM + idx];
        ceff[ch * Hdim * NM + idx] = make_float2((float)(2.0 * (cr * qr - ci * qi)),
                                                 (float)(2.0 * (cr * qi + ci * qr)));
    }
}

// ---------------- weight transpose + bf16 cast ----------------
__global__ void k_wt(const float* __restrict__ W1, const float* __restrict__ W2,
                     const float* __restrict__ W3, unsigned short* __restrict__ W1T,
                     unsigned short* __restrict__ W2T, unsigned short* __restrict__ W3T) {
    int t = blockIdx.x * 256 + threadIdx.x;  // 131072 threads
    int k = t >> 9, n = t & 511;             // W1,W2: [256][512]
    W1T[n * 256 + k] = f2bf(W1[t]);
    W2T[n * 256 + k] = f2bf(W2[t]);
    int k3 = t >> 8, n3 = t & 255;           // W3: [512][256]
    W3T[n3 * 512 + k3] = f2bf(W3[t]);
}

// ---------------- layernorm (fp32 out / bf16 out) ----------------
__global__ void k_ln(const float* __restrict__ x, const float* __restrict__ g,
                     const float* __restrict__ bt, float* __restrict__ out) {
    int row = blockIdx.x * 4 + (threadIdx.x >> 6);
    int lane = threadIdx.x & 63;
    float4 v = ((const float4*)(x + (size_t)row * Hdim))[lane];
    float s = v.x + v.y + v.z + v.w;
    float ss = v.x * v.x + v.y * v.y + v.z * v.z + v.w * v.w;
#pragma unroll
    for (int o = 1; o < 64; o <<= 1) { s += __shfl_xor(s, o, 64); ss += __shfl_xor(ss, o, 64); }
    float mean = s * (1.0f / Hdim);
    float var = ss * (1.0f / Hdim) - mean * mean;
    float rstd = rsqrtf(var + 1e-5f);
    float4 gg = ((const float4*)g)[lane];
    float4 bb = ((const float4*)bt)[lane];
    float4 o;
    o.x = (v.x - mean) * rstd * gg.x + bb.x;
    o.y = (v.y - mean) * rstd * gg.y + bb.y;
    o.z = (v.z - mean) * rstd * gg.z + bb.z;
    o.w = (v.w - mean) * rstd * gg.w + bb.w;
    ((float4*)(out + (size_t)row * Hdim))[lane] = o;
}

__global__ void k_ln_bf(const float* __restrict__ x, const float* __restrict__ g,
                        const float* __restrict__ bt, unsigned short* __restrict__ out) {
    int row = blockIdx.x * 4 + (threadIdx.x >> 6);
    int lane = threadIdx.x & 63;
    float4 v = ((const float4*)(x + (size_t)row * Hdim))[lane];
    float s = v.x + v.y + v.z + v.w;
    float ss = v.x * v.x + v.y * v.y + v.z * v.z + v.w * v.w;
#pragma unroll
    for (int o = 1; o < 64; o <<= 1) { s += __shfl_xor(s, o, 64); ss += __shfl_xor(ss, o, 64); }
    float mean = s * (1.0f / Hdim);
    float var = ss * (1.0f / Hdim) - mean * mean;
    float rstd = rsqrtf(var + 1e-5f);
    float4 gg = ((const float4*)g)[lane];
    float4 bb = ((const float4*)bt)[lane];
    ushort4 o;
    o.x = f2bf((v.x - mean) * rstd * gg.x + bb.x);
    o.y = f2bf((v.y - mean) * rstd * gg.y + bb.y);
    o.z = f2bf((v.z - mean) * rstd * gg.z + bb.z);
    o.w = f2bf((v.w - mean) * rstd * gg.w + bb.w);
    ((ushort4*)(out + (size_t)row * Hdim))[lane] = o;
}

// ---------------- pass A: per-chunk local end-states z (both dirs) ----------------
// mode-split: 4 lanes per h, NMT=8 modes each. fwd: z=sum w^{P-1-j}u[j]; bwd: z=sum w^j u[j]
__global__ __launch_bounds__(256, 4) void k_passA(const float* __restrict__ U,
                                                  const float2* __restrict__ wtab,
                                                  float2* __restrict__ Z) {
    int sub = threadIdx.x & 3, hl = threadIdx.x >> 2;
    int h = blockIdx.z * 64 + hl;
    int b = blockIdx.y;
    int c = blockIdx.x >> 1, dir = blockIdx.x & 1;
    int n0 = sub * NMT;
    float2 w[NMT], s[NMT];
#pragma unroll
    for (int n = 0; n < NMT; n++) { w[n] = wtab[h * NM + n0 + n]; s[n] = make_float2(0.f, 0.f); }
    const float* up = U + ((size_t)b * LL + (size_t)c * PCH) * Hdim + h;
    int off = dir ? (PCH - 1) * Hdim : 0;
    int step = dir ? -Hdim : Hdim;
    for (int j = 0; j < PCH; j++) {
        float u = up[off];
        off += step;
#pragma unroll
        for (int n = 0; n < NMT; n++) {
            float sr = fmaf(w[n].x, s[n].x, fmaf(-w[n].y, s[n].y, u));
            float si = fmaf(w[n].y, s[n].x, w[n].x * s[n].y);
            s[n].x = sr; s[n].y = si;
        }
    }
    float2* zp = Z + ((size_t)((dir * NB + b) * Hdim + h) * NCH + c) * NM + n0;
#pragma unroll
    for (int n = 0; n < NMT; n++) zp[n] = s[n];
}

// ---------------- prefix over chunks (in place: Z -> incoming state per chunk) ----------------
__global__ void k_prefix(float2* __restrict__ Z, const float2* __restrict__ wptab) {
    int t = blockIdx.x * 256 + threadIdx.x;  // 262144 = 2*16*256*32
    int n = t & 31;
    int h = (t >> 5) & 255;
    int b = (t >> 13) & 15;
    int dir = (t >> 17) & 1;
    float2 wp = wptab[h * NM + n];
    float2* zp = Z + (size_t)((dir * NB + b) * Hdim + h) * (NCH * NM) + n;
    float2 st = make_float2(0.f, 0.f);
    if (dir == 0) {
        for (int c = 0; c < NCH; c++) {
            float2 z = zp[c * NM];
            zp[c * NM] = st;
            float tr = fmaf(wp.x, st.x, fmaf(-wp.y, st.y, z.x));
            float ti = fmaf(wp.y, st.x, fmaf(wp.x, st.y, z.y));
            st = make_float2(tr, ti);
        }
    } else {
        for (int c = NCH - 1; c >= 0; c--) {
            float2 z = zp[c * NM];
            zp[c * NM] = st;
            float tr = fmaf(wp.x, st.x, fmaf(-wp.y, st.y, z.x));
            float ti = fmaf(wp.y, st.x, fmaf(wp.x, st.y, z.y));
            st = make_float2(tr, ti);
        }
    }
}

// ---------------- pass B fwd: y_fwd, seeded with incoming state ----------------
__global__ __launch_bounds__(256, 4) void k_pbf(const float* __restrict__ U,
                                                const float2* __restrict__ wtab,
                                                const float2* __restrict__ ce0,
                                                const float2* __restrict__ Z,
                                                float* __restrict__ YF) {
    int sub = threadIdx.x & 3, hl = threadIdx.x >> 2;
    int h = blockIdx.z * 64 + hl;
    int b = blockIdx.y, c = blockIdx.x;
    int n0 = sub * NMT;
    float2 w[NMT], s[NMT], ce[NMT];
    const float2* zp = Z + ((size_t)(b * Hdim + h) * NCH + c) * NM + n0;  // dir0
#pragma unroll
    for (int n = 0; n < NMT; n++) {
        w[n] = wtab[h * NM + n0 + n]; ce[n] = ce0[h * NM + n0 + n]; s[n] = zp[n];
    }
    size_t base = ((size_t)b * LL + (size_t)c * PCH) * Hdim + h;
    for (int j = 0; j < PCH; j++) {
        float u = U[base + (size_t)j * Hdim];
        float acc = 0.f;
#pragma unroll
        for (int n = 0; n < NMT; n++) {
            float sr = fmaf(w[n].x, s[n].x, fmaf(-w[n].y, s[n].y, u));
            float si = fmaf(w[n].y, s[n].x, w[n].x * s[n].y);
            s[n].x = sr; s[n].y = si;
            acc = fmaf(ce[n].x, sr, acc);
            acc = fmaf(-ce[n].y, si, acc);
        }
        acc += __shfl_xor(acc, 1, 64);
        acc += __shfl_xor(acc, 2, 64);
        if (sub == 0) YF[base + (size_t)j * Hdim] = acc;
    }
}

// ---------------- pass B bwd: y = yf + y_bwd + u*D, gelu, -> bf16 ----------------
__global__ __launch_bounds__(256, 4) void k_pbb(const float* __restrict__ U,
                                                const float* __restrict__ YF,
                                                const float2* __restrict__ wtab,
                                                const float2* __restrict__ ce1,
                                                const float2* __restrict__ Z,
                                                const float* __restrict__ Dsk,
                                                unsigned short* __restrict__ G) {
    int sub = threadIdx.x & 3, hl = threadIdx.x >> 2;
    int h = blockIdx.z * 64 + hl;
    int b = blockIdx.y, c = blockIdx.x;
    int n0 = sub * NMT;
    float2 w[NMT], s[NMT], ce[NMT];
    const float2* zp = Z + ((size_t)((NB + b) * Hdim + h) * NCH + c) * NM + n0;  // dir1
#pragma unroll
    for (int n = 0; n < NMT; n++) {
        w[n] = wtab[h * NM + n0 + n]; ce[n] = ce1[h * NM + n0 + n]; s[n] = zp[n];
    }
    float dskip = Dsk[h];
    size_t base = ((size_t)b * LL + (size_t)c * PCH) * Hdim + h;
    for (int j = PCH - 1; j >= 0; j--) {
        size_t idx = base + (size_t)j * Hdim;
        float u = U[idx];
        float acc = 0.f;
#pragma unroll
        for (int n = 0; n < NMT; n++) {
            acc = fmaf(ce[n].x, s[n].x, acc);
            acc = fmaf(-ce[n].y, s[n].y, acc);
        }
        acc += __shfl_xor(acc, 1, 64);
        acc += __shfl_xor(acc, 2, 64);
        if (sub == 0) {
            float tot = YF[idx] + acc + u * dskip;
            G[idx] = f2bf(gelu_f(tot));
        }
#pragma unroll
        for (int n = 0; n < NMT; n++) {   // state update AFTER emit (anticausal)
            float sr = fmaf(w[n].x, s[n].x, fmaf(-w[n].y, s[n].y, u));
            float si = fmaf(w[n].y, s[n].x, w[n].x * s[n].y);
            s[n].x = sr; s[n].y = si;
        }
    }
}

// ---------------- GEMM1: zz = G@Wout + bout ; X2 = x + zz[:,:256]*sigmoid(zz[:,256:]) ----------------
__global__ void k_gemm1(const unsigned short* __restrict__ Gm, const unsigned short* __restrict__ W1T,
                        const float* __restrict__ bo, const float* __restrict__ xin,
                        float* __restrict__ X2) {
    int w = threadIdx.x >> 6, lane = threadIdx.x & 63;
    int wr = w & 1, wc = w >> 1;
    int m0 = blockIdx.x * 128 + wr * 64;
    int nb = blockIdx.y * 64 + wc * 32;
    int lr = lane & 15, lk = (lane >> 4) * 8;
    f32x4 acc[4][4];
#pragma unroll
    for (int i = 0; i < 4; i++)
#pragma unroll
        for (int j = 0; j < 4; j++) acc[i][j] = (f32x4){0.f, 0.f, 0.f, 0.f};
    for (int kk = 0; kk < 256; kk += 32) {
        bf16x8 a[4], bA[2], bB[2];
#pragma unroll
        for (int mi = 0; mi < 4; mi++)
            a[mi] = *(const bf16x8*)(Gm + (size_t)(m0 + mi * 16 + lr) * 256 + kk + lk);
#pragma unroll
        for (int nf = 0; nf < 2; nf++) {
            int col = nb + nf * 16 + lr;
            bA[nf] = *(const bf16x8*)(W1T + (size_t)col * 256 + kk + lk);
            bB[nf] = *(const bf16x8*)(W1T + (size_t)(col + 256) * 256 + kk + lk);
        }
#pragma unroll
        for (int mi = 0; mi < 4; mi++)
#pragma unroll
            for (int nf = 0; nf < 2; nf++) {
                acc[mi][nf] = __builtin_amdgcn_mfma_f32_16x16x32_bf16(a[mi], bA[nf], acc[mi][nf], 0, 0, 0);
                acc[mi][nf + 2] = __builtin_amdgcn_mfma_f32_16x16x32_bf16(a[mi], bB[nf], acc[mi][nf + 2], 0, 0, 0);
            }
    }
#pragma unroll
    for (int mi = 0; mi < 4; mi++)
#pragma unroll
        for (int nf = 0; nf < 2; nf++) {
            int col = nb + nf * 16 + lr;
            float biasA = bo[col], biasB = bo[col + 256];
#pragma unroll
            for (int r = 0; r < 4; r++) {
                int row = m0 + mi * 16 + (lane >> 4) * 4 + r;
                float zzA = acc[mi][nf][r] + biasA;
                float zzB = acc[mi][nf + 2][r] + biasB;
                float v = zzA / (1.0f + expf(-zzB));
                size_t idx = (size_t)row * 256 + col;
                X2[idx] = xin[idx] + v;
            }
        }
}

// ---------------- GEMM2: M = gelu(T2@W2 + b2) (bf16 out) ----------------
__global__ void k_gemm2(const unsigned short* __restrict__ T2, const unsigned short* __restrict__ W2T,
                        const float* __restrict__ b2, unsigned short* __restrict__ Mo) {
    int w = threadIdx.x >> 6, lane = threadIdx.x & 63;
    int wr = w & 1, wc = w >> 1;
    int m0 = blockIdx.x * 128 + wr * 64;
    int nb = blockIdx.y * 64 + wc * 32;
    int lr = lane & 15, lk = (lane >> 4) * 8;
    f32x4 acc[4][2];
#pragma unroll
    for (int i = 0; i < 4; i++) { acc[i][0] = (f32x4){0.f,0.f,0.f,0.f}; acc[i][1] = (f32x4){0.f,0.f,0.f,0.f}; }
    for (int kk = 0; kk < 256; kk += 32) {
        bf16x8 a[4], b[2];
#pragma unroll
        for (int mi = 0; mi < 4; mi++)
            a[mi] = *(const bf16x8*)(T2 + (size_t)(m0 + mi * 16 + lr) * 256 + kk + lk);
#pragma unroll
        for (int nf = 0; nf < 2; nf++)
            b[nf] = *(const bf16x8*)(W2T + (size_t)(nb + nf * 16 + lr) * 256 + kk + lk);
#pragma unroll
        for (int mi = 0; mi < 4; mi++)
#pragma unroll
            for (int nf = 0; nf < 2; nf++)
                acc[mi][nf] = __builtin_amdgcn_mfma_f32_16x16x32_bf16(a[mi], b[nf], acc[mi][nf], 0, 0, 0);
    }
#pragma unroll
    for (int mi = 0; mi < 4; mi++)
#pragma unroll
        for (int nf = 0; nf < 2; nf++) {
            int col = nb + nf * 16 + lr;
            float bias = b2[col];
#pragma unroll
            for (int r = 0; r < 4; r++) {
                int row = m0 + mi * 16 + (lane >> 4) * 4 + r;
                Mo[(size_t)row * 512 + col] = f2bf(gelu_f(acc[mi][nf][r] + bias));
            }
        }
}

// ---------------- GEMM3: out = X2 + M@W3 + b3 ----------------
__global__ void k_gemm3(const unsigned short* __restrict__ Mb, const unsigned short* __restrict__ W3T,
                        const float* __restrict__ b3, const float* __restrict__ X2,
                        float* __restrict__ out) {
    int w = threadIdx.x >> 6, lane = threadIdx.x & 63;
    int wr = w & 1, wc = w >> 1;
    int m0 = blockIdx.x * 128 + wr * 64;
    int nb = blockIdx.y * 64 + wc * 32;
    int lr = lane & 15, lk = (lane >> 4) * 8;
    f32x4 acc[4][2];
#pragma unroll
    for (int i = 0; i < 4; i++) { acc[i][0] = (f32x4){0.f,0.f,0.f,0.f}; acc[i][1] = (f32x4){0.f,0.f,0.f,0.f}; }
    for (int kk = 0; kk < 512; kk += 32) {
        bf16x8 a[4], b[2];
#pragma unroll
        for (int mi = 0; mi < 4; mi++)
            a[mi] = *(const bf16x8*)(Mb + (size_t)(m0 + mi * 16 + lr) * 512 + kk + lk);
#pragma unroll
        for (int nf = 0; nf < 2; nf++)
            b[nf] = *(const bf16x8*)(W3T + (size_t)(nb + nf * 16 + lr) * 512 + kk + lk);
#pragma unroll
        for (int mi = 0; mi < 4; mi++)
#pragma unroll
            for (int nf = 0; nf < 2; nf++)
                acc[mi][nf] = __builtin_amdgcn_mfma_f32_16x16x32_bf16(a[mi], b[nf], acc[mi][nf], 0, 0, 0);
    }
#pragma unroll
    for (int mi = 0; mi < 4; mi++)
#pragma unroll
        for (int nf = 0; nf < 2; nf++) {
            int col = nb + nf * 16 + lr;
            float bias = b3[col];
#pragma unroll
            for (int r = 0; r < 4; r++) {
                int row = m0 + mi * 16 + (lane >> 4) * 4 + r;
                size_t idx = (size_t)row * 256 + col;
                out[idx] = X2[idx] + acc[mi][nf][r] + bias;
            }
        }
}

extern "C" void kernel_launch(void* const* d_in, const int* in_sizes, int n_in,
                              void* d_out, int out_size, void* d_ws, size_t ws_size,
                              hipStream_t stream) {
    const float* x     = (const float*)d_in[0];
    const float* ln1g  = (const float*)d_in[1];
    const float* ln1b  = (const float*)d_in[2];
    const float* ln2g  = (const float*)d_in[3];
    const float* ln2b  = (const float*)d_in[4];
    const float* logdt = (const float*)d_in[5];
    const float* Are   = (const float*)d_in[6];
    const float* Aim   = (const float*)d_in[7];
    const float* Cre   = (const float*)d_in[8];
    const float* Cim   = (const float*)d_in[9];
    const float* Dsk   = (const float*)d_in[10];
    const float* Wout  = (const float*)d_in[11];
    const float* bo    = (const float*)d_in[12];
    const float* W2    = (const float*)d_in[13];
    const float* b2    = (const float*)d_in[14];
    const float* W3    = (const float*)d_in[15];
    const float* b3    = (const float*)d_in[16];

    char* ws = (char*)d_ws;
    float*          U    = (float*)(ws + OFF_U);      // later X2
    float2*         Z    = (float2*)(ws + OFF_Z);
    float*          YF   = (float*)(ws + OFF_YF);     // later M (bf16)
    unsigned short* G    = (unsigned short*)(ws + OFF_G);  // later T2
    float2*         WT   = (float2*)(ws + OFF_WTAB);
    float2*         WP   = (float2*)(ws + OFF_WP);
    float2*         CE   = (float2*)(ws + OFF_CE);
    unsigned short* W1T  = (unsigned short*)(ws + OFF_W1T);
    unsigned short* W2T  = (unsigned short*)(ws + OFF_W2T);
    unsigned short* W3T  = (unsigned short*)(ws + OFF_W3T);
    float*          X2   = U;
    unsigned short* T2   = G;
    unsigned short* Mb   = (unsigned short*)YF;

    k_tab<<<32, 256, 0, stream>>>(logdt, Are, Aim, Cre, Cim, WT, WP, CE);
    k_wt<<<512, 256, 0, stream>>>(Wout, W2, W3, W1T, W2T, W3T);
    k_ln<<<NB * LL / 4, 256, 0, stream>>>(x, ln1g, ln1b, U);
    k_passA<<<dim3(NCH * 2, NB, 4), 256, 0, stream>>>(U, WT, Z);
    k_prefix<<<1024, 256, 0, stream>>>(Z, WP);
    k_pbf<<<dim3(NCH, NB, 4), 256, 0, stream>>>(U, WT, CE, Z, YF);
    k_pbb<<<dim3(NCH, NB, 4), 256, 0, stream>>>(U, YF, WT, CE + Hdim * NM, Z, Dsk, G);
    k_gemm1<<<dim3(512, 4), 256, 0, stream>>>(G, W1T, bo, x, X2);
    k_ln_bf<<<NB * LL / 4, 256, 0, stream>>>(X2, ln2g, ln2b, T2);
    k_gemm2<<<dim3(512, 8), 256, 0, stream>>>(T2, W2T, b2, Mb);
    k_gemm3<<<dim3(512, 4), 256, 0, stream>>>(Mb, W3T, b3, X2, (float*)d_out);
}

// Round 3
// 554.767 us; speedup vs baseline: 12.3243x; 1.4819x over previous
//
#include <hip/hip_runtime.h>
#include <hip/hip_bf16.h>

typedef __attribute__((ext_vector_type(8))) short bf16x8;
typedef __attribute__((ext_vector_type(4))) float f32x4;

#define Hdim 256
#define NM 32      // N2 modes
#define NB 16      // batch
#define LL 4096    // seq len
#define PCH 256    // chunk length
#define NCH 16     // chunks = LL/PCH
#define KBIG 384   // conv GEMM K: 256 u + 64 zf + 64 zb

// ---- workspace layout (bytes), total 186,122,240 ----
// region0 [0,67108864): U fp32 -> (Abig bf16 50331648 @0 | Wp bf16 16777216 @50331648) -> X2 fp32
#define OFF_ABIG ((size_t)0)
#define OFF_WPM  ((size_t)50331648)
#define OFF_UT   ((size_t)67108864)    // U_T bf16 [B][H][L] 33554432 (dead after conv)
#define OFF_ZG   ((size_t)100663296)   // Zg fp32 [h][bc][128] 33554432 ; then Yt bf16 [h][bc][j]
#define OFF_M    ((size_t)67108864)    // M bf16 67108864 (spans UT+ZG, alive gemm2->gemm3)
#define OFF_ZP   ((size_t)134217728)   // Zpacked bf16 [h][bc][128] 16777216
#define OFF_G    ((size_t)150994944)   // G bf16 (b,l,h) 33554432 ; reused as T2
#define OFF_KF   ((size_t)184549376)   // Kf fp32 [H][P] 262144
#define OFF_KB   ((size_t)184811520)   // Kb fp32 [H][P] 262144
#define OFF_WTAB ((size_t)185073664)   // w float2 [H][N2] 65536
#define OFF_WPT  ((size_t)185139200)   // w^P float2 [H][N2] 65536
#define OFF_CE   ((size_t)185204736)   // Ceff float2 [2][H][N2] 131072
#define OFF_W1T  ((size_t)185335808)
#define OFF_W2T  ((size_t)185597952)
#define OFF_W3T  ((size_t)185860096)

__device__ __forceinline__ float gelu_f(float v) {
    return 0.5f * v * (1.0f + erff(v * 0.70710678118654752f));
}
__device__ __forceinline__ unsigned short f2bf(float f) {  // RNE f32->bf16
    unsigned int u = __float_as_uint(f);
    u += 0x7fffu + ((u >> 16) & 1u);
    return (unsigned short)(u >> 16);
}

// ---------------- tables: w = exp(dt*A), w^P, Ceff = 2*C*(w-1)/A (x2 applied later) ----------------
__global__ void k_tab(const float* __restrict__ logdt, const float* __restrict__ Are,
                      const float* __restrict__ Aim, const float* __restrict__ Cre,
                      const float* __restrict__ Cim, float2* __restrict__ wtab,
                      float2* __restrict__ wptab, float2* __restrict__ ceff) {
    int idx = blockIdx.x * blockDim.x + threadIdx.x;
    if (idx >= Hdim * NM) return;
    int h = idx >> 5;
    float dt = expf(logdt[h]);
    double dar = (double)dt * (double)Are[idx];
    double dai = (double)dt * (double)Aim[idx];
    double wm = exp(dar);
    double wr = wm * cos(dai), wi = wm * sin(dai);
    wtab[idx] = make_float2((float)wr, (float)wi);
    double pm = exp(dar * (double)PCH);
    double pai = dai * (double)PCH;
    wptab[idx] = make_float2((float)(pm * cos(pai)), (float)(pm * sin(pai)));
    double are = (double)Are[idx], aim = (double)Aim[idx];
    double den = are * are + aim * aim;
    double nr = wr - 1.0, ni = wi;
    double qr = (nr * are + ni * aim) / den;
    double qi = (ni * are - nr * aim) / den;
    for (int ch = 0; ch < 2; ch++) {
        double cr = (double)Cre[ch * Hdim * NM + idx];
        double ci = (double)Cim[ch * Hdim * NM + idx];
        ceff[ch * Hdim * NM + idx] = make_float2((float)(cr * qr - ci * qi),
                                                 (float)(cr * qi + ci * qr));
    }
}

// ---------------- weight transpose + bf16 cast ----------------
__global__ void k_wt(const float* __restrict__ W1, const float* __restrict__ W2,
                     const float* __restrict__ W3, unsigned short* __restrict__ W1T,
                     unsigned short* __restrict__ W2T, unsigned short* __restrict__ W3T) {
    int t = blockIdx.x * 256 + threadIdx.x;  // 131072 threads
    int k = t >> 9, n = t & 511;             // W1,W2: [256][512]
    W1T[n * 256 + k] = f2bf(W1[t]);
    W2T[n * 256 + k] = f2bf(W2[t]);
    int k3 = t >> 8, n3 = t & 255;           // W3: [512][256]
    W3T[n3 * 512 + k3] = f2bf(W3[t]);
}

// ---------------- conv kernels kf[d]=2Re(Cf w^d), kb[d]=2Re(Cb w^d) ----------------
__global__ void k_kern(const float* __restrict__ logdt, const float* __restrict__ Are,
                       const float* __restrict__ Aim, const float2* __restrict__ CE,
                       float* __restrict__ Kf, float* __restrict__ Kb) {
    int t = blockIdx.x * 256 + threadIdx.x;  // 65536
    int h = t >> 8, d = t & 255;
    float dt = expf(logdt[h]);
    float kf = 0.f, kb = 0.f;
    for (int n = 0; n < NM; n++) {
        float dar = dt * Are[h * NM + n], dai = dt * Aim[h * NM + n];
        float m = expf((float)d * dar), ang = (float)d * dai;
        float wr = m * cosf(ang), wi = m * sinf(ang);
        float2 cf = CE[h * NM + n], cb = CE[Hdim * NM + h * NM + n];
        kf = fmaf(cf.x, wr, fmaf(-cf.y, wi, kf));
        kb = fmaf(cb.x, wr, fmaf(-cb.y, wi, kb));
    }
    Kf[t] = 2.f * kf;
    Kb[t] = 2.f * kb;
}

// ---------------- Abig[h][j][384]: dense conv row + Qf + Qb ----------------
__global__ void k_abuild(const float* __restrict__ Kf, const float* __restrict__ Kb,
                         const float* __restrict__ logdt, const float* __restrict__ Are,
                         const float* __restrict__ Aim, const float2* __restrict__ CE,
                         const float* __restrict__ Dsk, unsigned short* __restrict__ AB) {
    int t = blockIdx.x * 256 + threadIdx.x;  // 65536
    int h = t >> 8, j = t & 255;
    const float* kfr = Kf + h * 256;
    const float* kbr = Kb + h * 256;
    unsigned short* out = AB + (size_t)t * KBIG;
    float dsk = Dsk[h];
    for (int i = 0; i < 256; i++) {
        float v = (i <= j) ? kfr[j - i] : kbr[i - j - 1];
        if (i == j) v += dsk;
        out[i] = f2bf(v);
    }
    float dt = expf(logdt[h]);
    for (int n = 0; n < NM; n++) {
        float dar = dt * Are[h * NM + n], dai = dt * Aim[h * NM + n];
        float2 cf = CE[h * NM + n], cb = CE[Hdim * NM + h * NM + n];
        // Qf: coeff of zf_in -> 2*Re(Cf w^{j+1} z)
        float e1 = expf((float)(j + 1) * dar), a1 = (float)(j + 1) * dai;
        float wr1 = e1 * cosf(a1), wi1 = e1 * sinf(a1);
        float qfr = cf.x * wr1 - cf.y * wi1;
        float qfi = cf.x * wi1 + cf.y * wr1;
        out[256 + 2 * n] = f2bf(2.f * qfr);
        out[256 + 2 * n + 1] = f2bf(-2.f * qfi);
        // Qb: 2*Re(Cb w^{P-1-j} z)
        float p = (float)(PCH - 1 - j);
        float e2 = expf(p * dar), a2 = p * dai;
        float wr2 = e2 * cosf(a2), wi2 = e2 * sinf(a2);
        float qbr = cb.x * wr2 - cb.y * wi2;
        float qbi = cb.x * wi2 + cb.y * wr2;
        out[320 + 2 * n] = f2bf(2.f * qbr);
        out[320 + 2 * n + 1] = f2bf(-2.f * qbi);
    }
}

// ---------------- Wp[h][128][256]: state-GEMM matrix (rows: fwd 2n/2n+1 = Re/Im w^{P-1-i}, 64+: bwd w^i) ----------------
__global__ void k_wp(const float2* __restrict__ wtab, unsigned short* __restrict__ Wp) {
    int h = blockIdx.x;
    int r = threadIdx.x;         // 128
    int n = (r & 63) >> 1, reim = r & 1, dir = r >> 6;
    float2 w = wtab[h * NM + n];
    unsigned short* out = Wp + ((size_t)h * 128 + r) * 256;
    float vr = 1.f, vi = 0.f;
    if (dir == 0) {
        for (int k = 0; k < 256; k++) {
            out[255 - k] = f2bf(reim ? vi : vr);
            float nr = vr * w.x - vi * w.y;
            float ni = vr * w.y + vi * w.x;
            vr = nr; vi = ni;
        }
    } else {
        for (int i = 0; i < 256; i++) {
            out[i] = f2bf(reim ? vi : vr);
            float nr = vr * w.x - vi * w.y;
            float ni = vr * w.y + vi * w.x;
            vr = nr; vi = ni;
        }
    }
}

// ---------------- layernorm fp32 out ----------------
__global__ void k_ln(const float* __restrict__ x, const float* __restrict__ g,
                     const float* __restrict__ bt, float* __restrict__ out) {
    int row = blockIdx.x * 4 + (threadIdx.x >> 6);
    int lane = threadIdx.x & 63;
    float4 v = ((const float4*)(x + (size_t)row * Hdim))[lane];
    float s = v.x + v.y + v.z + v.w;
    float ss = v.x * v.x + v.y * v.y + v.z * v.z + v.w * v.w;
#pragma unroll
    for (int o = 1; o < 64; o <<= 1) { s += __shfl_xor(s, o, 64); ss += __shfl_xor(ss, o, 64); }
    float mean = s * (1.0f / Hdim);
    float var = ss * (1.0f / Hdim) - mean * mean;
    float rstd = rsqrtf(var + 1e-5f);
    float4 gg = ((const float4*)g)[lane];
    float4 bb = ((const float4*)bt)[lane];
    float4 o;
    o.x = (v.x - mean) * rstd * gg.x + bb.x;
    o.y = (v.y - mean) * rstd * gg.y + bb.y;
    o.z = (v.z - mean) * rstd * gg.z + bb.z;
    o.w = (v.w - mean) * rstd * gg.w + bb.w;
    ((float4*)(out + (size_t)row * Hdim))[lane] = o;
}

__global__ void k_ln_bf(const float* __restrict__ x, const float* __restrict__ g,
                        const float* __restrict__ bt, unsigned short* __restrict__ out) {
    int row = blockIdx.x * 4 + (threadIdx.x >> 6);
    int lane = threadIdx.x & 63;
    float4 v = ((const float4*)(x + (size_t)row * Hdim))[lane];
    float s = v.x + v.y + v.z + v.w;
    float ss = v.x * v.x + v.y * v.y + v.z * v.z + v.w * v.w;
#pragma unroll
    for (int o = 1; o < 64; o <<= 1) { s += __shfl_xor(s, o, 64); ss += __shfl_xor(ss, o, 64); }
    float mean = s * (1.0f / Hdim);
    float var = ss * (1.0f / Hdim) - mean * mean;
    float rstd = rsqrtf(var + 1e-5f);
    float4 gg = ((const float4*)g)[lane];
    float4 bb = ((const float4*)bt)[lane];
    ushort4 o;
    o.x = f2bf((v.x - mean) * rstd * gg.x + bb.x);
    o.y = f2bf((v.y - mean) * rstd * gg.y + bb.y);
    o.z = f2bf((v.z - mean) * rstd * gg.z + bb.z);
    o.w = f2bf((v.w - mean) * rstd * gg.w + bb.w);
    ((ushort4*)(out + (size_t)row * Hdim))[lane] = o;
}

// ---------------- transpose U (b,l,h) fp32 -> U_T (b,h,l) bf16 ----------------
__global__ void k_tr(const float* __restrict__ U, unsigned short* __restrict__ UT) {
    __shared__ float lds[64][65];
    int l0 = blockIdx.x * 64, h0 = blockIdx.y * 64, b = blockIdx.z;
    int t = threadIdx.x;
#pragma unroll
    for (int q = 0; q < 16; q++) {
        int idx = q * 256 + t;
        int ll = idx >> 6, hh = idx & 63;
        lds[ll][hh] = U[((size_t)(b * LL + l0 + ll)) * Hdim + h0 + hh];
    }
    __syncthreads();
#pragma unroll
    for (int q = 0; q < 16; q++) {
        int idx = q * 256 + t;
        int hh = idx >> 6, ll = idx & 63;
        UT[((size_t)(b * Hdim + h0 + hh)) * LL + l0 + ll] = f2bf(lds[ll][hh]);
    }
}

// ---------------- state GEMM: Zg[h][bc][r] = sum_i U_T[b][h][c*P+i] * Wp[h][r][i] ----------------
__global__ void k_zgemm(const unsigned short* __restrict__ UT, const unsigned short* __restrict__ Wp,
                        float* __restrict__ Zg) {
    int h = blockIdx.x;
    int w = threadIdx.x >> 6, lane = threadIdx.x & 63;
    int wr = w & 1, wc = w >> 1;
    int m0 = blockIdx.y * 128 + wr * 64;   // bc rows
    int nb = wc * 64;                      // r cols (N=128)
    int lr = lane & 15, lk = (lane >> 4) * 8;
    size_t baseU[4], baseW[4];
#pragma unroll
    for (int mi = 0; mi < 4; mi++) {
        int row = m0 + mi * 16 + lr;
        baseU[mi] = ((size_t)((row >> 4) * Hdim + h)) * LL + (row & 15) * PCH + lk;
    }
#pragma unroll
    for (int nf = 0; nf < 4; nf++) {
        int col = nb + nf * 16 + lr;
        baseW[nf] = ((size_t)h * 128 + col) * 256 + lk;
    }
    f32x4 acc[4][4];
#pragma unroll
    for (int i = 0; i < 4; i++)
#pragma unroll
        for (int jx = 0; jx < 4; jx++) acc[i][jx] = (f32x4){0.f, 0.f, 0.f, 0.f};
    for (int kk = 0; kk < 256; kk += 32) {
        bf16x8 a[4], b[4];
#pragma unroll
        for (int mi = 0; mi < 4; mi++) a[mi] = *(const bf16x8*)(UT + baseU[mi] + kk);
#pragma unroll
        for (int nf = 0; nf < 4; nf++) b[nf] = *(const bf16x8*)(Wp + baseW[nf] + kk);
#pragma unroll
        for (int mi = 0; mi < 4; mi++)
#pragma unroll
            for (int nf = 0; nf < 4; nf++)
                acc[mi][nf] = __builtin_amdgcn_mfma_f32_16x16x32_bf16(a[mi], b[nf], acc[mi][nf], 0, 0, 0);
    }
#pragma unroll
    for (int mi = 0; mi < 4; mi++)
#pragma unroll
        for (int nf = 0; nf < 4; nf++) {
            int col = nb + nf * 16 + lr;
#pragma unroll
            for (int r = 0; r < 4; r++) {
                int row = m0 + mi * 16 + (lane >> 4) * 4 + r;
                Zg[((size_t)h * 256 + row) * 128 + col] = acc[mi][nf][r];
            }
        }
}

// ---------------- prefix over chunks -> Zpacked bf16 [h][bc][128] (incoming states) ----------------
__global__ void k_prefix2(const float* __restrict__ Zg, const float2* __restrict__ wptab,
                          unsigned short* __restrict__ ZP) {
    int t = blockIdx.x * 256 + threadIdx.x;  // 262144 = 2*16*256*32
    int n = t & 31;
    int h = (t >> 5) & 255;
    int b = (t >> 13) & 15;
    int dir = (t >> 17) & 1;
    float2 wp = wptab[h * NM + n];
    float sr = 0.f, si = 0.f;
    int ro = dir ? 64 + 2 * n : 2 * n;
    if (dir == 0) {
        for (int c = 0; c < NCH; c++) {
            size_t base = ((size_t)h * 256 + b * NCH + c) * 128;
            ZP[base + ro] = f2bf(sr);
            ZP[base + ro + 1] = f2bf(si);
            float zr = Zg[base + ro], zi = Zg[base + ro + 1];
            float nr = fmaf(wp.x, sr, fmaf(-wp.y, si, zr));
            float ni = fmaf(wp.y, sr, fmaf(wp.x, si, zi));
            sr = nr; si = ni;
        }
    } else {
        for (int c = NCH - 1; c >= 0; c--) {
            size_t base = ((size_t)h * 256 + b * NCH + c) * 128;
            ZP[base + ro] = f2bf(sr);
            ZP[base + ro + 1] = f2bf(si);
            float zr = Zg[base + ro], zi = Zg[base + ro + 1];
            float nr = fmaf(wp.x, sr, fmaf(-wp.y, si, zr));
            float ni = fmaf(wp.y, sr, fmaf(wp.x, si, zi));
            sr = nr; si = ni;
        }
    }
}

// ---------------- conv GEMM: Yt[h][bc][j] = gelu( sum_k Bu[bc][k] * Abig[j][k] ) ----------------
__global__ void k_conv(const unsigned short* __restrict__ UT, const unsigned short* __restrict__ ZP,
                       const unsigned short* __restrict__ AB, unsigned short* __restrict__ Yt) {
    int h = blockIdx.x;
    int w = threadIdx.x >> 6, lane = threadIdx.x & 63;
    int wr = w & 1, wc = w >> 1;
    int m0 = blockIdx.y * 128 + wr * 64;   // bc rows
    int nb = blockIdx.z * 128 + wc * 64;   // j cols
    int lr = lane & 15, lk = (lane >> 4) * 8;
    size_t baseU[4], baseZ[4], baseA[4];
#pragma unroll
    for (int mi = 0; mi < 4; mi++) {
        int row = m0 + mi * 16 + lr;
        baseU[mi] = ((size_t)((row >> 4) * Hdim + h)) * LL + (row & 15) * PCH + lk;
        baseZ[mi] = ((size_t)h * 256 + row) * 128 + lk;
    }
#pragma unroll
    for (int nf = 0; nf < 4; nf++) {
        int col = nb + nf * 16 + lr;
        baseA[nf] = ((size_t)h * 256 + col) * KBIG + lk;
    }
    f32x4 acc[4][4];
#pragma unroll
    for (int i = 0; i < 4; i++)
#pragma unroll
        for (int jx = 0; jx < 4; jx++) acc[i][jx] = (f32x4){0.f, 0.f, 0.f, 0.f};
    for (int kk = 0; kk < 256; kk += 32) {
        bf16x8 a[4], b[4];
#pragma unroll
        for (int mi = 0; mi < 4; mi++) a[mi] = *(const bf16x8*)(UT + baseU[mi] + kk);
#pragma unroll
        for (int nf = 0; nf < 4; nf++) b[nf] = *(const bf16x8*)(AB + baseA[nf] + kk);
#pragma unroll
        for (int mi = 0; mi < 4; mi++)
#pragma unroll
            for (int nf = 0; nf < 4; nf++)
                acc[mi][nf] = __builtin_amdgcn_mfma_f32_16x16x32_bf16(a[mi], b[nf], acc[mi][nf], 0, 0, 0);
    }
    for (int kk = 0; kk < 128; kk += 32) {
        bf16x8 a[4], b[4];
#pragma unroll
        for (int mi = 0; mi < 4; mi++) a[mi] = *(const bf16x8*)(ZP + baseZ[mi] + kk);
#pragma unroll
        for (int nf = 0; nf < 4; nf++) b[nf] = *(const bf16x8*)(AB + baseA[nf] + 256 + kk);
#pragma unroll
        for (int mi = 0; mi < 4; mi++)
#pragma unroll
            for (int nf = 0; nf < 4; nf++)
                acc[mi][nf] = __builtin_amdgcn_mfma_f32_16x16x32_bf16(a[mi], b[nf], acc[mi][nf], 0, 0, 0);
    }
#pragma unroll
    for (int mi = 0; mi < 4; mi++)
#pragma unroll
        for (int nf = 0; nf < 4; nf++) {
            int col = nb + nf * 16 + lr;
#pragma unroll
            for (int r = 0; r < 4; r++) {
                int row = m0 + mi * 16 + (lane >> 4) * 4 + r;
                Yt[(size_t)h * 65536 + row * 256 + col] = f2bf(gelu_f(acc[mi][nf][r]));
            }
        }
}

// ---------------- transpose Yt [h][bc][j] -> G (b, c*P+j, h) bf16 ----------------
__global__ void k_trg(const unsigned short* __restrict__ Yt, unsigned short* __restrict__ G) {
    __shared__ unsigned short lds[64][65];
    int bc = blockIdx.x;
    int h0 = blockIdx.y * 64, j0 = blockIdx.z * 64;
    int t = threadIdx.x;
#pragma unroll
    for (int q = 0; q < 16; q++) {
        int idx = q * 256 + t;
        int hh = idx >> 6, jj = idx & 63;
        lds[hh][jj] = Yt[(size_t)(h0 + hh) * 65536 + bc * 256 + j0 + jj];
    }
    __syncthreads();
    int b = bc >> 4, c = bc & 15;
#pragma unroll
    for (int q = 0; q < 16; q++) {
        int idx = q * 256 + t;
        int jj = idx >> 6, hh = idx & 63;
        G[((size_t)(b * LL + c * PCH + j0 + jj)) * Hdim + h0 + hh] = lds[hh][jj];
    }
}

// ---------------- GEMM1: zz = G@Wout + bout ; X2 = x + zz[:,:256]*sigmoid(zz[:,256:]) ----------------
__global__ void k_gemm1(const unsigned short* __restrict__ Gm, const unsigned short* __restrict__ W1T,
                        const float* __restrict__ bo, const float* __restrict__ xin,
                        float* __restrict__ X2) {
    int w = threadIdx.x >> 6, lane = threadIdx.x & 63;
    int wr = w & 1, wc = w >> 1;
    int m0 = blockIdx.x * 128 + wr * 64;
    int nb = blockIdx.y * 64 + wc * 32;
    int lr = lane & 15, lk = (lane >> 4) * 8;
    f32x4 acc[4][4];
#pragma unroll
    for (int i = 0; i < 4; i++)
#pragma unroll
        for (int j = 0; j < 4; j++) acc[i][j] = (f32x4){0.f, 0.f, 0.f, 0.f};
    for (int kk = 0; kk < 256; kk += 32) {
        bf16x8 a[4], bA[2], bB[2];
#pragma unroll
        for (int mi = 0; mi < 4; mi++)
            a[mi] = *(const bf16x8*)(Gm + (size_t)(m0 + mi * 16 + lr) * 256 + kk + lk);
#pragma unroll
        for (int nf = 0; nf < 2; nf++) {
            int col = nb + nf * 16 + lr;
            bA[nf] = *(const bf16x8*)(W1T + (size_t)col * 256 + kk + lk);
            bB[nf] = *(const bf16x8*)(W1T + (size_t)(col + 256) * 256 + kk + lk);
        }
#pragma unroll
        for (int mi = 0; mi < 4; mi++)
#pragma unroll
            for (int nf = 0; nf < 2; nf++) {
                acc[mi][nf] = __builtin_amdgcn_mfma_f32_16x16x32_bf16(a[mi], bA[nf], acc[mi][nf], 0, 0, 0);
                acc[mi][nf + 2] = __builtin_amdgcn_mfma_f32_16x16x32_bf16(a[mi], bB[nf], acc[mi][nf + 2], 0, 0, 0);
            }
    }
#pragma unroll
    for (int mi = 0; mi < 4; mi++)
#pragma unroll
        for (int nf = 0; nf < 2; nf++) {
            int col = nb + nf * 16 + lr;
            float biasA = bo[col], biasB = bo[col + 256];
#pragma unroll
            for (int r = 0; r < 4; r++) {
                int row = m0 + mi * 16 + (lane >> 4) * 4 + r;
                float zzA = acc[mi][nf][r] + biasA;
                float zzB = acc[mi][nf + 2][r] + biasB;
                float v = zzA / (1.0f + expf(-zzB));
                size_t idx = (size_t)row * 256 + col;
                X2[idx] = xin[idx] + v;
            }
        }
}

// ---------------- GEMM2: M = gelu(T2@W2 + b2) (bf16 out) ----------------
__global__ void k_gemm2(const unsigned short* __restrict__ T2, const unsigned short* __restrict__ W2T,
                        const float* __restrict__ b2, unsigned short* __restrict__ Mo) {
    int w = threadIdx.x >> 6, lane = threadIdx.x & 63;
    int wr = w & 1, wc = w >> 1;
    int m0 = blockIdx.x * 128 + wr * 64;
    int nb = blockIdx.y * 64 + wc * 32;
    int lr = lane & 15, lk = (lane >> 4) * 8;
    f32x4 acc[4][2];
#pragma unroll
    for (int i = 0; i < 4; i++) { acc[i][0] = (f32x4){0.f,0.f,0.f,0.f}; acc[i][1] = (f32x4){0.f,0.f,0.f,0.f}; }
    for (int kk = 0; kk < 256; kk += 32) {
        bf16x8 a[4], b[2];
#pragma unroll
        for (int mi = 0; mi < 4; mi++)
            a[mi] = *(const bf16x8*)(T2 + (size_t)(m0 + mi * 16 + lr) * 256 + kk + lk);
#pragma unroll
        for (int nf = 0; nf < 2; nf++)
            b[nf] = *(const bf16x8*)(W2T + (size_t)(nb + nf * 16 + lr) * 256 + kk + lk);
#pragma unroll
        for (int mi = 0; mi < 4; mi++)
#pragma unroll
            for (int nf = 0; nf < 2; nf++)
                acc[mi][nf] = __builtin_amdgcn_mfma_f32_16x16x32_bf16(a[mi], b[nf], acc[mi][nf], 0, 0, 0);
    }
#pragma unroll
    for (int mi = 0; mi < 4; mi++)
#pragma unroll
        for (int nf = 0; nf < 2; nf++) {
            int col = nb + nf * 16 + lr;
            float bias = b2[col];
#pragma unroll
            for (int r = 0; r < 4; r++) {
                int row = m0 + mi * 16 + (lane >> 4) * 4 + r;
                Mo[(size_t)row * 512 + col] = f2bf(gelu_f(acc[mi][nf][r] + bias));
            }
        }
}

// ---------------- GEMM3: out = X2 + M@W3 + b3 ----------------
__global__ void k_gemm3(const unsigned short* __restrict__ Mb, const unsigned short* __restrict__ W3T,
                        const float* __restrict__ b3, const float* __restrict__ X2,
                        float* __restrict__ out) {
    int w = threadIdx.x >> 6, lane = threadIdx.x & 63;
    int wr = w & 1, wc = w >> 1;
    int m0 = blockIdx.x * 128 + wr * 64;
    int nb = blockIdx.y * 64 + wc * 32;
    int lr = lane & 15, lk = (lane >> 4) * 8;
    f32x4 acc[4][2];
#pragma unroll
    for (int i = 0; i < 4; i++) { acc[i][0] = (f32x4){0.f,0.f,0.f,0.f}; acc[i][1] = (f32x4){0.f,0.f,0.f,0.f}; }
    for (int kk = 0; kk < 512; kk += 32) {
        bf16x8 a[4], b[2];
#pragma unroll
        for (int mi = 0; mi < 4; mi++)
            a[mi] = *(const bf16x8*)(Mb + (size_t)(m0 + mi * 16 + lr) * 512 + kk + lk);
#pragma unroll
        for (int nf = 0; nf < 2; nf++)
            b[nf] = *(const bf16x8*)(W3T + (size_t)(nb + nf * 16 + lr) * 512 + kk + lk);
#pragma unroll
        for (int mi = 0; mi < 4; mi++)
#pragma unroll
            for (int nf = 0; nf < 2; nf++)
                acc[mi][nf] = __builtin_amdgcn_mfma_f32_16x16x32_bf16(a[mi], b[nf], acc[mi][nf], 0, 0, 0);
    }
#pragma unroll
    for (int mi = 0; mi < 4; mi++)
#pragma unroll
        for (int nf = 0; nf < 2; nf++) {
            int col = nb + nf * 16 + lr;
            float bias = b3[col];
#pragma unroll
            for (int r = 0; r < 4; r++) {
                int row = m0 + mi * 16 + (lane >> 4) * 4 + r;
                size_t idx = (size_t)row * 256 + col;
                out[idx] = X2[idx] + acc[mi][nf][r] + bias;
            }
        }
}

extern "C" void kernel_launch(void* const* d_in, const int* in_sizes, int n_in,
                              void* d_out, int out_size, void* d_ws, size_t ws_size,
                              hipStream_t stream) {
    const float* x     = (const float*)d_in[0];
    const float* ln1g  = (const float*)d_in[1];
    const float* ln1b  = (const float*)d_in[2];
    const float* ln2g  = (const float*)d_in[3];
    const float* ln2b  = (const float*)d_in[4];
    const float* logdt = (const float*)d_in[5];
    const float* Are   = (const float*)d_in[6];
    const float* Aim   = (const float*)d_in[7];
    const float* Cre   = (const float*)d_in[8];
    const float* Cim   = (const float*)d_in[9];
    const float* Dsk   = (const float*)d_in[10];
    const float* Wout  = (const float*)d_in[11];
    const float* bo    = (const float*)d_in[12];
    const float* W2    = (const float*)d_in[13];
    const float* b2    = (const float*)d_in[14];
    const float* W3    = (const float*)d_in[15];
    const float* b3    = (const float*)d_in[16];

    char* ws = (char*)d_ws;
    float*          U    = (float*)(ws + OFF_ABIG);        // region0 first life
    unsigned short* AB   = (unsigned short*)(ws + OFF_ABIG);
    unsigned short* Wp   = (unsigned short*)(ws + OFF_WPM);
    float*          X2   = (float*)(ws + OFF_ABIG);        // region0 third life
    unsigned short* UT   = (unsigned short*)(ws + OFF_UT);
    float*          Zg   = (float*)(ws + OFF_ZG);
    unsigned short* Yt   = (unsigned short*)(ws + OFF_ZG);
    unsigned short* Mb   = (unsigned short*)(ws + OFF_M);
    unsigned short* ZP   = (unsigned short*)(ws + OFF_ZP);
    unsigned short* G    = (unsigned short*)(ws + OFF_G);  // later T2
    float*          Kf   = (float*)(ws + OFF_KF);
    float*          Kb   = (float*)(ws + OFF_KB);
    float2*         WT   = (float2*)(ws + OFF_WTAB);
    float2*         WPT  = (float2*)(ws + OFF_WPT);
    float2*         CE   = (float2*)(ws + OFF_CE);
    unsigned short* W1T  = (unsigned short*)(ws + OFF_W1T);
    unsigned short* W2T  = (unsigned short*)(ws + OFF_W2T);
    unsigned short* W3T  = (unsigned short*)(ws + OFF_W3T);

    k_tab<<<32, 256, 0, stream>>>(logdt, Are, Aim, Cre, Cim, WT, WPT, CE);
    k_wt<<<512, 256, 0, stream>>>(Wout, W2, W3, W1T, W2T, W3T);
    k_kern<<<256, 256, 0, stream>>>(logdt, Are, Aim, CE, Kf, Kb);
    k_ln<<<NB * LL / 4, 256, 0, stream>>>(x, ln1g, ln1b, U);
    k_tr<<<dim3(64, 4, 16), 256, 0, stream>>>(U, UT);
    // region0 now free of U -> build Abig / Wp
    k_abuild<<<256, 256, 0, stream>>>(Kf, Kb, logdt, Are, Aim, CE, Dsk, AB);
    k_wp<<<256, 128, 0, stream>>>(WT, Wp);
    k_zgemm<<<dim3(256, 2), 256, 0, stream>>>(UT, Wp, Zg);
    k_prefix2<<<1024, 256, 0, stream>>>(Zg, WPT, ZP);
    k_conv<<<dim3(256, 2, 2), 256, 0, stream>>>(UT, ZP, AB, Yt);
    k_trg<<<dim3(256, 4, 4), 256, 0, stream>>>(Yt, G);
    k_gemm1<<<dim3(512, 4), 256, 0, stream>>>(G, W1T, bo, x, X2);
    k_ln_bf<<<NB * LL / 4, 256, 0, stream>>>(X2, ln2g, ln2b, G);
    k_gemm2<<<dim3(512, 8), 256, 0, stream>>>(G, W2T, b2, Mb);
    k_gemm3<<<dim3(512, 4), 256, 0, stream>>>(Mb, W3T, b3, X2, (float*)d_out);
}

// Round 4
// 523.414 us; speedup vs baseline: 13.0625x; 1.0599x over previous
//
#include <hip/hip_runtime.h>
#include <hip/hip_bf16.h>

typedef __attribute__((ext_vector_type(8))) short bf16x8;
typedef __attribute__((ext_vector_type(4))) float f32x4;

#define Hdim 256
#define NM 32      // N2 modes
#define NB 16      // batch
#define LL 4096    // seq len
#define PCH 256    // chunk length
#define NCH 16     // chunks = LL/PCH
#define KBIG 384   // conv GEMM K: 256 u + 64 zf + 64 zb

// ---- workspace layout (bytes), total 186,122,240 ----
// region0 [0,67108864): U fp32 -> (Abig bf16 50331648 @0 | Wp bf16 16777216 @50331648) -> X2 fp32
#define OFF_ABIG ((size_t)0)
#define OFF_WPM  ((size_t)50331648)
#define OFF_UT   ((size_t)67108864)    // U_T bf16 [B][H][L] 33554432 (dead after conv)
#define OFF_ZG   ((size_t)100663296)   // Zg fp32 [h][bc][128] 33554432 ; then Yt bf16 [h][bc][j]
#define OFF_M    ((size_t)67108864)    // M bf16 67108864 (spans UT+ZG, alive gemm2->gemm3)
#define OFF_ZP   ((size_t)134217728)   // Zpacked bf16 [h][bc][128] 16777216
#define OFF_G    ((size_t)150994944)   // G bf16 (b,l,h) 33554432 ; reused as T2
#define OFF_KF   ((size_t)184549376)   // Kf fp32 [H][P] 262144
#define OFF_KB   ((size_t)184811520)   // Kb fp32 [H][P] 262144
#define OFF_WTAB ((size_t)185073664)   // w float2 [H][N2] 65536
#define OFF_WPT  ((size_t)185139200)   // w^P float2 [H][N2] 65536
#define OFF_CE   ((size_t)185204736)   // Ceff float2 [2][H][N2] 131072
#define OFF_W1T  ((size_t)185335808)
#define OFF_W2T  ((size_t)185597952)
#define OFF_W3T  ((size_t)185860096)

__device__ __forceinline__ float gelu_f(float v) {
    return 0.5f * v * (1.0f + erff(v * 0.70710678118654752f));
}
__device__ __forceinline__ unsigned short f2bf(float f) {  // RNE f32->bf16
    unsigned int u = __float_as_uint(f);
    u += 0x7fffu + ((u >> 16) & 1u);
    return (unsigned short)(u >> 16);
}

// ---------------- tables: w = exp(dt*A), w^P, Ceff = C*(w-1)/A (x2 applied later) ----------------
__global__ void k_tab(const float* __restrict__ logdt, const float* __restrict__ Are,
                      const float* __restrict__ Aim, const float* __restrict__ Cre,
                      const float* __restrict__ Cim, float2* __restrict__ wtab,
                      float2* __restrict__ wptab, float2* __restrict__ ceff) {
    int idx = blockIdx.x * blockDim.x + threadIdx.x;
    if (idx >= Hdim * NM) return;
    int h = idx >> 5;
    float dt = expf(logdt[h]);
    double dar = (double)dt * (double)Are[idx];
    double dai = (double)dt * (double)Aim[idx];
    double wm = exp(dar);
    double wr = wm * cos(dai), wi = wm * sin(dai);
    wtab[idx] = make_float2((float)wr, (float)wi);
    double pm = exp(dar * (double)PCH);
    double pai = dai * (double)PCH;
    wptab[idx] = make_float2((float)(pm * cos(pai)), (float)(pm * sin(pai)));
    double are = (double)Are[idx], aim = (double)Aim[idx];
    double den = are * are + aim * aim;
    double nr = wr - 1.0, ni = wi;
    double qr = (nr * are + ni * aim) / den;
    double qi = (ni * are - nr * aim) / den;
    for (int ch = 0; ch < 2; ch++) {
        double cr = (double)Cre[ch * Hdim * NM + idx];
        double ci = (double)Cim[ch * Hdim * NM + idx];
        ceff[ch * Hdim * NM + idx] = make_float2((float)(cr * qr - ci * qi),
                                                 (float)(cr * qi + ci * qr));
    }
}

// ---------------- weight transpose + bf16 cast ----------------
__global__ void k_wt(const float* __restrict__ W1, const float* __restrict__ W2,
                     const float* __restrict__ W3, unsigned short* __restrict__ W1T,
                     unsigned short* __restrict__ W2T, unsigned short* __restrict__ W3T) {
    int t = blockIdx.x * 256 + threadIdx.x;  // 131072 threads
    int k = t >> 9, n = t & 511;             // W1,W2: [256][512]
    W1T[n * 256 + k] = f2bf(W1[t]);
    W2T[n * 256 + k] = f2bf(W2[t]);
    int k3 = t >> 8, n3 = t & 255;           // W3: [512][256]
    W3T[n3 * 512 + k3] = f2bf(W3[t]);
}

// ---------------- conv kernels kf[d]=2Re(Cf w^d), kb[d]=2Re(Cb w^d) ----------------
__global__ void k_kern(const float* __restrict__ logdt, const float* __restrict__ Are,
                       const float* __restrict__ Aim, const float2* __restrict__ CE,
                       float* __restrict__ Kf, float* __restrict__ Kb) {
    int t = blockIdx.x * 256 + threadIdx.x;  // 65536
    int h = t >> 8, d = t & 255;
    float dt = expf(logdt[h]);
    float kf = 0.f, kb = 0.f;
    for (int n = 0; n < NM; n++) {
        float dar = dt * Are[h * NM + n], dai = dt * Aim[h * NM + n];
        float m = expf((float)d * dar), ang = (float)d * dai;
        float wr = m * cosf(ang), wi = m * sinf(ang);
        float2 cf = CE[h * NM + n], cb = CE[Hdim * NM + h * NM + n];
        kf = fmaf(cf.x, wr, fmaf(-cf.y, wi, kf));
        kb = fmaf(cb.x, wr, fmaf(-cb.y, wi, kb));
    }
    Kf[t] = 2.f * kf;
    Kb[t] = 2.f * kb;
}

// ---------------- Abig[h][j][384]: dense conv row + Qf + Qb ----------------
__global__ void k_abuild(const float* __restrict__ Kf, const float* __restrict__ Kb,
                         const float* __restrict__ logdt, const float* __restrict__ Are,
                         const float* __restrict__ Aim, const float2* __restrict__ CE,
                         const float* __restrict__ Dsk, unsigned short* __restrict__ AB) {
    int t = blockIdx.x * 256 + threadIdx.x;  // 65536
    int h = t >> 8, j = t & 255;
    const float* kfr = Kf + h * 256;
    const float* kbr = Kb + h * 256;
    unsigned short* out = AB + (size_t)t * KBIG;
    float dsk = Dsk[h];
    for (int i = 0; i < 256; i++) {
        float v = (i <= j) ? kfr[j - i] : kbr[i - j - 1];
        if (i == j) v += dsk;
        out[i] = f2bf(v);
    }
    float dt = expf(logdt[h]);
    for (int n = 0; n < NM; n++) {
        float dar = dt * Are[h * NM + n], dai = dt * Aim[h * NM + n];
        float2 cf = CE[h * NM + n], cb = CE[Hdim * NM + h * NM + n];
        // Qf: coeff of zf_in -> 2*Re(Cf w^{j+1} z)
        float e1 = expf((float)(j + 1) * dar), a1 = (float)(j + 1) * dai;
        float wr1 = e1 * cosf(a1), wi1 = e1 * sinf(a1);
        float qfr = cf.x * wr1 - cf.y * wi1;
        float qfi = cf.x * wi1 + cf.y * wr1;
        out[256 + 2 * n] = f2bf(2.f * qfr);
        out[256 + 2 * n + 1] = f2bf(-2.f * qfi);
        // Qb: 2*Re(Cb w^{P-1-j} z)
        float p = (float)(PCH - 1 - j);
        float e2 = expf(p * dar), a2 = p * dai;
        float wr2 = e2 * cosf(a2), wi2 = e2 * sinf(a2);
        float qbr = cb.x * wr2 - cb.y * wi2;
        float qbi = cb.x * wi2 + cb.y * wr2;
        out[320 + 2 * n] = f2bf(2.f * qbr);
        out[320 + 2 * n + 1] = f2bf(-2.f * qbi);
    }
}

// ---------------- Wp[h][128][256]: state-GEMM matrix ----------------
__global__ void k_wp(const float2* __restrict__ wtab, unsigned short* __restrict__ Wp) {
    int h = blockIdx.x;
    int r = threadIdx.x;         // 128
    int n = (r & 63) >> 1, reim = r & 1, dir = r >> 6;
    float2 w = wtab[h * NM + n];
    unsigned short* out = Wp + ((size_t)h * 128 + r) * 256;
    float vr = 1.f, vi = 0.f;
    if (dir == 0) {
        for (int k = 0; k < 256; k++) {
            out[255 - k] = f2bf(reim ? vi : vr);
            float nr = vr * w.x - vi * w.y;
            float ni = vr * w.y + vi * w.x;
            vr = nr; vi = ni;
        }
    } else {
        for (int i = 0; i < 256; i++) {
            out[i] = f2bf(reim ? vi : vr);
            float nr = vr * w.x - vi * w.y;
            float ni = vr * w.y + vi * w.x;
            vr = nr; vi = ni;
        }
    }
}

// ---------------- layernorm fp32 out ----------------
__global__ void k_ln(const float* __restrict__ x, const float* __restrict__ g,
                     const float* __restrict__ bt, float* __restrict__ out) {
    int row = blockIdx.x * 4 + (threadIdx.x >> 6);
    int lane = threadIdx.x & 63;
    float4 v = ((const float4*)(x + (size_t)row * Hdim))[lane];
    float s = v.x + v.y + v.z + v.w;
    float ss = v.x * v.x + v.y * v.y + v.z * v.z + v.w * v.w;
#pragma unroll
    for (int o = 1; o < 64; o <<= 1) { s += __shfl_xor(s, o, 64); ss += __shfl_xor(ss, o, 64); }
    float mean = s * (1.0f / Hdim);
    float var = ss * (1.0f / Hdim) - mean * mean;
    float rstd = rsqrtf(var + 1e-5f);
    float4 gg = ((const float4*)g)[lane];
    float4 bb = ((const float4*)bt)[lane];
    float4 o;
    o.x = (v.x - mean) * rstd * gg.x + bb.x;
    o.y = (v.y - mean) * rstd * gg.y + bb.y;
    o.z = (v.z - mean) * rstd * gg.z + bb.z;
    o.w = (v.w - mean) * rstd * gg.w + bb.w;
    ((float4*)(out + (size_t)row * Hdim))[lane] = o;
}

__global__ void k_ln_bf(const float* __restrict__ x, const float* __restrict__ g,
                        const float* __restrict__ bt, unsigned short* __restrict__ out) {
    int row = blockIdx.x * 4 + (threadIdx.x >> 6);
    int lane = threadIdx.x & 63;
    float4 v = ((const float4*)(x + (size_t)row * Hdim))[lane];
    float s = v.x + v.y + v.z + v.w;
    float ss = v.x * v.x + v.y * v.y + v.z * v.z + v.w * v.w;
#pragma unroll
    for (int o = 1; o < 64; o <<= 1) { s += __shfl_xor(s, o, 64); ss += __shfl_xor(ss, o, 64); }
    float mean = s * (1.0f / Hdim);
    float var = ss * (1.0f / Hdim) - mean * mean;
    float rstd = rsqrtf(var + 1e-5f);
    float4 gg = ((const float4*)g)[lane];
    float4 bb = ((const float4*)bt)[lane];
    ushort4 o;
    o.x = f2bf((v.x - mean) * rstd * gg.x + bb.x);
    o.y = f2bf((v.y - mean) * rstd * gg.y + bb.y);
    o.z = f2bf((v.z - mean) * rstd * gg.z + bb.z);
    o.w = f2bf((v.w - mean) * rstd * gg.w + bb.w);
    ((ushort4*)(out + (size_t)row * Hdim))[lane] = o;
}

// ---------------- transpose U (b,l,h) fp32 -> U_T (b,h,l) bf16 ----------------
__global__ void k_tr(const float* __restrict__ U, unsigned short* __restrict__ UT) {
    __shared__ float lds[64][65];
    int l0 = blockIdx.x * 64, h0 = blockIdx.y * 64, b = blockIdx.z;
    int t = threadIdx.x;
#pragma unroll
    for (int q = 0; q < 16; q++) {
        int idx = q * 256 + t;
        int ll = idx >> 6, hh = idx & 63;
        lds[ll][hh] = U[((size_t)(b * LL + l0 + ll)) * Hdim + h0 + hh];
    }
    __syncthreads();
#pragma unroll
    for (int q = 0; q < 16; q++) {
        int idx = q * 256 + t;
        int hh = idx >> 6, ll = idx & 63;
        UT[((size_t)(b * Hdim + h0 + hh)) * LL + l0 + ll] = f2bf(lds[ll][hh]);
    }
}

// ---------------- state GEMM: Zg[h][bc][r], full 256x128 tile per h ----------------
__global__ __launch_bounds__(512) void k_zgemm(const unsigned short* __restrict__ UT,
                                               const unsigned short* __restrict__ Wp,
                                               float* __restrict__ Zg) {
    int h = blockIdx.x;
    int w = threadIdx.x >> 6, lane = threadIdx.x & 63;
    int wr = w & 3, wc = w >> 2;           // 4 row groups x 2 col groups
    int m0 = wr * 64;                      // bc rows
    int nb = wc * 64;                      // r cols
    int lr = lane & 15, lk = (lane >> 4) * 8;
    const unsigned short *pU[4], *pW[4];
#pragma unroll
    for (int mi = 0; mi < 4; mi++) {
        int row = m0 + mi * 16 + lr;
        pU[mi] = UT + ((size_t)((row >> 4) * Hdim + h)) * LL + (row & 15) * PCH + lk;
    }
#pragma unroll
    for (int nf = 0; nf < 4; nf++) {
        int col = nb + nf * 16 + lr;
        pW[nf] = Wp + ((size_t)h * 128 + col) * 256 + lk;
    }
    f32x4 acc[4][4];
#pragma unroll
    for (int i = 0; i < 4; i++)
#pragma unroll
        for (int jx = 0; jx < 4; jx++) acc[i][jx] = (f32x4){0.f, 0.f, 0.f, 0.f};
    for (int kk = 0; kk < 256; kk += 32) {
        bf16x8 a[4], b[4];
#pragma unroll
        for (int mi = 0; mi < 4; mi++) a[mi] = *(const bf16x8*)(pU[mi] + kk);
#pragma unroll
        for (int nf = 0; nf < 4; nf++) b[nf] = *(const bf16x8*)(pW[nf] + kk);
#pragma unroll
        for (int mi = 0; mi < 4; mi++)
#pragma unroll
            for (int nf = 0; nf < 4; nf++)
                acc[mi][nf] = __builtin_amdgcn_mfma_f32_16x16x32_bf16(a[mi], b[nf], acc[mi][nf], 0, 0, 0);
    }
#pragma unroll
    for (int mi = 0; mi < 4; mi++)
#pragma unroll
        for (int nf = 0; nf < 4; nf++) {
            int col = nb + nf * 16 + lr;
#pragma unroll
            for (int r = 0; r < 4; r++) {
                int row = m0 + mi * 16 + (lane >> 4) * 4 + r;
                Zg[((size_t)h * 256 + row) * 128 + col] = acc[mi][nf][r];
            }
        }
}

// ---------------- prefix over chunks -> Zpacked bf16 [h][bc][128] ----------------
__global__ void k_prefix2(const float* __restrict__ Zg, const float2* __restrict__ wptab,
                          unsigned short* __restrict__ ZP) {
    int t = blockIdx.x * 256 + threadIdx.x;  // 262144 = 2*16*256*32
    int n = t & 31;
    int h = (t >> 5) & 255;
    int b = (t >> 13) & 15;
    int dir = (t >> 17) & 1;
    float2 wp = wptab[h * NM + n];
    float sr = 0.f, si = 0.f;
    int ro = dir ? 64 + 2 * n : 2 * n;
    if (dir == 0) {
        for (int c = 0; c < NCH; c++) {
            size_t base = ((size_t)h * 256 + b * NCH + c) * 128;
            ZP[base + ro] = f2bf(sr);
            ZP[base + ro + 1] = f2bf(si);
            float zr = Zg[base + ro], zi = Zg[base + ro + 1];
            float nr = fmaf(wp.x, sr, fmaf(-wp.y, si, zr));
            float ni = fmaf(wp.y, sr, fmaf(wp.x, si, zi));
            sr = nr; si = ni;
        }
    } else {
        for (int c = NCH - 1; c >= 0; c--) {
            size_t base = ((size_t)h * 256 + b * NCH + c) * 128;
            ZP[base + ro] = f2bf(sr);
            ZP[base + ro + 1] = f2bf(si);
            float zr = Zg[base + ro], zi = Zg[base + ro + 1];
            float nr = fmaf(wp.x, sr, fmaf(-wp.y, si, zr));
            float ni = fmaf(wp.y, sr, fmaf(wp.x, si, zi));
            sr = nr; si = ni;
        }
    }
}

// ---------------- conv GEMM: Yt[h][bc][j], tile 128bc x 256j (full j) ----------------
__global__ __launch_bounds__(512) void k_conv(const unsigned short* __restrict__ UT,
                                              const unsigned short* __restrict__ ZP,
                                              const unsigned short* __restrict__ AB,
                                              unsigned short* __restrict__ Yt) {
    int h = blockIdx.x;
    int w = threadIdx.x >> 6, lane = threadIdx.x & 63;
    int wr = w & 1, wc = w >> 1;           // 2 row x 4 col
    int m0 = blockIdx.y * 128 + wr * 64;   // bc rows
    int nb = wc * 64;                      // j cols (full 256)
    int lr = lane & 15, lk = (lane >> 4) * 8;
    const unsigned short *pU[4], *pZ[4], *pA[4];
#pragma unroll
    for (int mi = 0; mi < 4; mi++) {
        int row = m0 + mi * 16 + lr;
        pU[mi] = UT + ((size_t)((row >> 4) * Hdim + h)) * LL + (row & 15) * PCH + lk;
        pZ[mi] = ZP + ((size_t)h * 256 + row) * 128 + lk;
    }
#pragma unroll
    for (int nf = 0; nf < 4; nf++) {
        int col = nb + nf * 16 + lr;
        pA[nf] = AB + ((size_t)h * 256 + col) * KBIG + lk;
    }
    f32x4 acc[4][4];
#pragma unroll
    for (int i = 0; i < 4; i++)
#pragma unroll
        for (int jx = 0; jx < 4; jx++) acc[i][jx] = (f32x4){0.f, 0.f, 0.f, 0.f};
    for (int kk = 0; kk < 256; kk += 32) {
        bf16x8 a[4], b[4];
#pragma unroll
        for (int mi = 0; mi < 4; mi++) a[mi] = *(const bf16x8*)(pU[mi] + kk);
#pragma unroll
        for (int nf = 0; nf < 4; nf++) b[nf] = *(const bf16x8*)(pA[nf] + kk);
#pragma unroll
        for (int mi = 0; mi < 4; mi++)
#pragma unroll
            for (int nf = 0; nf < 4; nf++)
                acc[mi][nf] = __builtin_amdgcn_mfma_f32_16x16x32_bf16(a[mi], b[nf], acc[mi][nf], 0, 0, 0);
    }
    for (int kk = 0; kk < 128; kk += 32) {
        bf16x8 a[4], b[4];
#pragma unroll
        for (int mi = 0; mi < 4; mi++) a[mi] = *(const bf16x8*)(pZ[mi] + kk);
#pragma unroll
        for (int nf = 0; nf < 4; nf++) b[nf] = *(const bf16x8*)(pA[nf] + 256 + kk);
#pragma unroll
        for (int mi = 0; mi < 4; mi++)
#pragma unroll
            for (int nf = 0; nf < 4; nf++)
                acc[mi][nf] = __builtin_amdgcn_mfma_f32_16x16x32_bf16(a[mi], b[nf], acc[mi][nf], 0, 0, 0);
    }
#pragma unroll
    for (int mi = 0; mi < 4; mi++)
#pragma unroll
        for (int nf = 0; nf < 4; nf++) {
            int col = nb + nf * 16 + lr;
#pragma unroll
            for (int r = 0; r < 4; r++) {
                int row = m0 + mi * 16 + (lane >> 4) * 4 + r;
                Yt[(size_t)h * 65536 + row * 256 + col] = f2bf(gelu_f(acc[mi][nf][r]));
            }
        }
}

// ---------------- transpose Yt [h][bc][j] -> G (b, c*P+j, h) bf16 ----------------
__global__ void k_trg(const unsigned short* __restrict__ Yt, unsigned short* __restrict__ G) {
    __shared__ unsigned short lds[64][65];
    int bc = blockIdx.x;
    int h0 = blockIdx.y * 64, j0 = blockIdx.z * 64;
    int t = threadIdx.x;
#pragma unroll
    for (int q = 0; q < 16; q++) {
        int idx = q * 256 + t;
        int hh = idx >> 6, jj = idx & 63;
        lds[hh][jj] = Yt[(size_t)(h0 + hh) * 65536 + bc * 256 + j0 + jj];
    }
    __syncthreads();
    int b = bc >> 4, c = bc & 15;
#pragma unroll
    for (int q = 0; q < 16; q++) {
        int idx = q * 256 + t;
        int jj = idx >> 6, hh = idx & 63;
        G[((size_t)(b * LL + c * PCH + j0 + jj)) * Hdim + h0 + hh] = lds[hh][jj];
    }
}

// ---------------- GEMM1: 128 rows x all 256 GLU cols; X2 = x + glu(zz) ----------------
__global__ __launch_bounds__(1024) void k_gemm1(const unsigned short* __restrict__ Gm,
                                                const unsigned short* __restrict__ W1T,
                                                const float* __restrict__ bo,
                                                const float* __restrict__ xin,
                                                float* __restrict__ X2) {
    int w = threadIdx.x >> 6, lane = threadIdx.x & 63;
    int wr = w & 1, wc = w >> 1;           // 2 row x 8 col groups
    int m0 = blockIdx.x * 128 + wr * 64;
    int nb = wc * 32;                      // GLU col base (0..224)
    int lr = lane & 15, lk = (lane >> 4) * 8;
    const unsigned short *pA[4], *pBA[2], *pBB[2];
#pragma unroll
    for (int mi = 0; mi < 4; mi++)
        pA[mi] = Gm + (size_t)(m0 + mi * 16 + lr) * 256 + lk;
#pragma unroll
    for (int nf = 0; nf < 2; nf++) {
        int col = nb + nf * 16 + lr;
        pBA[nf] = W1T + (size_t)col * 256 + lk;
        pBB[nf] = W1T + (size_t)(col + 256) * 256 + lk;
    }
    f32x4 acc[4][4];
#pragma unroll
    for (int i = 0; i < 4; i++)
#pragma unroll
        for (int j = 0; j < 4; j++) acc[i][j] = (f32x4){0.f, 0.f, 0.f, 0.f};
    for (int kk = 0; kk < 256; kk += 32) {
        bf16x8 a[4], bA[2], bB[2];
#pragma unroll
        for (int mi = 0; mi < 4; mi++) a[mi] = *(const bf16x8*)(pA[mi] + kk);
#pragma unroll
        for (int nf = 0; nf < 2; nf++) {
            bA[nf] = *(const bf16x8*)(pBA[nf] + kk);
            bB[nf] = *(const bf16x8*)(pBB[nf] + kk);
        }
#pragma unroll
        for (int mi = 0; mi < 4; mi++)
#pragma unroll
            for (int nf = 0; nf < 2; nf++) {
                acc[mi][nf] = __builtin_amdgcn_mfma_f32_16x16x32_bf16(a[mi], bA[nf], acc[mi][nf], 0, 0, 0);
                acc[mi][nf + 2] = __builtin_amdgcn_mfma_f32_16x16x32_bf16(a[mi], bB[nf], acc[mi][nf + 2], 0, 0, 0);
            }
    }
#pragma unroll
    for (int mi = 0; mi < 4; mi++)
#pragma unroll
        for (int nf = 0; nf < 2; nf++) {
            int col = nb + nf * 16 + lr;
            float biasA = bo[col], biasB = bo[col + 256];
#pragma unroll
            for (int r = 0; r < 4; r++) {
                int row = m0 + mi * 16 + (lane >> 4) * 4 + r;
                float zzA = acc[mi][nf][r] + biasA;
                float zzB = acc[mi][nf + 2][r] + biasB;
                float v = zzA / (1.0f + expf(-zzB));
                size_t idx = (size_t)row * 256 + col;
                X2[idx] = xin[idx] + v;
            }
        }
}

// ---------------- GEMM2: 128 rows x full 512 cols; M = gelu(T2@W2+b2) bf16 ----------------
__global__ __launch_bounds__(1024) void k_gemm2(const unsigned short* __restrict__ T2,
                                                const unsigned short* __restrict__ W2T,
                                                const float* __restrict__ b2,
                                                unsigned short* __restrict__ Mo) {
    int w = threadIdx.x >> 6, lane = threadIdx.x & 63;
    int wr = w & 1, wc = w >> 1;           // 2 row x 8 col groups
    int m0 = blockIdx.x * 128 + wr * 64;
    int nb = wc * 64;
    int lr = lane & 15, lk = (lane >> 4) * 8;
    const unsigned short *pA[4], *pB[4];
#pragma unroll
    for (int mi = 0; mi < 4; mi++)
        pA[mi] = T2 + (size_t)(m0 + mi * 16 + lr) * 256 + lk;
#pragma unroll
    for (int nf = 0; nf < 4; nf++)
        pB[nf] = W2T + (size_t)(nb + nf * 16 + lr) * 256 + lk;
    f32x4 acc[4][4];
#pragma unroll
    for (int i = 0; i < 4; i++)
#pragma unroll
        for (int j = 0; j < 4; j++) acc[i][j] = (f32x4){0.f, 0.f, 0.f, 0.f};
    for (int kk = 0; kk < 256; kk += 32) {
        bf16x8 a[4], b[4];
#pragma unroll
        for (int mi = 0; mi < 4; mi++) a[mi] = *(const bf16x8*)(pA[mi] + kk);
#pragma unroll
        for (int nf = 0; nf < 4; nf++) b[nf] = *(const bf16x8*)(pB[nf] + kk);
#pragma unroll
        for (int mi = 0; mi < 4; mi++)
#pragma unroll
            for (int nf = 0; nf < 4; nf++)
                acc[mi][nf] = __builtin_amdgcn_mfma_f32_16x16x32_bf16(a[mi], b[nf], acc[mi][nf], 0, 0, 0);
    }
#pragma unroll
    for (int mi = 0; mi < 4; mi++)
#pragma unroll
        for (int nf = 0; nf < 4; nf++) {
            int col = nb + nf * 16 + lr;
            float bias = b2[col];
#pragma unroll
            for (int r = 0; r < 4; r++) {
                int row = m0 + mi * 16 + (lane >> 4) * 4 + r;
                Mo[(size_t)row * 512 + col] = f2bf(gelu_f(acc[mi][nf][r] + bias));
            }
        }
}

// ---------------- GEMM3: 128 rows x full 256 cols; out = X2 + M@W3 + b3 ----------------
__global__ __launch_bounds__(512) void k_gemm3(const unsigned short* __restrict__ Mb,
                                               const unsigned short* __restrict__ W3T,
                                               const float* __restrict__ b3,
                                               const float* __restrict__ X2,
                                               float* __restrict__ out) {
    int w = threadIdx.x >> 6, lane = threadIdx.x & 63;
    int wr = w & 1, wc = w >> 1;           // 2 row x 4 col groups
    int m0 = blockIdx.x * 128 + wr * 64;
    int nb = wc * 64;
    int lr = lane & 15, lk = (lane >> 4) * 8;
    const unsigned short *pA[4], *pB[4];
#pragma unroll
    for (int mi = 0; mi < 4; mi++)
        pA[mi] = Mb + (size_t)(m0 + mi * 16 + lr) * 512 + lk;
#pragma unroll
    for (int nf = 0; nf < 4; nf++)
        pB[nf] = W3T + (size_t)(nb + nf * 16 + lr) * 512 + lk;
    f32x4 acc[4][4];
#pragma unroll
    for (int i = 0; i < 4; i++)
#pragma unroll
        for (int j = 0; j < 4; j++) acc[i][j] = (f32x4){0.f, 0.f, 0.f, 0.f};
    for (int kk = 0; kk < 512; kk += 32) {
        bf16x8 a[4], b[4];
#pragma unroll
        for (int mi = 0; mi < 4; mi++) a[mi] = *(const bf16x8*)(pA[mi] + kk);
#pragma unroll
        for (int nf = 0; nf < 4; nf++) b[nf] = *(const bf16x8*)(pB[nf] + kk);
#pragma unroll
        for (int mi = 0; mi < 4; mi++)
#pragma unroll
            for (int nf = 0; nf < 4; nf++)
                acc[mi][nf] = __builtin_amdgcn_mfma_f32_16x16x32_bf16(a[mi], b[nf], acc[mi][nf], 0, 0, 0);
    }
#pragma unroll
    for (int mi = 0; mi < 4; mi++)
#pragma unroll
        for (int nf = 0; nf < 4; nf++) {
            int col = nb + nf * 16 + lr;
            float bias = b3[col];
#pragma unroll
            for (int r = 0; r < 4; r++) {
                int row = m0 + mi * 16 + (lane >> 4) * 4 + r;
                size_t idx = (size_t)row * 256 + col;
                out[idx] = X2[idx] + acc[mi][nf][r] + bias;
            }
        }
}

extern "C" void kernel_launch(void* const* d_in, const int* in_sizes, int n_in,
                              void* d_out, int out_size, void* d_ws, size_t ws_size,
                              hipStream_t stream) {
    const float* x     = (const float*)d_in[0];
    const float* ln1g  = (const float*)d_in[1];
    const float* ln1b  = (const float*)d_in[2];
    const float* ln2g  = (const float*)d_in[3];
    const float* ln2b  = (const float*)d_in[4];
    const float* logdt = (const float*)d_in[5];
    const float* Are   = (const float*)d_in[6];
    const float* Aim   = (const float*)d_in[7];
    const float* Cre   = (const float*)d_in[8];
    const float* Cim   = (const float*)d_in[9];
    const float* Dsk   = (const float*)d_in[10];
    const float* Wout  = (const float*)d_in[11];
    const float* bo    = (const float*)d_in[12];
    const float* W2    = (const float*)d_in[13];
    const float* b2    = (const float*)d_in[14];
    const float* W3    = (const float*)d_in[15];
    const float* b3    = (const float*)d_in[16];

    char* ws = (char*)d_ws;
    float*          U    = (float*)(ws + OFF_ABIG);        // region0 first life
    unsigned short* AB   = (unsigned short*)(ws + OFF_ABIG);
    unsigned short* Wp   = (unsigned short*)(ws + OFF_WPM);
    float*          X2   = (float*)(ws + OFF_ABIG);        // region0 third life
    unsigned short* UT   = (unsigned short*)(ws + OFF_UT);
    float*          Zg   = (float*)(ws + OFF_ZG);
    unsigned short* Yt   = (unsigned short*)(ws + OFF_ZG);
    unsigned short* Mb   = (unsigned short*)(ws + OFF_M);
    unsigned short* ZP   = (unsigned short*)(ws + OFF_ZP);
    unsigned short* G    = (unsigned short*)(ws + OFF_G);  // later T2
    float*          Kf   = (float*)(ws + OFF_KF);
    float*          Kb   = (float*)(ws + OFF_KB);
    float2*         WT   = (float2*)(ws + OFF_WTAB);
    float2*         WPT  = (float2*)(ws + OFF_WPT);
    float2*         CE   = (float2*)(ws + OFF_CE);
    unsigned short* W1T  = (unsigned short*)(ws + OFF_W1T);
    unsigned short* W2T  = (unsigned short*)(ws + OFF_W2T);
    unsigned short* W3T  = (unsigned short*)(ws + OFF_W3T);

    k_tab<<<32, 256, 0, stream>>>(logdt, Are, Aim, Cre, Cim, WT, WPT, CE);
    k_wt<<<512, 256, 0, stream>>>(Wout, W2, W3, W1T, W2T, W3T);
    k_kern<<<256, 256, 0, stream>>>(logdt, Are, Aim, CE, Kf, Kb);
    k_ln<<<NB * LL / 4, 256, 0, stream>>>(x, ln1g, ln1b, U);
    k_tr<<<dim3(64, 4, 16), 256, 0, stream>>>(U, UT);
    // region0 now free of U -> build Abig / Wp
    k_abuild<<<256, 256, 0, stream>>>(Kf, Kb, logdt, Are, Aim, CE, Dsk, AB);
    k_wp<<<256, 128, 0, stream>>>(WT, Wp);
    k_zgemm<<<256, 512, 0, stream>>>(UT, Wp, Zg);
    k_prefix2<<<1024, 256, 0, stream>>>(Zg, WPT, ZP);
    k_conv<<<dim3(256, 2), 512, 0, stream>>>(UT, ZP, AB, Yt);
    k_trg<<<dim3(256, 4, 4), 256, 0, stream>>>(Yt, G);
    k_gemm1<<<512, 1024, 0, stream>>>(G, W1T, bo, x, X2);
    k_ln_bf<<<NB * LL / 4, 256, 0, stream>>>(X2, ln2g, ln2b, G);
    k_gemm2<<<512, 1024, 0, stream>>>(G, W2T, b2, Mb);
    k_gemm3<<<512, 512, 0, stream>>>(Mb, W3T, b3, X2, (float*)d_out);
}

// Round 5
// 439.574 us; speedup vs baseline: 15.5539x; 1.1907x over previous
//
#include <hip/hip_runtime.h>
#include <hip/hip_bf16.h>

typedef __attribute__((ext_vector_type(8))) short bf16x8;
typedef __attribute__((ext_vector_type(4))) float f32x4;

#define Hdim 256
#define NM 32      // N2 modes
#define NB 16      // batch
#define LL 4096    // seq len
#define PCH 256    // chunk length
#define NCH 16     // chunks = LL/PCH
#define KBIG 384   // conv GEMM K: 256 u + 64 zf + 64 zb

// ---- workspace layout (bytes), total 186,122,240 ----
#define OFF_ABIG ((size_t)0)
#define OFF_WPM  ((size_t)50331648)
#define OFF_UT   ((size_t)67108864)    // U_T bf16 [B][H][L] 33554432
#define OFF_ZG   ((size_t)100663296)   // Zg fp32 [h][bc][128] ; then Yt bf16
#define OFF_M    ((size_t)67108864)    // M bf16 (spans UT+ZG, alive gemm2->gemm3)
#define OFF_ZP   ((size_t)134217728)   // Zpacked bf16 [h][bc][128]
#define OFF_G    ((size_t)150994944)   // G bf16 (b,l,h) ; reused as T2
#define OFF_KF   ((size_t)184549376)
#define OFF_KB   ((size_t)184811520)
#define OFF_WTAB ((size_t)185073664)
#define OFF_WPT  ((size_t)185139200)
#define OFF_CE   ((size_t)185204736)
#define OFF_W1T  ((size_t)185335808)
#define OFF_W2T  ((size_t)185597952)
#define OFF_W3T  ((size_t)185860096)

typedef const __attribute__((address_space(1))) void* gas_p;
typedef __attribute__((address_space(3))) void* las_p;

__device__ __forceinline__ float gelu_f(float v) {
    return 0.5f * v * (1.0f + erff(v * 0.70710678118654752f));
}
__device__ __forceinline__ unsigned short f2bf(float f) {  // RNE f32->bf16
    unsigned int u = __float_as_uint(f);
    u += 0x7fffu + ((u >> 16) & 1u);
    return (unsigned short)(u >> 16);
}

// stage ROWS x 64 bf16 tile (row-major, ld elems) into linear LDS [ROWS][64] via global_load_lds
template<int ROWS>
__device__ __forceinline__ void stage64(const unsigned short* __restrict__ src, int ld, int k0,
                                        unsigned short* lds, int t) {
#pragma unroll
    for (int i = 0; i < ROWS / 32; i++) {
        int e = i * 2048 + t * 8;
        int r = e >> 6, k = e & 63;
        const unsigned short* g = src + (size_t)r * ld + (k0 + k);
        unsigned short* l = lds + i * 2048 + (t >> 6) * 512;   // wave-uniform base
        __builtin_amdgcn_global_load_lds((gas_p)g, (las_p)l, 16, 0, 0);
    }
}

// ---------------- tables ----------------
__global__ void k_tab(const float* __restrict__ logdt, const float* __restrict__ Are,
                      const float* __restrict__ Aim, const float* __restrict__ Cre,
                      const float* __restrict__ Cim, float2* __restrict__ wtab,
                      float2* __restrict__ wptab, float2* __restrict__ ceff) {
    int idx = blockIdx.x * blockDim.x + threadIdx.x;
    if (idx >= Hdim * NM) return;
    int h = idx >> 5;
    float dt = expf(logdt[h]);
    double dar = (double)dt * (double)Are[idx];
    double dai = (double)dt * (double)Aim[idx];
    double wm = exp(dar);
    double wr = wm * cos(dai), wi = wm * sin(dai);
    wtab[idx] = make_float2((float)wr, (float)wi);
    double pm = exp(dar * (double)PCH);
    double pai = dai * (double)PCH;
    wptab[idx] = make_float2((float)(pm * cos(pai)), (float)(pm * sin(pai)));
    double are = (double)Are[idx], aim = (double)Aim[idx];
    double den = are * are + aim * aim;
    double nr = wr - 1.0, ni = wi;
    double qr = (nr * are + ni * aim) / den;
    double qi = (ni * are - nr * aim) / den;
    for (int ch = 0; ch < 2; ch++) {
        double cr = (double)Cre[ch * Hdim * NM + idx];
        double ci = (double)Cim[ch * Hdim * NM + idx];
        ceff[ch * Hdim * NM + idx] = make_float2((float)(cr * qr - ci * qi),
                                                 (float)(cr * qi + ci * qr));
    }
}

// ---------------- weight transpose + bf16 cast ----------------
__global__ void k_wt(const float* __restrict__ W1, const float* __restrict__ W2,
                     const float* __restrict__ W3, unsigned short* __restrict__ W1T,
                     unsigned short* __restrict__ W2T, unsigned short* __restrict__ W3T) {
    int t = blockIdx.x * 256 + threadIdx.x;  // 131072 threads
    int k = t >> 9, n = t & 511;             // W1,W2: [256][512]
    W1T[n * 256 + k] = f2bf(W1[t]);
    W2T[n * 256 + k] = f2bf(W2[t]);
    int k3 = t >> 8, n3 = t & 255;           // W3: [512][256]
    W3T[n3 * 512 + k3] = f2bf(W3[t]);
}

// ---------------- conv kernels kf[d]=2Re(Cf w^d), kb[d]=2Re(Cb w^d) ----------------
__global__ void k_kern(const float* __restrict__ logdt, const float* __restrict__ Are,
                       const float* __restrict__ Aim, const float2* __restrict__ CE,
                       float* __restrict__ Kf, float* __restrict__ Kb) {
    int t = blockIdx.x * 256 + threadIdx.x;  // 65536
    int h = t >> 8, d = t & 255;
    float dt = expf(logdt[h]);
    float kf = 0.f, kb = 0.f;
    for (int n = 0; n < NM; n++) {
        float dar = dt * Are[h * NM + n], dai = dt * Aim[h * NM + n];
        float m = expf((float)d * dar), ang = (float)d * dai;
        float wr = m * cosf(ang), wi = m * sinf(ang);
        float2 cf = CE[h * NM + n], cb = CE[Hdim * NM + h * NM + n];
        kf = fmaf(cf.x, wr, fmaf(-cf.y, wi, kf));
        kb = fmaf(cb.x, wr, fmaf(-cb.y, wi, kb));
    }
    Kf[t] = 2.f * kf;
    Kb[t] = 2.f * kb;
}

// ---------------- Abig[h][j][384]: dense conv row + Qf + Qb ----------------
__global__ void k_abuild(const float* __restrict__ Kf, const float* __restrict__ Kb,
                         const float* __restrict__ logdt, const float* __restrict__ Are,
                         const float* __restrict__ Aim, const float2* __restrict__ CE,
                         const float* __restrict__ Dsk, unsigned short* __restrict__ AB) {
    int t = blockIdx.x * 256 + threadIdx.x;  // 65536
    int h = t >> 8, j = t & 255;
    const float* kfr = Kf + h * 256;
    const float* kbr = Kb + h * 256;
    unsigned short* out = AB + (size_t)t * KBIG;
    float dsk = Dsk[h];
    for (int i = 0; i < 256; i++) {
        float v = (i <= j) ? kfr[j - i] : kbr[i - j - 1];
        if (i == j) v += dsk;
        out[i] = f2bf(v);
    }
    float dt = expf(logdt[h]);
    for (int n = 0; n < NM; n++) {
        float dar = dt * Are[h * NM + n], dai = dt * Aim[h * NM + n];
        float2 cf = CE[h * NM + n], cb = CE[Hdim * NM + h * NM + n];
        float e1 = expf((float)(j + 1) * dar), a1 = (float)(j + 1) * dai;
        float wr1 = e1 * cosf(a1), wi1 = e1 * sinf(a1);
        float qfr = cf.x * wr1 - cf.y * wi1;
        float qfi = cf.x * wi1 + cf.y * wr1;
        out[256 + 2 * n] = f2bf(2.f * qfr);
        out[256 + 2 * n + 1] = f2bf(-2.f * qfi);
        float p = (float)(PCH - 1 - j);
        float e2 = expf(p * dar), a2 = p * dai;
        float wr2 = e2 * cosf(a2), wi2 = e2 * sinf(a2);
        float qbr = cb.x * wr2 - cb.y * wi2;
        float qbi = cb.x * wi2 + cb.y * wr2;
        out[320 + 2 * n] = f2bf(2.f * qbr);
        out[320 + 2 * n + 1] = f2bf(-2.f * qbi);
    }
}

// ---------------- Wp[h][128][256]: state-GEMM matrix ----------------
__global__ void k_wp(const float2* __restrict__ wtab, unsigned short* __restrict__ Wp) {
    int h = blockIdx.x;
    int r = threadIdx.x;         // 128
    int n = (r & 63) >> 1, reim = r & 1, dir = r >> 6;
    float2 w = wtab[h * NM + n];
    unsigned short* out = Wp + ((size_t)h * 128 + r) * 256;
    float vr = 1.f, vi = 0.f;
    if (dir == 0) {
        for (int k = 0; k < 256; k++) {
            out[255 - k] = f2bf(reim ? vi : vr);
            float nr = vr * w.x - vi * w.y;
            float ni = vr * w.y + vi * w.x;
            vr = nr; vi = ni;
        }
    } else {
        for (int i = 0; i < 256; i++) {
            out[i] = f2bf(reim ? vi : vr);
            float nr = vr * w.x - vi * w.y;
            float ni = vr * w.y + vi * w.x;
            vr = nr; vi = ni;
        }
    }
}

// ---------------- layernorm fp32 / bf16 out ----------------
__global__ void k_ln(const float* __restrict__ x, const float* __restrict__ g,
                     const float* __restrict__ bt, float* __restrict__ out) {
    int row = blockIdx.x * 4 + (threadIdx.x >> 6);
    int lane = threadIdx.x & 63;
    float4 v = ((const float4*)(x + (size_t)row * Hdim))[lane];
    float s = v.x + v.y + v.z + v.w;
    float ss = v.x * v.x + v.y * v.y + v.z * v.z + v.w * v.w;
#pragma unroll
    for (int o = 1; o < 64; o <<= 1) { s += __shfl_xor(s, o, 64); ss += __shfl_xor(ss, o, 64); }
    float mean = s * (1.0f / Hdim);
    float var = ss * (1.0f / Hdim) - mean * mean;
    float rstd = rsqrtf(var + 1e-5f);
    float4 gg = ((const float4*)g)[lane];
    float4 bb = ((const float4*)bt)[lane];
    float4 o;
    o.x = (v.x - mean) * rstd * gg.x + bb.x;
    o.y = (v.y - mean) * rstd * gg.y + bb.y;
    o.z = (v.z - mean) * rstd * gg.z + bb.z;
    o.w = (v.w - mean) * rstd * gg.w + bb.w;
    ((float4*)(out + (size_t)row * Hdim))[lane] = o;
}

__global__ void k_ln_bf(const float* __restrict__ x, const float* __restrict__ g,
                        const float* __restrict__ bt, unsigned short* __restrict__ out) {
    int row = blockIdx.x * 4 + (threadIdx.x >> 6);
    int lane = threadIdx.x & 63;
    float4 v = ((const float4*)(x + (size_t)row * Hdim))[lane];
    float s = v.x + v.y + v.z + v.w;
    float ss = v.x * v.x + v.y * v.y + v.z * v.z + v.w * v.w;
#pragma unroll
    for (int o = 1; o < 64; o <<= 1) { s += __shfl_xor(s, o, 64); ss += __shfl_xor(ss, o, 64); }
    float mean = s * (1.0f / Hdim);
    float var = ss * (1.0f / Hdim) - mean * mean;
    float rstd = rsqrtf(var + 1e-5f);
    float4 gg = ((const float4*)g)[lane];
    float4 bb = ((const float4*)bt)[lane];
    ushort4 o;
    o.x = f2bf((v.x - mean) * rstd * gg.x + bb.x);
    o.y = f2bf((v.y - mean) * rstd * gg.y + bb.y);
    o.z = f2bf((v.z - mean) * rstd * gg.z + bb.z);
    o.w = f2bf((v.w - mean) * rstd * gg.w + bb.w);
    ((ushort4*)(out + (size_t)row * Hdim))[lane] = o;
}

// ---------------- transpose U (b,l,h) fp32 -> U_T (b,h,l) bf16 ----------------
__global__ void k_tr(const float* __restrict__ U, unsigned short* __restrict__ UT) {
    __shared__ float lds[64][65];
    int l0 = blockIdx.x * 64, h0 = blockIdx.y * 64, b = blockIdx.z;
    int t = threadIdx.x;
#pragma unroll
    for (int q = 0; q < 16; q++) {
        int idx = q * 256 + t;
        int ll = idx >> 6, hh = idx & 63;
        lds[ll][hh] = U[((size_t)(b * LL + l0 + ll)) * Hdim + h0 + hh];
    }
    __syncthreads();
#pragma unroll
    for (int q = 0; q < 16; q++) {
        int idx = q * 256 + t;
        int hh = idx >> 6, ll = idx & 63;
        UT[((size_t)(b * Hdim + h0 + hh)) * LL + l0 + ll] = f2bf(lds[ll][hh]);
    }
}

// ---------------- state GEMM: Zg[h][bc][r], full 256x128 tile per h ----------------
__global__ __launch_bounds__(512) void k_zgemm(const unsigned short* __restrict__ UT,
                                               const unsigned short* __restrict__ Wp,
                                               float* __restrict__ Zg) {
    int h = blockIdx.x;
    int w = threadIdx.x >> 6, lane = threadIdx.x & 63;
    int wr = w & 3, wc = w >> 2;
    int m0 = wr * 64;
    int nb = wc * 64;
    int lr = lane & 15, lk = (lane >> 4) * 8;
    const unsigned short *pU[4], *pW[4];
#pragma unroll
    for (int mi = 0; mi < 4; mi++) {
        int row = m0 + mi * 16 + lr;
        pU[mi] = UT + ((size_t)((row >> 4) * Hdim + h)) * LL + (row & 15) * PCH + lk;
    }
#pragma unroll
    for (int nf = 0; nf < 4; nf++) {
        int col = nb + nf * 16 + lr;
        pW[nf] = Wp + ((size_t)h * 128 + col) * 256 + lk;
    }
    f32x4 acc[4][4];
#pragma unroll
    for (int i = 0; i < 4; i++)
#pragma unroll
        for (int jx = 0; jx < 4; jx++) acc[i][jx] = (f32x4){0.f, 0.f, 0.f, 0.f};
    for (int kk = 0; kk < 256; kk += 32) {
        bf16x8 a[4], b[4];
#pragma unroll
        for (int mi = 0; mi < 4; mi++) a[mi] = *(const bf16x8*)(pU[mi] + kk);
#pragma unroll
        for (int nf = 0; nf < 4; nf++) b[nf] = *(const bf16x8*)(pW[nf] + kk);
#pragma unroll
        for (int mi = 0; mi < 4; mi++)
#pragma unroll
            for (int nf = 0; nf < 4; nf++)
                acc[mi][nf] = __builtin_amdgcn_mfma_f32_16x16x32_bf16(a[mi], b[nf], acc[mi][nf], 0, 0, 0);
    }
#pragma unroll
    for (int mi = 0; mi < 4; mi++)
#pragma unroll
        for (int nf = 0; nf < 4; nf++) {
            int col = nb + nf * 16 + lr;
#pragma unroll
            for (int r = 0; r < 4; r++) {
                int row = m0 + mi * 16 + (lane >> 4) * 4 + r;
                Zg[((size_t)h * 256 + row) * 128 + col] = acc[mi][nf][r];
            }
        }
}

// ---------------- prefix over chunks -> Zpacked bf16 [h][bc][128] ----------------
__global__ void k_prefix2(const float* __restrict__ Zg, const float2* __restrict__ wptab,
                          unsigned short* __restrict__ ZP) {
    int t = blockIdx.x * 256 + threadIdx.x;
    int n = t & 31;
    int h = (t >> 5) & 255;
    int b = (t >> 13) & 15;
    int dir = (t >> 17) & 1;
    float2 wp = wptab[h * NM + n];
    float sr = 0.f, si = 0.f;
    int ro = dir ? 64 + 2 * n : 2 * n;
    if (dir == 0) {
        for (int c = 0; c < NCH; c++) {
            size_t base = ((size_t)h * 256 + b * NCH + c) * 128;
            ZP[base + ro] = f2bf(sr);
            ZP[base + ro + 1] = f2bf(si);
            float zr = Zg[base + ro], zi = Zg[base + ro + 1];
            float nr = fmaf(wp.x, sr, fmaf(-wp.y, si, zr));
            float ni = fmaf(wp.y, sr, fmaf(wp.x, si, zi));
            sr = nr; si = ni;
        }
    } else {
        for (int c = NCH - 1; c >= 0; c--) {
            size_t base = ((size_t)h * 256 + b * NCH + c) * 128;
            ZP[base + ro] = f2bf(sr);
            ZP[base + ro + 1] = f2bf(si);
            float zr = Zg[base + ro], zi = Zg[base + ro + 1];
            float nr = fmaf(wp.x, sr, fmaf(-wp.y, si, zr));
            float ni = fmaf(wp.y, sr, fmaf(wp.x, si, zi));
            sr = nr; si = ni;
        }
    }
}

// ---------------- conv GEMM: Yt[h][bc][j], tile 128bc x 256j ----------------
__global__ __launch_bounds__(512) void k_conv(const unsigned short* __restrict__ UT,
                                              const unsigned short* __restrict__ ZP,
                                              const unsigned short* __restrict__ AB,
                                              unsigned short* __restrict__ Yt) {
    int h = blockIdx.x;
    int w = threadIdx.x >> 6, lane = threadIdx.x & 63;
    int wr = w & 1, wc = w >> 1;
    int m0 = blockIdx.y * 128 + wr * 64;
    int nb = wc * 64;
    int lr = lane & 15, lk = (lane >> 4) * 8;
    const unsigned short *pU[4], *pZ[4], *pA[4];
#pragma unroll
    for (int mi = 0; mi < 4; mi++) {
        int row = m0 + mi * 16 + lr;
        pU[mi] = UT + ((size_t)((row >> 4) * Hdim + h)) * LL + (row & 15) * PCH + lk;
        pZ[mi] = ZP + ((size_t)h * 256 + row) * 128 + lk;
    }
#pragma unroll
    for (int nf = 0; nf < 4; nf++) {
        int col = nb + nf * 16 + lr;
        pA[nf] = AB + ((size_t)h * 256 + col) * KBIG + lk;
    }
    f32x4 acc[4][4];
#pragma unroll
    for (int i = 0; i < 4; i++)
#pragma unroll
        for (int jx = 0; jx < 4; jx++) acc[i][jx] = (f32x4){0.f, 0.f, 0.f, 0.f};
    for (int kk = 0; kk < 256; kk += 32) {
        bf16x8 a[4], b[4];
#pragma unroll
        for (int mi = 0; mi < 4; mi++) a[mi] = *(const bf16x8*)(pU[mi] + kk);
#pragma unroll
        for (int nf = 0; nf < 4; nf++) b[nf] = *(const bf16x8*)(pA[nf] + kk);
#pragma unroll
        for (int mi = 0; mi < 4; mi++)
#pragma unroll
            for (int nf = 0; nf < 4; nf++)
                acc[mi][nf] = __builtin_amdgcn_mfma_f32_16x16x32_bf16(a[mi], b[nf], acc[mi][nf], 0, 0, 0);
    }
    for (int kk = 0; kk < 128; kk += 32) {
        bf16x8 a[4], b[4];
#pragma unroll
        for (int mi = 0; mi < 4; mi++) a[mi] = *(const bf16x8*)(pZ[mi] + kk);
#pragma unroll
        for (int nf = 0; nf < 4; nf++) b[nf] = *(const bf16x8*)(pA[nf] + 256 + kk);
#pragma unroll
        for (int mi = 0; mi < 4; mi++)
#pragma unroll
            for (int nf = 0; nf < 4; nf++)
                acc[mi][nf] = __builtin_amdgcn_mfma_f32_16x16x32_bf16(a[mi], b[nf], acc[mi][nf], 0, 0, 0);
    }
#pragma unroll
    for (int mi = 0; mi < 4; mi++)
#pragma unroll
        for (int nf = 0; nf < 4; nf++) {
            int col = nb + nf * 16 + lr;
#pragma unroll
            for (int r = 0; r < 4; r++) {
                int row = m0 + mi * 16 + (lane >> 4) * 4 + r;
                Yt[(size_t)h * 65536 + row * 256 + col] = f2bf(gelu_f(acc[mi][nf][r]));
            }
        }
}

// ---------------- transpose Yt [h][bc][j] -> G (b, c*P+j, h) bf16 ----------------
__global__ void k_trg(const unsigned short* __restrict__ Yt, unsigned short* __restrict__ G) {
    __shared__ unsigned short lds[64][65];
    int bc = blockIdx.x;
    int h0 = blockIdx.y * 64, j0 = blockIdx.z * 64;
    int t = threadIdx.x;
#pragma unroll
    for (int q = 0; q < 16; q++) {
        int idx = q * 256 + t;
        int hh = idx >> 6, jj = idx & 63;
        lds[hh][jj] = Yt[(size_t)(h0 + hh) * 65536 + bc * 256 + j0 + jj];
    }
    __syncthreads();
    int b = bc >> 4, c = bc & 15;
#pragma unroll
    for (int q = 0; q < 16; q++) {
        int idx = q * 256 + t;
        int jj = idx >> 6, hh = idx & 63;
        G[((size_t)(b * LL + c * PCH + j0 + jj)) * Hdim + h0 + hh] = lds[hh][jj];
    }
}

// ---------------- GEMM1 (LDS-staged): X2 = x + glu(G@Wout + bo) ----------------
__global__ __launch_bounds__(256) void k_gemm1(const unsigned short* __restrict__ Gm,
                                               const unsigned short* __restrict__ W1T,
                                               const float* __restrict__ bo,
                                               const float* __restrict__ xin,
                                               float* __restrict__ X2) {
    __shared__ unsigned short As[128 * 64];
    __shared__ unsigned short BsA[64 * 64];
    __shared__ unsigned short BsB[64 * 64];
    int t = threadIdx.x;
    int w = t >> 6, lane = t & 63;
    int m0w = (w & 1) * 64, n0w = (w >> 1) * 32;
    int lr = lane & 15, lk = (lane >> 4) * 8;
    int mblk = blockIdx.x * 128, nblk = blockIdx.y * 64;
    const unsigned short* Ab  = Gm + (size_t)mblk * 256;
    const unsigned short* BbA = W1T + (size_t)nblk * 256;
    const unsigned short* BbB = W1T + (size_t)(nblk + 256) * 256;
    f32x4 acc[4][4];
#pragma unroll
    for (int i = 0; i < 4; i++)
#pragma unroll
        for (int j = 0; j < 4; j++) acc[i][j] = (f32x4){0.f, 0.f, 0.f, 0.f};
    for (int k0 = 0; k0 < 256; k0 += 64) {
        stage64<128>(Ab, 256, k0, As, t);
        stage64<64>(BbA, 256, k0, BsA, t);
        stage64<64>(BbB, 256, k0, BsB, t);
        __syncthreads();
#pragma unroll
        for (int kk = 0; kk < 64; kk += 32) {
            bf16x8 a[4], bA[2], bB[2];
#pragma unroll
            for (int mi = 0; mi < 4; mi++)
                a[mi] = *(const bf16x8*)(As + (m0w + mi * 16 + lr) * 64 + kk + lk);
#pragma unroll
            for (int nf = 0; nf < 2; nf++) {
                bA[nf] = *(const bf16x8*)(BsA + (n0w + nf * 16 + lr) * 64 + kk + lk);
                bB[nf] = *(const bf16x8*)(BsB + (n0w + nf * 16 + lr) * 64 + kk + lk);
            }
#pragma unroll
            for (int mi = 0; mi < 4; mi++)
#pragma unroll
                for (int nf = 0; nf < 2; nf++) {
                    acc[mi][nf] = __builtin_amdgcn_mfma_f32_16x16x32_bf16(a[mi], bA[nf], acc[mi][nf], 0, 0, 0);
                    acc[mi][nf + 2] = __builtin_amdgcn_mfma_f32_16x16x32_bf16(a[mi], bB[nf], acc[mi][nf + 2], 0, 0, 0);
                }
        }
        __syncthreads();
    }
#pragma unroll
    for (int mi = 0; mi < 4; mi++)
#pragma unroll
        for (int nf = 0; nf < 2; nf++) {
            int col = nblk + n0w + nf * 16 + lr;
            float biasA = bo[col], biasB = bo[col + 256];
#pragma unroll
            for (int r = 0; r < 4; r++) {
                int row = mblk + m0w + mi * 16 + (lane >> 4) * 4 + r;
                float zzA = acc[mi][nf][r] + biasA;
                float zzB = acc[mi][nf + 2][r] + biasB;
                float v = zzA / (1.0f + expf(-zzB));
                size_t idx = (size_t)row * 256 + col;
                X2[idx] = xin[idx] + v;
            }
        }
}

// ---------------- GEMM2 (LDS-staged): M = gelu(T2@W2 + b2) bf16 ----------------
__global__ __launch_bounds__(256) void k_gemm2(const unsigned short* __restrict__ T2,
                                               const unsigned short* __restrict__ W2T,
                                               const float* __restrict__ b2,
                                               unsigned short* __restrict__ Mo) {
    __shared__ unsigned short As[128 * 64];
    __shared__ unsigned short Bs[128 * 64];
    int t = threadIdx.x;
    int w = t >> 6, lane = t & 63;
    int m0w = (w & 1) * 64, n0w = (w >> 1) * 64;
    int lr = lane & 15, lk = (lane >> 4) * 8;
    int mblk = blockIdx.x * 128, nblk = blockIdx.y * 128;
    const unsigned short* Ab = T2 + (size_t)mblk * 256;
    const unsigned short* Bb = W2T + (size_t)nblk * 256;
    f32x4 acc[4][4];
#pragma unroll
    for (int i = 0; i < 4; i++)
#pragma unroll
        for (int j = 0; j < 4; j++) acc[i][j] = (f32x4){0.f, 0.f, 0.f, 0.f};
    for (int k0 = 0; k0 < 256; k0 += 64) {
        stage64<128>(Ab, 256, k0, As, t);
        stage64<128>(Bb, 256, k0, Bs, t);
        __syncthreads();
#pragma unroll
        for (int kk = 0; kk < 64; kk += 32) {
            bf16x8 a[4], b[4];
#pragma unroll
            for (int mi = 0; mi < 4; mi++)
                a[mi] = *(const bf16x8*)(As + (m0w + mi * 16 + lr) * 64 + kk + lk);
#pragma unroll
            for (int nf = 0; nf < 4; nf++)
                b[nf] = *(const bf16x8*)(Bs + (n0w + nf * 16 + lr) * 64 + kk + lk);
#pragma unroll
            for (int mi = 0; mi < 4; mi++)
#pragma unroll
                for (int nf = 0; nf < 4; nf++)
                    acc[mi][nf] = __builtin_amdgcn_mfma_f32_16x16x32_bf16(a[mi], b[nf], acc[mi][nf], 0, 0, 0);
        }
        __syncthreads();
    }
#pragma unroll
    for (int mi = 0; mi < 4; mi++)
#pragma unroll
        for (int nf = 0; nf < 4; nf++) {
            int col = nblk + n0w + nf * 16 + lr;
            float bias = b2[col];
#pragma unroll
            for (int r = 0; r < 4; r++) {
                int row = mblk + m0w + mi * 16 + (lane >> 4) * 4 + r;
                Mo[(size_t)row * 512 + col] = f2bf(gelu_f(acc[mi][nf][r] + bias));
            }
        }
}

// ---------------- GEMM3 (LDS-staged): out = X2 + M@W3 + b3 ----------------
__global__ __launch_bounds__(256) void k_gemm3(const unsigned short* __restrict__ Mb,
                                               const unsigned short* __restrict__ W3T,
                                               const float* __restrict__ b3,
                                               const float* __restrict__ X2,
                                               float* __restrict__ out) {
    __shared__ unsigned short As[128 * 64];
    __shared__ unsigned short Bs[128 * 64];
    int t = threadIdx.x;
    int w = t >> 6, lane = t & 63;
    int m0w = (w & 1) * 64, n0w = (w >> 1) * 64;
    int lr = lane & 15, lk = (lane >> 4) * 8;
    int mblk = blockIdx.x * 128, nblk = blockIdx.y * 128;
    const unsigned short* Ab = Mb + (size_t)mblk * 512;
    const unsigned short* Bb = W3T + (size_t)nblk * 512;
    f32x4 acc[4][4];
#pragma unroll
    for (int i = 0; i < 4; i++)
#pragma unroll
        for (int j = 0; j < 4; j++) acc[i][j] = (f32x4){0.f, 0.f, 0.f, 0.f};
    for (int k0 = 0; k0 < 512; k0 += 64) {
        stage64<128>(Ab, 512, k0, As, t);
        stage64<128>(Bb, 512, k0, Bs, t);
        __syncthreads();
#pragma unroll
        for (int kk = 0; kk < 64; kk += 32) {
            bf16x8 a[4], b[4];
#pragma unroll
            for (int mi = 0; mi < 4; mi++)
                a[mi] = *(const bf16x8*)(As + (m0w + mi * 16 + lr) * 64 + kk + lk);
#pragma unroll
            for (int nf = 0; nf < 4; nf++)
                b[nf] = *(const bf16x8*)(Bs + (n0w + nf * 16 + lr) * 64 + kk + lk);
#pragma unroll
            for (int mi = 0; mi < 4; mi++)
#pragma unroll
                for (int nf = 0; nf < 4; nf++)
                    acc[mi][nf] = __builtin_amdgcn_mfma_f32_16x16x32_bf16(a[mi], b[nf], acc[mi][nf], 0, 0, 0);
        }
        __syncthreads();
    }
#pragma unroll
    for (int mi = 0; mi < 4; mi++)
#pragma unroll
        for (int nf = 0; nf < 4; nf++) {
            int col = nblk + n0w + nf * 16 + lr;
            float bias = b3[col];
#pragma unroll
            for (int r = 0; r < 4; r++) {
                int row = mblk + m0w + mi * 16 + (lane >> 4) * 4 + r;
                size_t idx = (size_t)row * 256 + col;
                out[idx] = X2[idx] + acc[mi][nf][r] + bias;
            }
        }
}

extern "C" void kernel_launch(void* const* d_in, const int* in_sizes, int n_in,
                              void* d_out, int out_size, void* d_ws, size_t ws_size,
                              hipStream_t stream) {
    const float* x     = (const float*)d_in[0];
    const float* ln1g  = (const float*)d_in[1];
    const float* ln1b  = (const float*)d_in[2];
    const float* ln2g  = (const float*)d_in[3];
    const float* ln2b  = (const float*)d_in[4];
    const float* logdt = (const float*)d_in[5];
    const float* Are   = (const float*)d_in[6];
    const float* Aim   = (const float*)d_in[7];
    const float* Cre   = (const float*)d_in[8];
    const float* Cim   = (const float*)d_in[9];
    const float* Dsk   = (const float*)d_in[10];
    const float* Wout  = (const float*)d_in[11];
    const float* bo    = (const float*)d_in[12];
    const float* W2    = (const float*)d_in[13];
    const float* b2    = (const float*)d_in[14];
    const float* W3    = (const float*)d_in[15];
    const float* b3    = (const float*)d_in[16];

    char* ws = (char*)d_ws;
    float*          U    = (float*)(ws + OFF_ABIG);
    unsigned short* AB   = (unsigned short*)(ws + OFF_ABIG);
    unsigned short* Wp   = (unsigned short*)(ws + OFF_WPM);
    float*          X2   = (float*)(ws + OFF_ABIG);
    unsigned short* UT   = (unsigned short*)(ws + OFF_UT);
    float*          Zg   = (float*)(ws + OFF_ZG);
    unsigned short* Yt   = (unsigned short*)(ws + OFF_ZG);
    unsigned short* Mb   = (unsigned short*)(ws + OFF_M);
    unsigned short* ZP   = (unsigned short*)(ws + OFF_ZP);
    unsigned short* G    = (unsigned short*)(ws + OFF_G);
    float*          Kf   = (float*)(ws + OFF_KF);
    float*          Kb   = (float*)(ws + OFF_KB);
    float2*         WT   = (float2*)(ws + OFF_WTAB);
    float2*         WPT  = (float2*)(ws + OFF_WPT);
    float2*         CE   = (float2*)(ws + OFF_CE);
    unsigned short* W1T  = (unsigned short*)(ws + OFF_W1T);
    unsigned short* W2T  = (unsigned short*)(ws + OFF_W2T);
    unsigned short* W3T  = (unsigned short*)(ws + OFF_W3T);

    k_tab<<<32, 256, 0, stream>>>(logdt, Are, Aim, Cre, Cim, WT, WPT, CE);
    k_wt<<<512, 256, 0, stream>>>(Wout, W2, W3, W1T, W2T, W3T);
    k_kern<<<256, 256, 0, stream>>>(logdt, Are, Aim, CE, Kf, Kb);
    k_ln<<<NB * LL / 4, 256, 0, stream>>>(x, ln1g, ln1b, U);
    k_tr<<<dim3(64, 4, 16), 256, 0, stream>>>(U, UT);
    k_abuild<<<256, 256, 0, stream>>>(Kf, Kb, logdt, Are, Aim, CE, Dsk, AB);
    k_wp<<<256, 128, 0, stream>>>(WT, Wp);
    k_zgemm<<<256, 512, 0, stream>>>(UT, Wp, Zg);
    k_prefix2<<<1024, 256, 0, stream>>>(Zg, WPT, ZP);
    k_conv<<<dim3(256, 2), 512, 0, stream>>>(UT, ZP, AB, Yt);
    k_trg<<<dim3(256, 4, 4), 256, 0, stream>>>(Yt, G);
    k_gemm1<<<dim3(512, 4), 256, 0, stream>>>(G, W1T, bo, x, X2);
    k_ln_bf<<<NB * LL / 4, 256, 0, stream>>>(X2, ln2g, ln2b, G);
    k_gemm2<<<dim3(512, 4), 256, 0, stream>>>(G, W2T, b2, Mb);
    k_gemm3<<<dim3(512, 2), 256, 0, stream>>>(Mb, W3T, b3, X2, (float*)d_out);
}

// Round 7
// 371.811 us; speedup vs baseline: 18.3886x; 1.1823x over previous
//
#include <hip/hip_runtime.h>
#include <hip/hip_bf16.h>

typedef __attribute__((ext_vector_type(8))) short bf16x8;
typedef __attribute__((ext_vector_type(4))) float f32x4;

#define Hdim 256
#define NM 32      // N2 modes
#define NB 16      // batch
#define LL 4096    // seq len
#define PCH 256    // chunk length
#define NCH 16     // chunks = LL/PCH
#define KBIG 384   // conv GEMM K: 256 u + 64 zf + 64 zb

// ---- workspace layout (bytes), total 186,122,240 ----
#define OFF_ABIG ((size_t)0)
#define OFF_WPM  ((size_t)50331648)
#define OFF_UT   ((size_t)67108864)    // U_T bf16 [B][H][L] 33554432
#define OFF_ZG   ((size_t)100663296)   // Zg fp32 [h][bc][128] ; then Yt bf16
#define OFF_M    ((size_t)67108864)    // M bf16 (spans UT+ZG, alive gemm2->gemm3)
#define OFF_ZP   ((size_t)134217728)   // Zpacked bf16 [h][bc][128]
#define OFF_G    ((size_t)150994944)   // G bf16 (b,l,h) ; reused as T2
#define OFF_WTAB ((size_t)185073664)
#define OFF_WPT  ((size_t)185139200)
#define OFF_CE   ((size_t)185204736)
#define OFF_W1T  ((size_t)185335808)
#define OFF_W2T  ((size_t)185597952)
#define OFF_W3T  ((size_t)185860096)

typedef const __attribute__((address_space(1))) void* gas_p;
typedef __attribute__((address_space(3))) void* las_p;

__device__ __forceinline__ float gelu_f(float v) {
    return 0.5f * v * (1.0f + erff(v * 0.70710678118654752f));
}
__device__ __forceinline__ unsigned short f2bf(float f) {  // RNE f32->bf16
    unsigned int u = __float_as_uint(f);
    u += 0x7fffu + ((u >> 16) & 1u);
    return (unsigned short)(u >> 16);
}

// stage ROWS x 64 bf16 tile (row-major, ld elems) into linear LDS [ROWS][64] via global_load_lds
template<int ROWS>
__device__ __forceinline__ void stage64(const unsigned short* __restrict__ src, int ld, int k0,
                                        unsigned short* lds, int t) {
#pragma unroll
    for (int i = 0; i < ROWS / 32; i++) {
        int e = i * 2048 + t * 8;
        int r = e >> 6, k = e & 63;
        const unsigned short* g = src + (size_t)r * ld + (k0 + k);
        unsigned short* l = lds + i * 2048 + (t >> 6) * 512;   // wave-uniform base
        __builtin_amdgcn_global_load_lds((gas_p)g, (las_p)l, 16, 0, 0);
    }
}

// ---------------- tables ----------------
__global__ void k_tab(const float* __restrict__ logdt, const float* __restrict__ Are,
                      const float* __restrict__ Aim, const float* __restrict__ Cre,
                      const float* __restrict__ Cim, float2* __restrict__ wtab,
                      float2* __restrict__ wptab, float2* __restrict__ ceff) {
    int idx = blockIdx.x * blockDim.x + threadIdx.x;
    if (idx >= Hdim * NM) return;
    int h = idx >> 5;
    float dt = expf(logdt[h]);
    double dar = (double)dt * (double)Are[idx];
    double dai = (double)dt * (double)Aim[idx];
    double wm = exp(dar);
    double wr = wm * cos(dai), wi = wm * sin(dai);
    wtab[idx] = make_float2((float)wr, (float)wi);
    double pm = exp(dar * (double)PCH);
    double pai = dai * (double)PCH;
    wptab[idx] = make_float2((float)(pm * cos(pai)), (float)(pm * sin(pai)));
    double are = (double)Are[idx], aim = (double)Aim[idx];
    double den = are * are + aim * aim;
    double nr = wr - 1.0, ni = wi;
    double qr = (nr * are + ni * aim) / den;
    double qi = (ni * are - nr * aim) / den;
    for (int ch = 0; ch < 2; ch++) {
        double cr = (double)Cre[ch * Hdim * NM + idx];
        double ci = (double)Cim[ch * Hdim * NM + idx];
        ceff[ch * Hdim * NM + idx] = make_float2((float)(cr * qr - ci * qi),
                                                 (float)(cr * qi + ci * qr));
    }
}

// ---------------- weight transpose + bf16 cast ----------------
__global__ void k_wt(const float* __restrict__ W1, const float* __restrict__ W2,
                     const float* __restrict__ W3, unsigned short* __restrict__ W1T,
                     unsigned short* __restrict__ W2T, unsigned short* __restrict__ W3T) {
    int t = blockIdx.x * 256 + threadIdx.x;  // 131072 threads
    int k = t >> 9, n = t & 511;             // W1,W2: [256][512]
    W1T[n * 256 + k] = f2bf(W1[t]);
    W2T[n * 256 + k] = f2bf(W2[t]);
    int k3 = t >> 8, n3 = t & 255;           // W3: [512][256]
    W3T[n3 * 512 + k3] = f2bf(W3[t]);
}

// ---------------- merged: wpow table -> kf/kb -> Abig rows -> Wp rows (all coalesced) ----------------
__global__ __launch_bounds__(256) void k_abw(const float* __restrict__ logdt,
                                             const float* __restrict__ Are,
                                             const float* __restrict__ Aim,
                                             const float2* __restrict__ CE,
                                             const float* __restrict__ Dsk,
                                             unsigned short* __restrict__ AB,
                                             unsigned short* __restrict__ Wp) {
    __shared__ float2 wpow[32][257];   // w^j, j=0..256
    __shared__ float kf[256], kb[256];
    __shared__ float2 ce_s[64];        // [0..31] fwd, [32..63] bwd
    int h = blockIdx.x;
    int t = threadIdx.x;
    if (t < 64) ce_s[t] = CE[(t >> 5) * (Hdim * NM) + h * NM + (t & 31)];
    {   // build wpow: thread = n*8+seg, each does a 32-step recurrence from w^(32*seg)
        int n = t >> 3, seg = t & 7;
        float dt = expf(logdt[h]);
        float dar = dt * Are[h * NM + n], dai = dt * Aim[h * NM + n];
        float em = expf(dar);
        float wr = em * cosf(dai), wi = em * sinf(dai);
        int j0 = seg * 32;
        float m = expf((float)j0 * dar), ang = (float)j0 * dai;
        float vr = m * cosf(ang), vi = m * sinf(ang);
        for (int q = 0; q < 32; q++) {
            wpow[n][j0 + q] = make_float2(vr, vi);
            float nr2 = vr * wr - vi * wi;
            float ni2 = vr * wi + vi * wr;
            vr = nr2; vi = ni2;
        }
        if (seg == 7) wpow[n][256] = make_float2(vr, vi);
    }
    __syncthreads();
    {   // conv kernels kf[d], kb[d] (lane = d)
        float kfv = 0.f, kbv = 0.f;
#pragma unroll
        for (int n = 0; n < NM; n++) {
            float2 wv = wpow[n][t];
            float2 cf = ce_s[n], cb = ce_s[32 + n];
            kfv = fmaf(cf.x, wv.x, fmaf(-cf.y, wv.y, kfv));
            kbv = fmaf(cb.x, wv.x, fmaf(-cb.y, wv.y, kbv));
        }
        kf[t] = 2.f * kfv;
        kb[t] = 2.f * kbv;
    }
    __syncthreads();
    float dsk = Dsk[h];
    // Abig rows: lane = column i; extra 128 cols from lanes 0..127
    for (int j = 0; j < 256; j++) {
        unsigned short* out = AB + ((size_t)h * 256 + j) * KBIG;
        float v = (t <= j) ? kf[j - t] : kb[t - j - 1];
        if (t == j) v += dsk;
        out[t] = f2bf(v);
        if (t < 128) {
            int n = (t & 63) >> 1, reim = t & 1;
            float2 c = (t < 64) ? ce_s[n] : ce_s[32 + n];
            float2 wv = (t < 64) ? wpow[n][j + 1] : wpow[n][255 - j];
            float re = c.x * wv.x - c.y * wv.y;
            float im = c.x * wv.y + c.y * wv.x;
            out[256 + t] = f2bf(reim ? -2.f * im : 2.f * re);
        }
    }
    // Wp rows: row r, lane = column i
    for (int r = 0; r < 128; r++) {
        int n = (r & 63) >> 1, reim = r & 1, dir = r >> 6;
        float2 wv = wpow[n][dir ? t : 255 - t];
        Wp[((size_t)h * 128 + r) * 256 + t] = f2bf(reim ? wv.y : wv.x);
    }
}

// ---------------- fused layernorm + transpose: x (b,l,h) fp32 -> UT (b,h,l) bf16 ----------------
__global__ __launch_bounds__(256) void k_lntr(const float* __restrict__ x,
                                              const float* __restrict__ g,
                                              const float* __restrict__ bt,
                                              unsigned short* __restrict__ UT) {
    __shared__ unsigned short lds[256][65];
    int lt = blockIdx.x, b = blockIdx.y;
    int t = threadIdx.x;
    int lane = t & 63, w = t >> 6;
    float4 gg = ((const float4*)g)[lane];
    float4 bb = ((const float4*)bt)[lane];
#pragma unroll
    for (int q = 0; q < 16; q++) {
        int l = q * 4 + w;
        float4 v = ((const float4*)(x + ((size_t)(b * LL + lt * 64 + l)) * Hdim))[lane];
        float s = v.x + v.y + v.z + v.w;
        float ss = v.x * v.x + v.y * v.y + v.z * v.z + v.w * v.w;
#pragma unroll
        for (int o = 1; o < 64; o <<= 1) { s += __shfl_xor(s, o, 64); ss += __shfl_xor(ss, o, 64); }
        float mean = s * (1.0f / Hdim);
        float var = ss * (1.0f / Hdim) - mean * mean;
        float rstd = rsqrtf(var + 1e-5f);
        lds[lane * 4 + 0][l] = f2bf((v.x - mean) * rstd * gg.x + bb.x);
        lds[lane * 4 + 1][l] = f2bf((v.y - mean) * rstd * gg.y + bb.y);
        lds[lane * 4 + 2][l] = f2bf((v.z - mean) * rstd * gg.z + bb.z);
        lds[lane * 4 + 3][l] = f2bf((v.w - mean) * rstd * gg.w + bb.w);
    }
    __syncthreads();
    // write out full 256h x 64l tile (64 iterations of 256 threads)
    for (int q = 0; q < 64; q++) {
        int idx = q * 256 + t;
        int hh = idx >> 6, ll = idx & 63;
        UT[((size_t)(b * Hdim + hh)) * LL + lt * 64 + ll] = lds[hh][ll];
    }
}

// ---------------- layernorm bf16 out (second LN) ----------------
__global__ void k_ln_bf(const float* __restrict__ x, const float* __restrict__ g,
                        const float* __restrict__ bt, unsigned short* __restrict__ out) {
    int row = blockIdx.x * 4 + (threadIdx.x >> 6);
    int lane = threadIdx.x & 63;
    float4 v = ((const float4*)(x + (size_t)row * Hdim))[lane];
    float s = v.x + v.y + v.z + v.w;
    float ss = v.x * v.x + v.y * v.y + v.z * v.z + v.w * v.w;
#pragma unroll
    for (int o = 1; o < 64; o <<= 1) { s += __shfl_xor(s, o, 64); ss += __shfl_xor(ss, o, 64); }
    float mean = s * (1.0f / Hdim);
    float var = ss * (1.0f / Hdim) - mean * mean;
    float rstd = rsqrtf(var + 1e-5f);
    float4 gg = ((const float4*)g)[lane];
    float4 bb = ((const float4*)bt)[lane];
    ushort4 o;
    o.x = f2bf((v.x - mean) * rstd * gg.x + bb.x);
    o.y = f2bf((v.y - mean) * rstd * gg.y + bb.y);
    o.z = f2bf((v.z - mean) * rstd * gg.z + bb.z);
    o.w = f2bf((v.w - mean) * rstd * gg.w + bb.w);
    ((ushort4*)(out + (size_t)row * Hdim))[lane] = o;
}

// ---------------- state GEMM: Zg[h][bc][r], full 256x128 tile per h ----------------
__global__ __launch_bounds__(512) void k_zgemm(const unsigned short* __restrict__ UT,
                                               const unsigned short* __restrict__ Wp,
                                               float* __restrict__ Zg) {
    int h = blockIdx.x;
    int w = threadIdx.x >> 6, lane = threadIdx.x & 63;
    int wr = w & 3, wc = w >> 2;
    int m0 = wr * 64;
    int nb = wc * 64;
    int lr = lane & 15, lk = (lane >> 4) * 8;
    const unsigned short *pU[4], *pW[4];
#pragma unroll
    for (int mi = 0; mi < 4; mi++) {
        int row = m0 + mi * 16 + lr;
        pU[mi] = UT + ((size_t)((row >> 4) * Hdim + h)) * LL + (row & 15) * PCH + lk;
    }
#pragma unroll
    for (int nf = 0; nf < 4; nf++) {
        int col = nb + nf * 16 + lr;
        pW[nf] = Wp + ((size_t)h * 128 + col) * 256 + lk;
    }
    f32x4 acc[4][4];
#pragma unroll
    for (int i = 0; i < 4; i++)
#pragma unroll
        for (int jx = 0; jx < 4; jx++) acc[i][jx] = (f32x4){0.f, 0.f, 0.f, 0.f};
    for (int kk = 0; kk < 256; kk += 32) {
        bf16x8 a[4], b[4];
#pragma unroll
        for (int mi = 0; mi < 4; mi++) a[mi] = *(const bf16x8*)(pU[mi] + kk);
#pragma unroll
        for (int nf = 0; nf < 4; nf++) b[nf] = *(const bf16x8*)(pW[nf] + kk);
#pragma unroll
        for (int mi = 0; mi < 4; mi++)
#pragma unroll
            for (int nf = 0; nf < 4; nf++)
                acc[mi][nf] = __builtin_amdgcn_mfma_f32_16x16x32_bf16(a[mi], b[nf], acc[mi][nf], 0, 0, 0);
    }
#pragma unroll
    for (int mi = 0; mi < 4; mi++)
#pragma unroll
        for (int nf = 0; nf < 4; nf++) {
            int col = nb + nf * 16 + lr;
#pragma unroll
            for (int r = 0; r < 4; r++) {
                int row = m0 + mi * 16 + (lane >> 4) * 4 + r;
                Zg[((size_t)h * 256 + row) * 128 + col] = acc[mi][nf][r];
            }
        }
}

// ---------------- prefix over chunks -> Zpacked bf16 [h][bc][128] ----------------
__global__ void k_prefix2(const float* __restrict__ Zg, const float2* __restrict__ wptab,
                          unsigned short* __restrict__ ZP) {
    int t = blockIdx.x * 256 + threadIdx.x;
    int n = t & 31;
    int h = (t >> 5) & 255;
    int b = (t >> 13) & 15;
    int dir = (t >> 17) & 1;
    float2 wp = wptab[h * NM + n];
    float sr = 0.f, si = 0.f;
    int ro = dir ? 64 + 2 * n : 2 * n;
    if (dir == 0) {
        for (int c = 0; c < NCH; c++) {
            size_t base = ((size_t)h * 256 + b * NCH + c) * 128;
            ZP[base + ro] = f2bf(sr);
            ZP[base + ro + 1] = f2bf(si);
            float zr = Zg[base + ro], zi = Zg[base + ro + 1];
            float nr = fmaf(wp.x, sr, fmaf(-wp.y, si, zr));
            float ni = fmaf(wp.y, sr, fmaf(wp.x, si, zi));
            sr = nr; si = ni;
        }
    } else {
        for (int c = NCH - 1; c >= 0; c--) {
            size_t base = ((size_t)h * 256 + b * NCH + c) * 128;
            ZP[base + ro] = f2bf(sr);
            ZP[base + ro + 1] = f2bf(si);
            float zr = Zg[base + ro], zi = Zg[base + ro + 1];
            float nr = fmaf(wp.x, sr, fmaf(-wp.y, si, zr));
            float ni = fmaf(wp.y, sr, fmaf(wp.x, si, zi));
            sr = nr; si = ni;
        }
    }
}

// ---------------- conv GEMM: Yt[h][bc][j], tile 128bc x 256j ----------------
__global__ __launch_bounds__(512) void k_conv(const unsigned short* __restrict__ UT,
                                              const unsigned short* __restrict__ ZP,
                                              const unsigned short* __restrict__ AB,
                                              unsigned short* __restrict__ Yt) {
    int h = blockIdx.x;
    int w = threadIdx.x >> 6, lane = threadIdx.x & 63;
    int wr = w & 1, wc = w >> 1;
    int m0 = blockIdx.y * 128 + wr * 64;
    int nb = wc * 64;
    int lr = lane & 15, lk = (lane >> 4) * 8;
    const unsigned short *pU[4], *pZ[4], *pA[4];
#pragma unroll
    for (int mi = 0; mi < 4; mi++) {
        int row = m0 + mi * 16 + lr;
        pU[mi] = UT + ((size_t)((row >> 4) * Hdim + h)) * LL + (row & 15) * PCH + lk;
        pZ[mi] = ZP + ((size_t)h * 256 + row) * 128 + lk;
    }
#pragma unroll
    for (int nf = 0; nf < 4; nf++) {
        int col = nb + nf * 16 + lr;
        pA[nf] = AB + ((size_t)h * 256 + col) * KBIG + lk;
    }
    f32x4 acc[4][4];
#pragma unroll
    for (int i = 0; i < 4; i++)
#pragma unroll
        for (int jx = 0; jx < 4; jx++) acc[i][jx] = (f32x4){0.f, 0.f, 0.f, 0.f};
    for (int kk = 0; kk < 256; kk += 32) {
        bf16x8 a[4], b[4];
#pragma unroll
        for (int mi = 0; mi < 4; mi++) a[mi] = *(const bf16x8*)(pU[mi] + kk);
#pragma unroll
        for (int nf = 0; nf < 4; nf++) b[nf] = *(const bf16x8*)(pA[nf] + kk);
#pragma unroll
        for (int mi = 0; mi < 4; mi++)
#pragma unroll
            for (int nf = 0; nf < 4; nf++)
                acc[mi][nf] = __builtin_amdgcn_mfma_f32_16x16x32_bf16(a[mi], b[nf], acc[mi][nf], 0, 0, 0);
    }
    for (int kk = 0; kk < 128; kk += 32) {
        bf16x8 a[4], b[4];
#pragma unroll
        for (int mi = 0; mi < 4; mi++) a[mi] = *(const bf16x8*)(pZ[mi] + kk);
#pragma unroll
        for (int nf = 0; nf < 4; nf++) b[nf] = *(const bf16x8*)(pA[nf] + 256 + kk);
#pragma unroll
        for (int mi = 0; mi < 4; mi++)
#pragma unroll
            for (int nf = 0; nf < 4; nf++)
                acc[mi][nf] = __builtin_amdgcn_mfma_f32_16x16x32_bf16(a[mi], b[nf], acc[mi][nf], 0, 0, 0);
    }
#pragma unroll
    for (int mi = 0; mi < 4; mi++)
#pragma unroll
        for (int nf = 0; nf < 4; nf++) {
            int col = nb + nf * 16 + lr;
#pragma unroll
            for (int r = 0; r < 4; r++) {
                int row = m0 + mi * 16 + (lane >> 4) * 4 + r;
                Yt[(size_t)h * 65536 + row * 256 + col] = f2bf(gelu_f(acc[mi][nf][r]));
            }
        }
}

// ---------------- transpose Yt [h][bc][j] -> G (b, c*P+j, h) bf16 ----------------
__global__ void k_trg(const unsigned short* __restrict__ Yt, unsigned short* __restrict__ G) {
    __shared__ unsigned short lds[64][65];
    int bc = blockIdx.x;
    int h0 = blockIdx.y * 64, j0 = blockIdx.z * 64;
    int t = threadIdx.x;
#pragma unroll
    for (int q = 0; q < 16; q++) {
        int idx = q * 256 + t;
        int hh = idx >> 6, jj = idx & 63;
        lds[hh][jj] = Yt[(size_t)(h0 + hh) * 65536 + bc * 256 + j0 + jj];
    }
    __syncthreads();
    int b = bc >> 4, c = bc & 15;
#pragma unroll
    for (int q = 0; q < 16; q++) {
        int idx = q * 256 + t;
        int jj = idx >> 6, hh = idx & 63;
        G[((size_t)(b * LL + c * PCH + j0 + jj)) * Hdim + h0 + hh] = lds[hh][jj];
    }
}

// ---------------- GEMM1 (LDS-staged): X2 = x + glu(G@Wout + bo) ----------------
__global__ __launch_bounds__(256) void k_gemm1(const unsigned short* __restrict__ Gm,
                                               const unsigned short* __restrict__ W1T,
                                               const float* __restrict__ bo,
                                               const float* __restrict__ xin,
                                               float* __restrict__ X2) {
    __shared__ unsigned short As[128 * 64];
    __shared__ unsigned short BsA[64 * 64];
    __shared__ unsigned short BsB[64 * 64];
    int t = threadIdx.x;
    int w = t >> 6, lane = t & 63;
    int m0w = (w & 1) * 64, n0w = (w >> 1) * 32;
    int lr = lane & 15, lk = (lane >> 4) * 8;
    int mblk = blockIdx.x * 128, nblk = blockIdx.y * 64;
    const unsigned short* Ab  = Gm + (size_t)mblk * 256;
    const unsigned short* BbA = W1T + (size_t)nblk * 256;
    const unsigned short* BbB = W1T + (size_t)(nblk + 256) * 256;
    f32x4 acc[4][4];
#pragma unroll
    for (int i = 0; i < 4; i++)
#pragma unroll
        for (int j = 0; j < 4; j++) acc[i][j] = (f32x4){0.f, 0.f, 0.f, 0.f};
    for (int k0 = 0; k0 < 256; k0 += 64) {
        stage64<128>(Ab, 256, k0, As, t);
        stage64<64>(BbA, 256, k0, BsA, t);
        stage64<64>(BbB, 256, k0, BsB, t);
        __syncthreads();
#pragma unroll
        for (int kk = 0; kk < 64; kk += 32) {
            bf16x8 a[4], bA[2], bB[2];
#pragma unroll
            for (int mi = 0; mi < 4; mi++)
                a[mi] = *(const bf16x8*)(As + (m0w + mi * 16 + lr) * 64 + kk + lk);
#pragma unroll
            for (int nf = 0; nf < 2; nf++) {
                bA[nf] = *(const bf16x8*)(BsA + (n0w + nf * 16 + lr) * 64 + kk + lk);
                bB[nf] = *(const bf16x8*)(BsB + (n0w + nf * 16 + lr) * 64 + kk + lk);
            }
#pragma unroll
            for (int mi = 0; mi < 4; mi++)
#pragma unroll
                for (int nf = 0; nf < 2; nf++) {
                    acc[mi][nf] = __builtin_amdgcn_mfma_f32_16x16x32_bf16(a[mi], bA[nf], acc[mi][nf], 0, 0, 0);
                    acc[mi][nf + 2] = __builtin_amdgcn_mfma_f32_16x16x32_bf16(a[mi], bB[nf], acc[mi][nf + 2], 0, 0, 0);
                }
        }
        __syncthreads();
    }
#pragma unroll
    for (int mi = 0; mi < 4; mi++)
#pragma unroll
        for (int nf = 0; nf < 2; nf++) {
            int col = nblk + n0w + nf * 16 + lr;
            float biasA = bo[col], biasB = bo[col + 256];
#pragma unroll
            for (int r = 0; r < 4; r++) {
                int row = mblk + m0w + mi * 16 + (lane >> 4) * 4 + r;
                float zzA = acc[mi][nf][r] + biasA;
                float zzB = acc[mi][nf + 2][r] + biasB;
                float v = zzA / (1.0f + expf(-zzB));
                size_t idx = (size_t)row * 256 + col;
                X2[idx] = xin[idx] + v;
            }
        }
}

// ---------------- GEMM2 (LDS-staged): M = gelu(T2@W2 + b2) bf16 ----------------
__global__ __launch_bounds__(256) void k_gemm2(const unsigned short* __restrict__ T2,
                                               const unsigned short* __restrict__ W2T,
                                               const float* __restrict__ b2,
                                               unsigned short* __restrict__ Mo) {
    __shared__ unsigned short As[128 * 64];
    __shared__ unsigned short Bs[128 * 64];
    int t = threadIdx.x;
    int w = t >> 6, lane = t & 63;
    int m0w = (w & 1) * 64, n0w = (w >> 1) * 64;
    int lr = lane & 15, lk = (lane >> 4) * 8;
    int mblk = blockIdx.x * 128, nblk = blockIdx.y * 128;
    const unsigned short* Ab = T2 + (size_t)mblk * 256;
    const unsigned short* Bb = W2T + (size_t)nblk * 256;
    f32x4 acc[4][4];
#pragma unroll
    for (int i = 0; i < 4; i++)
#pragma unroll
        for (int j = 0; j < 4; j++) acc[i][j] = (f32x4){0.f, 0.f, 0.f, 0.f};
    for (int k0 = 0; k0 < 256; k0 += 64) {
        stage64<128>(Ab, 256, k0, As, t);
        stage64<128>(Bb, 256, k0, Bs, t);
        __syncthreads();
#pragma unroll
        for (int kk = 0; kk < 64; kk += 32) {
            bf16x8 a[4], b[4];
#pragma unroll
            for (int mi = 0; mi < 4; mi++)
                a[mi] = *(const bf16x8*)(As + (m0w + mi * 16 + lr) * 64 + kk + lk);
#pragma unroll
            for (int nf = 0; nf < 4; nf++)
                b[nf] = *(const bf16x8*)(Bs + (n0w + nf * 16 + lr) * 64 + kk + lk);
#pragma unroll
            for (int mi = 0; mi < 4; mi++)
#pragma unroll
                for (int nf = 0; nf < 4; nf++)
                    acc[mi][nf] = __builtin_amdgcn_mfma_f32_16x16x32_bf16(a[mi], b[nf], acc[mi][nf], 0, 0, 0);
        }
        __syncthreads();
    }
#pragma unroll
    for (int mi = 0; mi < 4; mi++)
#pragma unroll
        for (int nf = 0; nf < 4; nf++) {
            int col = nblk + n0w + nf * 16 + lr;
            float bias = b2[col];
#pragma unroll
            for (int r = 0; r < 4; r++) {
                int row = mblk + m0w + mi * 16 + (lane >> 4) * 4 + r;
                Mo[(size_t)row * 512 + col] = f2bf(gelu_f(acc[mi][nf][r] + bias));
            }
        }
}

// ---------------- GEMM3 (LDS-staged): out = X2 + M@W3 + b3 ----------------
__global__ __launch_bounds__(256) void k_gemm3(const unsigned short* __restrict__ Mb,
                                               const unsigned short* __restrict__ W3T,
                                               const float* __restrict__ b3,
                                               const float* __restrict__ X2,
                                               float* __restrict__ out) {
    __shared__ unsigned short As[128 * 64];
    __shared__ unsigned short Bs[128 * 64];
    int t = threadIdx.x;
    int w = t >> 6, lane = t & 63;
    int m0w = (w & 1) * 64, n0w = (w >> 1) * 64;
    int lr = lane & 15, lk = (lane >> 4) * 8;
    int mblk = blockIdx.x * 128, nblk = blockIdx.y * 128;
    const unsigned short* Ab = Mb + (size_t)mblk * 512;
    const unsigned short* Bb = W3T + (size_t)nblk * 512;
    f32x4 acc[4][4];
#pragma unroll
    for (int i = 0; i < 4; i++)
#pragma unroll
        for (int j = 0; j < 4; j++) acc[i][j] = (f32x4){0.f, 0.f, 0.f, 0.f};
    for (int k0 = 0; k0 < 512; k0 += 64) {
        stage64<128>(Ab, 512, k0, As, t);
        stage64<128>(Bb, 512, k0, Bs, t);
        __syncthreads();
#pragma unroll
        for (int kk = 0; kk < 64; kk += 32) {
            bf16x8 a[4], b[4];
#pragma unroll
            for (int mi = 0; mi < 4; mi++)
                a[mi] = *(const bf16x8*)(As + (m0w + mi * 16 + lr) * 64 + kk + lk);
#pragma unroll
            for (int nf = 0; nf < 4; nf++)
                b[nf] = *(const bf16x8*)(Bs + (n0w + nf * 16 + lr) * 64 + kk + lk);
#pragma unroll
            for (int mi = 0; mi < 4; mi++)
#pragma unroll
                for (int nf = 0; nf < 4; nf++)
                    acc[mi][nf] = __builtin_amdgcn_mfma_f32_16x16x32_bf16(a[mi], b[nf], acc[mi][nf], 0, 0, 0);
        }
        __syncthreads();
    }
#pragma unroll
    for (int mi = 0; mi < 4; mi++)
#pragma unroll
        for (int nf = 0; nf < 4; nf++) {
            int col = nblk + n0w + nf * 16 + lr;
            float bias = b3[col];
#pragma unroll
            for (int r = 0; r < 4; r++) {
                int row = mblk + m0w + mi * 16 + (lane >> 4) * 4 + r;
                size_t idx = (size_t)row * 256 + col;
                out[idx] = X2[idx] + acc[mi][nf][r] + bias;
            }
        }
}

extern "C" void kernel_launch(void* const* d_in, const int* in_sizes, int n_in,
                              void* d_out, int out_size, void* d_ws, size_t ws_size,
                              hipStream_t stream) {
    const float* x     = (const float*)d_in[0];
    const float* ln1g  = (const float*)d_in[1];
    const float* ln1b  = (const float*)d_in[2];
    const float* ln2g  = (const float*)d_in[3];
    const float* ln2b  = (const float*)d_in[4];
    const float* logdt = (const float*)d_in[5];
    const float* Are   = (const float*)d_in[6];
    const float* Aim   = (const float*)d_in[7];
    const float* Cre   = (const float*)d_in[8];
    const float* Cim   = (const float*)d_in[9];
    const float* Dsk   = (const float*)d_in[10];
    const float* Wout  = (const float*)d_in[11];
    const float* bo    = (const float*)d_in[12];
    const float* W2    = (const float*)d_in[13];
    const float* b2    = (const float*)d_in[14];
    const float* W3    = (const float*)d_in[15];
    const float* b3    = (const float*)d_in[16];

    char* ws = (char*)d_ws;
    unsigned short* AB   = (unsigned short*)(ws + OFF_ABIG);
    unsigned short* Wp   = (unsigned short*)(ws + OFF_WPM);
    float*          X2   = (float*)(ws + OFF_ABIG);
    unsigned short* UT   = (unsigned short*)(ws + OFF_UT);
    float*          Zg   = (float*)(ws + OFF_ZG);
    unsigned short* Yt   = (unsigned short*)(ws + OFF_ZG);
    unsigned short* Mb   = (unsigned short*)(ws + OFF_M);
    unsigned short* ZP   = (unsigned short*)(ws + OFF_ZP);
    unsigned short* G    = (unsigned short*)(ws + OFF_G);
    float2*         WT   = (float2*)(ws + OFF_WTAB);
    float2*         WPT  = (float2*)(ws + OFF_WPT);
    float2*         CE   = (float2*)(ws + OFF_CE);
    unsigned short* W1T  = (unsigned short*)(ws + OFF_W1T);
    unsigned short* W2T  = (unsigned short*)(ws + OFF_W2T);
    unsigned short* W3T  = (unsigned short*)(ws + OFF_W3T);

    k_tab<<<32, 256, 0, stream>>>(logdt, Are, Aim, Cre, Cim, WT, WPT, CE);
    k_wt<<<512, 256, 0, stream>>>(Wout, W2, W3, W1T, W2T, W3T);
    k_lntr<<<dim3(64, 16), 256, 0, stream>>>(x, ln1g, ln1b, UT);
    k_abw<<<256, 256, 0, stream>>>(logdt, Are, Aim, CE, Dsk, AB, Wp);
    k_zgemm<<<256, 512, 0, stream>>>(UT, Wp, Zg);
    k_prefix2<<<1024, 256, 0, stream>>>(Zg, WPT, ZP);
    k_conv<<<dim3(256, 2), 512, 0, stream>>>(UT, ZP, AB, Yt);
    k_trg<<<dim3(256, 4, 4), 256, 0, stream>>>(Yt, G);
    k_gemm1<<<dim3(512, 4), 256, 0, stream>>>(G, W1T, bo, x, X2);
    k_ln_bf<<<NB * LL / 4, 256, 0, stream>>>(X2, ln2g, ln2b, G);
    k_gemm2<<<dim3(512, 4), 256, 0, stream>>>(G, W2T, b2, Mb);
    k_gemm3<<<dim3(512, 2), 256, 0, stream>>>(Mb, W3T, b3, X2, (float*)d_out);
}

// Round 8
// 331.971 us; speedup vs baseline: 20.5954x; 1.1200x over previous
//
#include <hip/hip_runtime.h>
#include <hip/hip_bf16.h>

typedef __attribute__((ext_vector_type(8))) short bf16x8;
typedef __attribute__((ext_vector_type(4))) float f32x4;

#define Hdim 256
#define NM 32      // N2 modes
#define NB 16      // batch
#define LL 4096    // seq len
#define PCH 256    // chunk length
#define NCH 16     // chunks = LL/PCH
#define KBIG 384   // conv GEMM K: 256 u + 64 zf + 64 zb

// ---- workspace layout (bytes), total 186,122,240 ----
#define OFF_ABIG ((size_t)0)
#define OFF_WPM  ((size_t)50331648)
#define OFF_UT   ((size_t)67108864)    // U_T bf16 [B][H][L] 33554432
#define OFF_ZG   ((size_t)100663296)   // Zg fp32 [h][bc][128] ; then Yt bf16
#define OFF_M    ((size_t)67108864)    // M bf16 (spans UT+ZG, alive gemm2->gemm3)
#define OFF_ZP   ((size_t)134217728)   // Zpacked bf16 [h][bc][128]
#define OFF_G    ((size_t)150994944)   // G bf16 (b,l,h) ; reused as T2
#define OFF_WTAB ((size_t)185073664)
#define OFF_WPT  ((size_t)185139200)
#define OFF_CE   ((size_t)185204736)
#define OFF_W1T  ((size_t)185335808)
#define OFF_W2T  ((size_t)185597952)
#define OFF_W3T  ((size_t)185860096)

typedef const __attribute__((address_space(1))) void* gas_p;
typedef __attribute__((address_space(3))) void* las_p;

__device__ __forceinline__ float gelu_f(float v) {
    return 0.5f * v * (1.0f + erff(v * 0.70710678118654752f));
}
__device__ __forceinline__ unsigned short f2bf(float f) {  // RNE f32->bf16
    unsigned int u = __float_as_uint(f);
    u += 0x7fffu + ((u >> 16) & 1u);
    return (unsigned short)(u >> 16);
}

// stage ROWS x 64 bf16 tile (row-major, ld elems) into linear LDS [ROWS][64]
template<int ROWS, int THREADS>
__device__ __forceinline__ void stage64(const unsigned short* __restrict__ src, int ld, int k0,
                                        unsigned short* lds, int t) {
    constexpr int EPI = THREADS * 8;   // elems per iter
#pragma unroll
    for (int i = 0; i < (ROWS * 64) / EPI; i++) {
        int e = i * EPI + t * 8;
        int r = e >> 6, k = e & 63;
        const unsigned short* g = src + (size_t)r * ld + (k0 + k);
        unsigned short* l = lds + i * EPI + (t >> 6) * 512;   // wave-uniform base
        __builtin_amdgcn_global_load_lds((gas_p)g, (las_p)l, 16, 0, 0);
    }
}

// stage ROWS x 64 tile of UT (bc-rows) for head h: row = rbase+r, base = ((row>>4)*H+h)*L + (row&15)*P
template<int ROWS, int THREADS>
__device__ __forceinline__ void stageUT(const unsigned short* __restrict__ UT, int h, int rbase,
                                        int k0, unsigned short* lds, int t) {
    constexpr int EPI = THREADS * 8;
#pragma unroll
    for (int i = 0; i < (ROWS * 64) / EPI; i++) {
        int e = i * EPI + t * 8;
        int r = e >> 6, k = e & 63;
        int row = rbase + r;
        const unsigned short* g = UT + ((size_t)((row >> 4) * Hdim + h)) * LL
                                  + (row & 15) * PCH + (k0 + k);
        unsigned short* l = lds + i * EPI + (t >> 6) * 512;
        __builtin_amdgcn_global_load_lds((gas_p)g, (las_p)l, 16, 0, 0);
    }
}

// ---------------- tables ----------------
__global__ void k_tab(const float* __restrict__ logdt, const float* __restrict__ Are,
                      const float* __restrict__ Aim, const float* __restrict__ Cre,
                      const float* __restrict__ Cim, float2* __restrict__ wtab,
                      float2* __restrict__ wptab, float2* __restrict__ ceff) {
    int idx = blockIdx.x * blockDim.x + threadIdx.x;
    if (idx >= Hdim * NM) return;
    int h = idx >> 5;
    float dt = expf(logdt[h]);
    double dar = (double)dt * (double)Are[idx];
    double dai = (double)dt * (double)Aim[idx];
    double wm = exp(dar);
    double wr = wm * cos(dai), wi = wm * sin(dai);
    wtab[idx] = make_float2((float)wr, (float)wi);
    double pm = exp(dar * (double)PCH);
    double pai = dai * (double)PCH;
    wptab[idx] = make_float2((float)(pm * cos(pai)), (float)(pm * sin(pai)));
    double are = (double)Are[idx], aim = (double)Aim[idx];
    double den = are * are + aim * aim;
    double nr = wr - 1.0, ni = wi;
    double qr = (nr * are + ni * aim) / den;
    double qi = (ni * are - nr * aim) / den;
    for (int ch = 0; ch < 2; ch++) {
        double cr = (double)Cre[ch * Hdim * NM + idx];
        double ci = (double)Cim[ch * Hdim * NM + idx];
        ceff[ch * Hdim * NM + idx] = make_float2((float)(cr * qr - ci * qi),
                                                 (float)(cr * qi + ci * qr));
    }
}

// ---------------- weight transpose + bf16 cast ----------------
__global__ void k_wt(const float* __restrict__ W1, const float* __restrict__ W2,
                     const float* __restrict__ W3, unsigned short* __restrict__ W1T,
                     unsigned short* __restrict__ W2T, unsigned short* __restrict__ W3T) {
    int t = blockIdx.x * 256 + threadIdx.x;  // 131072 threads
    int k = t >> 9, n = t & 511;             // W1,W2: [256][512]
    W1T[n * 256 + k] = f2bf(W1[t]);
    W2T[n * 256 + k] = f2bf(W2[t]);
    int k3 = t >> 8, n3 = t & 255;           // W3: [512][256]
    W3T[n3 * 512 + k3] = f2bf(W3[t]);
}

// ---------------- merged: wpow table -> kf/kb -> Abig rows -> Wp rows (all coalesced) ----------------
__global__ __launch_bounds__(256) void k_abw(const float* __restrict__ logdt,
                                             const float* __restrict__ Are,
                                             const float* __restrict__ Aim,
                                             const float2* __restrict__ CE,
                                             const float* __restrict__ Dsk,
                                             unsigned short* __restrict__ AB,
                                             unsigned short* __restrict__ Wp) {
    __shared__ float2 wpow[32][257];   // w^j, j=0..256
    __shared__ float kf[256], kb[256];
    __shared__ float2 ce_s[64];        // [0..31] fwd, [32..63] bwd
    int h = blockIdx.x;
    int t = threadIdx.x;
    if (t < 64) ce_s[t] = CE[(t >> 5) * (Hdim * NM) + h * NM + (t & 31)];
    {   // build wpow: thread = n*8+seg, each does a 32-step recurrence from w^(32*seg)
        int n = t >> 3, seg = t & 7;
        float dt = expf(logdt[h]);
        float dar = dt * Are[h * NM + n], dai = dt * Aim[h * NM + n];
        float em = expf(dar);
        float wr = em * cosf(dai), wi = em * sinf(dai);
        int j0 = seg * 32;
        float m = expf((float)j0 * dar), ang = (float)j0 * dai;
        float vr = m * cosf(ang), vi = m * sinf(ang);
        for (int q = 0; q < 32; q++) {
            wpow[n][j0 + q] = make_float2(vr, vi);
            float nr2 = vr * wr - vi * wi;
            float ni2 = vr * wi + vi * wr;
            vr = nr2; vi = ni2;
        }
        if (seg == 7) wpow[n][256] = make_float2(vr, vi);
    }
    __syncthreads();
    {   // conv kernels kf[d], kb[d] (lane = d)
        float kfv = 0.f, kbv = 0.f;
#pragma unroll
        for (int n = 0; n < NM; n++) {
            float2 wv = wpow[n][t];
            float2 cf = ce_s[n], cb = ce_s[32 + n];
            kfv = fmaf(cf.x, wv.x, fmaf(-cf.y, wv.y, kfv));
            kbv = fmaf(cb.x, wv.x, fmaf(-cb.y, wv.y, kbv));
        }
        kf[t] = 2.f * kfv;
        kb[t] = 2.f * kbv;
    }
    __syncthreads();
    float dsk = Dsk[h];
    // Abig rows: lane = column i; extra 128 cols from lanes 0..127
    for (int j = 0; j < 256; j++) {
        unsigned short* out = AB + ((size_t)h * 256 + j) * KBIG;
        float v = (t <= j) ? kf[j - t] : kb[t - j - 1];
        if (t == j) v += dsk;
        out[t] = f2bf(v);
        if (t < 128) {
            int n = (t & 63) >> 1, reim = t & 1;
            float2 c = (t < 64) ? ce_s[n] : ce_s[32 + n];
            float2 wv = (t < 64) ? wpow[n][j + 1] : wpow[n][255 - j];
            float re = c.x * wv.x - c.y * wv.y;
            float im = c.x * wv.y + c.y * wv.x;
            out[256 + t] = f2bf(reim ? -2.f * im : 2.f * re);
        }
    }
    // Wp rows: row r, lane = column i
    for (int r = 0; r < 128; r++) {
        int n = (r & 63) >> 1, reim = r & 1, dir = r >> 6;
        float2 wv = wpow[n][dir ? t : 255 - t];
        Wp[((size_t)h * 128 + r) * 256 + t] = f2bf(reim ? wv.y : wv.x);
    }
}

// ---------------- fused layernorm + transpose: x (b,l,h) fp32 -> UT (b,h,l) bf16 ----------------
__global__ __launch_bounds__(256) void k_lntr(const float* __restrict__ x,
                                              const float* __restrict__ g,
                                              const float* __restrict__ bt,
                                              unsigned short* __restrict__ UT) {
    __shared__ unsigned short lds[256][65];
    int lt = blockIdx.x, b = blockIdx.y;
    int t = threadIdx.x;
    int lane = t & 63, w = t >> 6;
    float4 gg = ((const float4*)g)[lane];
    float4 bb = ((const float4*)bt)[lane];
#pragma unroll
    for (int q = 0; q < 16; q++) {
        int l = q * 4 + w;
        float4 v = ((const float4*)(x + ((size_t)(b * LL + lt * 64 + l)) * Hdim))[lane];
        float s = v.x + v.y + v.z + v.w;
        float ss = v.x * v.x + v.y * v.y + v.z * v.z + v.w * v.w;
#pragma unroll
        for (int o = 1; o < 64; o <<= 1) { s += __shfl_xor(s, o, 64); ss += __shfl_xor(ss, o, 64); }
        float mean = s * (1.0f / Hdim);
        float var = ss * (1.0f / Hdim) - mean * mean;
        float rstd = rsqrtf(var + 1e-5f);
        lds[lane * 4 + 0][l] = f2bf((v.x - mean) * rstd * gg.x + bb.x);
        lds[lane * 4 + 1][l] = f2bf((v.y - mean) * rstd * gg.y + bb.y);
        lds[lane * 4 + 2][l] = f2bf((v.z - mean) * rstd * gg.z + bb.z);
        lds[lane * 4 + 3][l] = f2bf((v.w - mean) * rstd * gg.w + bb.w);
    }
    __syncthreads();
    for (int q = 0; q < 64; q++) {
        int idx = q * 256 + t;
        int hh = idx >> 6, ll = idx & 63;
        UT[((size_t)(b * Hdim + hh)) * LL + lt * 64 + ll] = lds[hh][ll];
    }
}

// ---------------- layernorm bf16 out (second LN) ----------------
__global__ void k_ln_bf(const float* __restrict__ x, const float* __restrict__ g,
                        const float* __restrict__ bt, unsigned short* __restrict__ out) {
    int row = blockIdx.x * 4 + (threadIdx.x >> 6);
    int lane = threadIdx.x & 63;
    float4 v = ((const float4*)(x + (size_t)row * Hdim))[lane];
    float s = v.x + v.y + v.z + v.w;
    float ss = v.x * v.x + v.y * v.y + v.z * v.z + v.w * v.w;
#pragma unroll
    for (int o = 1; o < 64; o <<= 1) { s += __shfl_xor(s, o, 64); ss += __shfl_xor(ss, o, 64); }
    float mean = s * (1.0f / Hdim);
    float var = ss * (1.0f / Hdim) - mean * mean;
    float rstd = rsqrtf(var + 1e-5f);
    float4 gg = ((const float4*)g)[lane];
    float4 bb = ((const float4*)bt)[lane];
    ushort4 o;
    o.x = f2bf((v.x - mean) * rstd * gg.x + bb.x);
    o.y = f2bf((v.y - mean) * rstd * gg.y + bb.y);
    o.z = f2bf((v.z - mean) * rstd * gg.z + bb.z);
    o.w = f2bf((v.w - mean) * rstd * gg.w + bb.w);
    ((ushort4*)(out + (size_t)row * Hdim))[lane] = o;
}

// ---------------- state GEMM (LDS-staged): Zg[h][bc][r], 256x128 per h ----------------
__global__ __launch_bounds__(512) void k_zgemm(const unsigned short* __restrict__ UT,
                                               const unsigned short* __restrict__ Wp,
                                               float* __restrict__ Zg) {
    __shared__ unsigned short As[256 * 64];
    __shared__ unsigned short Bs[128 * 64];
    int h = blockIdx.x;
    int t = threadIdx.x;
    int w = t >> 6, lane = t & 63;
    int m0 = (w & 3) * 64;     // 4 row groups
    int nb = (w >> 2) * 64;    // 2 col groups
    int lr = lane & 15, lk = (lane >> 4) * 8;
    f32x4 acc[4][4];
#pragma unroll
    for (int i = 0; i < 4; i++)
#pragma unroll
        for (int jx = 0; jx < 4; jx++) acc[i][jx] = (f32x4){0.f, 0.f, 0.f, 0.f};
    for (int k0 = 0; k0 < 256; k0 += 64) {
        stageUT<256, 512>(UT, h, 0, k0, As, t);
        stage64<128, 512>(Wp + (size_t)h * 128 * 256, 256, k0, Bs, t);
        __syncthreads();
#pragma unroll
        for (int kk = 0; kk < 64; kk += 32) {
            bf16x8 a[4], b[4];
#pragma unroll
            for (int mi = 0; mi < 4; mi++)
                a[mi] = *(const bf16x8*)(As + (m0 + mi * 16 + lr) * 64 + kk + lk);
#pragma unroll
            for (int nf = 0; nf < 4; nf++)
                b[nf] = *(const bf16x8*)(Bs + (nb + nf * 16 + lr) * 64 + kk + lk);
#pragma unroll
            for (int mi = 0; mi < 4; mi++)
#pragma unroll
                for (int nf = 0; nf < 4; nf++)
                    acc[mi][nf] = __builtin_amdgcn_mfma_f32_16x16x32_bf16(a[mi], b[nf], acc[mi][nf], 0, 0, 0);
        }
        __syncthreads();
    }
#pragma unroll
    for (int mi = 0; mi < 4; mi++)
#pragma unroll
        for (int nf = 0; nf < 4; nf++) {
            int col = nb + nf * 16 + lr;
#pragma unroll
            for (int r = 0; r < 4; r++) {
                int row = m0 + mi * 16 + (lane >> 4) * 4 + r;
                Zg[((size_t)h * 256 + row) * 128 + col] = acc[mi][nf][r];
            }
        }
}

// ---------------- prefix over chunks -> Zpacked bf16 [h][bc][128] ----------------
__global__ void k_prefix2(const float* __restrict__ Zg, const float2* __restrict__ wptab,
                          unsigned short* __restrict__ ZP) {
    int t = blockIdx.x * 256 + threadIdx.x;
    int n = t & 31;
    int h = (t >> 5) & 255;
    int b = (t >> 13) & 15;
    int dir = (t >> 17) & 1;
    float2 wp = wptab[h * NM + n];
    float sr = 0.f, si = 0.f;
    int ro = dir ? 64 + 2 * n : 2 * n;
    if (dir == 0) {
        for (int c = 0; c < NCH; c++) {
            size_t base = ((size_t)h * 256 + b * NCH + c) * 128;
            ZP[base + ro] = f2bf(sr);
            ZP[base + ro + 1] = f2bf(si);
            float zr = Zg[base + ro], zi = Zg[base + ro + 1];
            float nr = fmaf(wp.x, sr, fmaf(-wp.y, si, zr));
            float ni = fmaf(wp.y, sr, fmaf(wp.x, si, zi));
            sr = nr; si = ni;
        }
    } else {
        for (int c = NCH - 1; c >= 0; c--) {
            size_t base = ((size_t)h * 256 + b * NCH + c) * 128;
            ZP[base + ro] = f2bf(sr);
            ZP[base + ro + 1] = f2bf(si);
            float zr = Zg[base + ro], zi = Zg[base + ro + 1];
            float nr = fmaf(wp.x, sr, fmaf(-wp.y, si, zr));
            float ni = fmaf(wp.y, sr, fmaf(wp.x, si, zi));
            sr = nr; si = ni;
        }
    }
}

// ---------------- conv GEMM (LDS-staged): Yt[h][bc][j], tile 128bc x 256j ----------------
__global__ __launch_bounds__(512) void k_conv(const unsigned short* __restrict__ UT,
                                              const unsigned short* __restrict__ ZP,
                                              const unsigned short* __restrict__ AB,
                                              unsigned short* __restrict__ Yt) {
    __shared__ unsigned short As[128 * 64];
    __shared__ unsigned short Bs[256 * 64];
    // XCD-chunked swizzle (512 blocks, 512%8==0 -> bijective): both bc-halves of an h share an XCD
    int wgid = ((int)blockIdx.x % 8) * 64 + (int)blockIdx.x / 8;
    int h = wgid >> 1;
    int mbase = (wgid & 1) * 128;
    int t = threadIdx.x;
    int w = t >> 6, lane = t & 63;
    int m0 = (w & 1) * 64;     // 2 row groups
    int nb = (w >> 1) * 64;    // 4 col groups (full 256 j)
    int lr = lane & 15, lk = (lane >> 4) * 8;
    const unsigned short* ABh = AB + (size_t)h * 256 * KBIG;
    f32x4 acc[4][4];
#pragma unroll
    for (int i = 0; i < 4; i++)
#pragma unroll
        for (int jx = 0; jx < 4; jx++) acc[i][jx] = (f32x4){0.f, 0.f, 0.f, 0.f};
    // u-part: K = 256
    for (int k0 = 0; k0 < 256; k0 += 64) {
        stageUT<128, 512>(UT, h, mbase, k0, As, t);
        stage64<256, 512>(ABh, KBIG, k0, Bs, t);
        __syncthreads();
#pragma unroll
        for (int kk = 0; kk < 64; kk += 32) {
            bf16x8 a[4], b[4];
#pragma unroll
            for (int mi = 0; mi < 4; mi++)
                a[mi] = *(const bf16x8*)(As + (m0 + mi * 16 + lr) * 64 + kk + lk);
#pragma unroll
            for (int nf = 0; nf < 4; nf++)
                b[nf] = *(const bf16x8*)(Bs + (nb + nf * 16 + lr) * 64 + kk + lk);
#pragma unroll
            for (int mi = 0; mi < 4; mi++)
#pragma unroll
                for (int nf = 0; nf < 4; nf++)
                    acc[mi][nf] = __builtin_amdgcn_mfma_f32_16x16x32_bf16(a[mi], b[nf], acc[mi][nf], 0, 0, 0);
        }
        __syncthreads();
    }
    // z-part: K = 128 from ZP, AB cols 256..383
    for (int k0 = 0; k0 < 128; k0 += 64) {
        stage64<128, 512>(ZP + ((size_t)h * 256 + mbase) * 128, 128, k0, As, t);
        stage64<256, 512>(ABh + 256, KBIG, k0, Bs, t);
        __syncthreads();
#pragma unroll
        for (int kk = 0; kk < 64; kk += 32) {
            bf16x8 a[4], b[4];
#pragma unroll
            for (int mi = 0; mi < 4; mi++)
                a[mi] = *(const bf16x8*)(As + (m0 + mi * 16 + lr) * 64 + kk + lk);
#pragma unroll
            for (int nf = 0; nf < 4; nf++)
                b[nf] = *(const bf16x8*)(Bs + (nb + nf * 16 + lr) * 64 + kk + lk);
#pragma unroll
            for (int mi = 0; mi < 4; mi++)
#pragma unroll
                for (int nf = 0; nf < 4; nf++)
                    acc[mi][nf] = __builtin_amdgcn_mfma_f32_16x16x32_bf16(a[mi], b[nf], acc[mi][nf], 0, 0, 0);
        }
        __syncthreads();
    }
#pragma unroll
    for (int mi = 0; mi < 4; mi++)
#pragma unroll
        for (int nf = 0; nf < 4; nf++) {
            int col = nb + nf * 16 + lr;
#pragma unroll
            for (int r = 0; r < 4; r++) {
                int row = mbase + m0 + mi * 16 + (lane >> 4) * 4 + r;
                Yt[(size_t)h * 65536 + row * 256 + col] = f2bf(gelu_f(acc[mi][nf][r]));
            }
        }
}

// ---------------- transpose Yt [h][bc][j] -> G (b, c*P+j, h) bf16 ----------------
__global__ void k_trg(const unsigned short* __restrict__ Yt, unsigned short* __restrict__ G) {
    __shared__ unsigned short lds[64][65];
    int bc = blockIdx.x;
    int h0 = blockIdx.y * 64, j0 = blockIdx.z * 64;
    int t = threadIdx.x;
#pragma unroll
    for (int q = 0; q < 16; q++) {
        int idx = q * 256 + t;
        int hh = idx >> 6, jj = idx & 63;
        lds[hh][jj] = Yt[(size_t)(h0 + hh) * 65536 + bc * 256 + j0 + jj];
    }
    __syncthreads();
    int b = bc >> 4, c = bc & 15;
#pragma unroll
    for (int q = 0; q < 16; q++) {
        int idx = q * 256 + t;
        int jj = idx >> 6, hh = idx & 63;
        G[((size_t)(b * LL + c * PCH + j0 + jj)) * Hdim + h0 + hh] = lds[hh][jj];
    }
}

// ---------------- GEMM1 (LDS-staged): X2 = x + glu(G@Wout + bo) ----------------
__global__ __launch_bounds__(256) void k_gemm1(const unsigned short* __restrict__ Gm,
                                               const unsigned short* __restrict__ W1T,
                                               const float* __restrict__ bo,
                                               const float* __restrict__ xin,
                                               float* __restrict__ X2) {
    __shared__ unsigned short As[128 * 64];
    __shared__ unsigned short BsA[64 * 64];
    __shared__ unsigned short BsB[64 * 64];
    int t = threadIdx.x;
    int w = t >> 6, lane = t & 63;
    int m0w = (w & 1) * 64, n0w = (w >> 1) * 32;
    int lr = lane & 15, lk = (lane >> 4) * 8;
    int mblk = blockIdx.x * 128, nblk = blockIdx.y * 64;
    const unsigned short* Ab  = Gm + (size_t)mblk * 256;
    const unsigned short* BbA = W1T + (size_t)nblk * 256;
    const unsigned short* BbB = W1T + (size_t)(nblk + 256) * 256;
    f32x4 acc[4][4];
#pragma unroll
    for (int i = 0; i < 4; i++)
#pragma unroll
        for (int j = 0; j < 4; j++) acc[i][j] = (f32x4){0.f, 0.f, 0.f, 0.f};
    for (int k0 = 0; k0 < 256; k0 += 64) {
        stage64<128, 256>(Ab, 256, k0, As, t);
        stage64<64, 256>(BbA, 256, k0, BsA, t);
        stage64<64, 256>(BbB, 256, k0, BsB, t);
        __syncthreads();
#pragma unroll
        for (int kk = 0; kk < 64; kk += 32) {
            bf16x8 a[4], bA[2], bB[2];
#pragma unroll
            for (int mi = 0; mi < 4; mi++)
                a[mi] = *(const bf16x8*)(As + (m0w + mi * 16 + lr) * 64 + kk + lk);
#pragma unroll
            for (int nf = 0; nf < 2; nf++) {
                bA[nf] = *(const bf16x8*)(BsA + (n0w + nf * 16 + lr) * 64 + kk + lk);
                bB[nf] = *(const bf16x8*)(BsB + (n0w + nf * 16 + lr) * 64 + kk + lk);
            }
#pragma unroll
            for (int mi = 0; mi < 4; mi++)
#pragma unroll
                for (int nf = 0; nf < 2; nf++) {
                    acc[mi][nf] = __builtin_amdgcn_mfma_f32_16x16x32_bf16(a[mi], bA[nf], acc[mi][nf], 0, 0, 0);
                    acc[mi][nf + 2] = __builtin_amdgcn_mfma_f32_16x16x32_bf16(a[mi], bB[nf], acc[mi][nf + 2], 0, 0, 0);
                }
        }
        __syncthreads();
    }
#pragma unroll
    for (int mi = 0; mi < 4; mi++)
#pragma unroll
        for (int nf = 0; nf < 2; nf++) {
            int col = nblk + n0w + nf * 16 + lr;
            float biasA = bo[col], biasB = bo[col + 256];
#pragma unroll
            for (int r = 0; r < 4; r++) {
                int row = mblk + m0w + mi * 16 + (lane >> 4) * 4 + r;
                float zzA = acc[mi][nf][r] + biasA;
                float zzB = acc[mi][nf + 2][r] + biasB;
                float v = zzA / (1.0f + expf(-zzB));
                size_t idx = (size_t)row * 256 + col;
                X2[idx] = xin[idx] + v;
            }
        }
}

// ---------------- GEMM2 (LDS-staged): M = gelu(T2@W2 + b2) bf16 ----------------
__global__ __launch_bounds__(256) void k_gemm2(const unsigned short* __restrict__ T2,
                                               const unsigned short* __restrict__ W2T,
                                               const float* __restrict__ b2,
                                               unsigned short* __restrict__ Mo) {
    __shared__ unsigned short As[128 * 64];
    __shared__ unsigned short Bs[128 * 64];
    int t = threadIdx.x;
    int w = t >> 6, lane = t & 63;
    int m0w = (w & 1) * 64, n0w = (w >> 1) * 64;
    int lr = lane & 15, lk = (lane >> 4) * 8;
    int mblk = blockIdx.x * 128, nblk = blockIdx.y * 128;
    const unsigned short* Ab = T2 + (size_t)mblk * 256;
    const unsigned short* Bb = W2T + (size_t)nblk * 256;
    f32x4 acc[4][4];
#pragma unroll
    for (int i = 0; i < 4; i++)
#pragma unroll
        for (int j = 0; j < 4; j++) acc[i][j] = (f32x4){0.f, 0.f, 0.f, 0.f};
    for (int k0 = 0; k0 < 256; k0 += 64) {
        stage64<128, 256>(Ab, 256, k0, As, t);
        stage64<128, 256>(Bb, 256, k0, Bs, t);
        __syncthreads();
#pragma unroll
        for (int kk = 0; kk < 64; kk += 32) {
            bf16x8 a[4], b[4];
#pragma unroll
            for (int mi = 0; mi < 4; mi++)
                a[mi] = *(const bf16x8*)(As + (m0w + mi * 16 + lr) * 64 + kk + lk);
#pragma unroll
            for (int nf = 0; nf < 4; nf++)
                b[nf] = *(const bf16x8*)(Bs + (n0w + nf * 16 + lr) * 64 + kk + lk);
#pragma unroll
            for (int mi = 0; mi < 4; mi++)
#pragma unroll
                for (int nf = 0; nf < 4; nf++)
                    acc[mi][nf] = __builtin_amdgcn_mfma_f32_16x16x32_bf16(a[mi], b[nf], acc[mi][nf], 0, 0, 0);
        }
        __syncthreads();
    }
#pragma unroll
    for (int mi = 0; mi < 4; mi++)
#pragma unroll
        for (int nf = 0; nf < 4; nf++) {
            int col = nblk + n0w + nf * 16 + lr;
            float bias = b2[col];
#pragma unroll
            for (int r = 0; r < 4; r++) {
                int row = mblk + m0w + mi * 16 + (lane >> 4) * 4 + r;
                Mo[(size_t)row * 512 + col] = f2bf(gelu_f(acc[mi][nf][r] + bias));
            }
        }
}

// ---------------- GEMM3 (LDS-staged): out = X2 + M@W3 + b3 ----------------
__global__ __launch_bounds__(256) void k_gemm3(const unsigned short* __restrict__ Mb,
                                               const unsigned short* __restrict__ W3T,
                                               const float* __restrict__ b3,
                                               const float* __restrict__ X2,
                                               float* __restrict__ out) {
    __shared__ unsigned short As[128 * 64];
    __shared__ unsigned short Bs[128 * 64];
    int t = threadIdx.x;
    int w = t >> 6, lane = t & 63;
    int m0w = (w & 1) * 64, n0w = (w >> 1) * 64;
    int lr = lane & 15, lk = (lane >> 4) * 8;
    int mblk = blockIdx.x * 128, nblk = blockIdx.y * 128;
    const unsigned short* Ab = Mb + (size_t)mblk * 512;
    const unsigned short* Bb = W3T + (size_t)nblk * 512;
    f32x4 acc[4][4];
#pragma unroll
    for (int i = 0; i < 4; i++)
#pragma unroll
        for (int j = 0; j < 4; j++) acc[i][j] = (f32x4){0.f, 0.f, 0.f, 0.f};
    for (int k0 = 0; k0 < 512; k0 += 64) {
        stage64<128, 256>(Ab, 512, k0, As, t);
        stage64<128, 256>(Bb, 512, k0, Bs, t);
        __syncthreads();
#pragma unroll
        for (int kk = 0; kk < 64; kk += 32) {
            bf16x8 a[4], b[4];
#pragma unroll
            for (int mi = 0; mi < 4; mi++)
                a[mi] = *(const bf16x8*)(As + (m0w + mi * 16 + lr) * 64 + kk + lk);
#pragma unroll
            for (int nf = 0; nf < 4; nf++)
                b[nf] = *(const bf16x8*)(Bs + (n0w + nf * 16 + lr) * 64 + kk + lk);
#pragma unroll
            for (int mi = 0; mi < 4; mi++)
#pragma unroll
                for (int nf = 0; nf < 4; nf++)
                    acc[mi][nf] = __builtin_amdgcn_mfma_f32_16x16x32_bf16(a[mi], b[nf], acc[mi][nf], 0, 0, 0);
        }
        __syncthreads();
    }
#pragma unroll
    for (int mi = 0; mi < 4; mi++)
#pragma unroll
        for (int nf = 0; nf < 4; nf++) {
            int col = nblk + n0w + nf * 16 + lr;
            float bias = b3[col];
#pragma unroll
            for (int r = 0; r < 4; r++) {
                int row = mblk + m0w + mi * 16 + (lane >> 4) * 4 + r;
                size_t idx = (size_t)row * 256 + col;
                out[idx] = X2[idx] + acc[mi][nf][r] + bias;
            }
        }
}

extern "C" void kernel_launch(void* const* d_in, const int* in_sizes, int n_in,
                              void* d_out, int out_size, void* d_ws, size_t ws_size,
                              hipStream_t stream) {
    const float* x     = (const float*)d_in[0];
    const float* ln1g  = (const float*)d_in[1];
    const float* ln1b  = (const float*)d_in[2];
    const float* ln2g  = (const float*)d_in[3];
    const float* ln2b  = (const float*)d_in[4];
    const float* logdt = (const float*)d_in[5];
    const float* Are   = (const float*)d_in[6];
    const float* Aim   = (const float*)d_in[7];
    const float* Cre   = (const float*)d_in[8];
    const float* Cim   = (const float*)d_in[9];
    const float* Dsk   = (const float*)d_in[10];
    const float* Wout  = (const float*)d_in[11];
    const float* bo    = (const float*)d_in[12];
    const float* W2    = (const float*)d_in[13];
    const float* b2    = (const float*)d_in[14];
    const float* W3    = (const float*)d_in[15];
    const float* b3    = (const float*)d_in[16];

    char* ws = (char*)d_ws;
    unsigned short* AB   = (unsigned short*)(ws + OFF_ABIG);
    unsigned short* Wp   = (unsigned short*)(ws + OFF_WPM);
    float*          X2   = (float*)(ws + OFF_ABIG);
    unsigned short* UT   = (unsigned short*)(ws + OFF_UT);
    float*          Zg   = (float*)(ws + OFF_ZG);
    unsigned short* Yt   = (unsigned short*)(ws + OFF_ZG);
    unsigned short* Mb   = (unsigned short*)(ws + OFF_M);
    unsigned short* ZP   = (unsigned short*)(ws + OFF_ZP);
    unsigned short* G    = (unsigned short*)(ws + OFF_G);
    float2*         WT   = (float2*)(ws + OFF_WTAB);
    float2*         WPT  = (float2*)(ws + OFF_WPT);
    float2*         CE   = (float2*)(ws + OFF_CE);
    unsigned short* W1T  = (unsigned short*)(ws + OFF_W1T);
    unsigned short* W2T  = (unsigned short*)(ws + OFF_W2T);
    unsigned short* W3T  = (unsigned short*)(ws + OFF_W3T);

    k_tab<<<32, 256, 0, stream>>>(logdt, Are, Aim, Cre, Cim, WT, WPT, CE);
    k_wt<<<512, 256, 0, stream>>>(Wout, W2, W3, W1T, W2T, W3T);
    k_lntr<<<dim3(64, 16), 256, 0, stream>>>(x, ln1g, ln1b, UT);
    k_abw<<<256, 256, 0, stream>>>(logdt, Are, Aim, CE, Dsk, AB, Wp);
    k_zgemm<<<256, 512, 0, stream>>>(UT, Wp, Zg);
    k_prefix2<<<1024, 256, 0, stream>>>(Zg, WPT, ZP);
    k_conv<<<512, 512, 0, stream>>>(UT, ZP, AB, Yt);
    k_trg<<<dim3(256, 4, 4), 256, 0, stream>>>(Yt, G);
    k_gemm1<<<dim3(512, 4), 256, 0, stream>>>(G, W1T, bo, x, X2);
    k_ln_bf<<<NB * LL / 4, 256, 0, stream>>>(X2, ln2g, ln2b, G);
    k_gemm2<<<dim3(512, 4), 256, 0, stream>>>(G, W2T, b2, Mb);
    k_gemm3<<<dim3(512, 2), 256, 0, stream>>>(Mb, W3T, b3, X2, (float*)d_out);
}